// Round 1
// baseline (1072.011 us; speedup 1.0000x reference)
//
#include <hip/hip_runtime.h>
#include <math.h>

// Problem constants
#define HW_N   16384
#define DIM    256
#define NSEL   4096
#define NQ     1024
#define NHEAD  8
#define HD     32
#define NP_    25
#define DFF_   1024

// Workspace layout (float offsets). Total ~19.93M floats ~= 76 MB.
#define OFF_CNT     8192LL          // 2 uints (global atomic counters for topk)
#define OFF_SELREF  8448LL          // 2*4096*7
#define OFF_SELSRC  65792LL         // 2*4096*256
#define OFF_SELPOS  2162944LL       // 2*4096*256 (later reused as boxout)
#define OFF_QUERY   4260096LL       // 2*4096*256 (later reused as src2)
#define OFF_BIG     6357248LL       // 2*16384*256 (vproj, later ffn hidden)
#define OFF_F       14745856LL      // multi-use region, 5177344 floats

__device__ __forceinline__ unsigned int f2s(float f) {
    unsigned int u = __float_as_uint(f);
    return (u & 0x80000000u) ? ~u : (u | 0x80000000u);
}

// ---------------- top-k: histogram select + 8192-wide 64-bit bitonic sort ----
extern "C" __global__ __launch_bounds__(1024)
void topk_kernel(const float* __restrict__ score, int* __restrict__ idx_out,
                 unsigned int* __restrict__ gcnt) {
    extern __shared__ unsigned int smu[];   // 65536 B = 16384 u32
    const int t = threadIdx.x;
    const int bb = blockIdx.x;
    const float* sc = score + (long long)bb * HW_N;

    unsigned int* hist = smu;          // [8192]
    unsigned int* scan = smu + 8192;   // [1024]
    // smu[9216] = threshold bin T

    for (int i = t; i < 8192; i += 1024) hist[i] = 0u;
    if (t == 0) gcnt[bb] = 0u;
    __syncthreads();

    for (int j = 0; j < 16; ++j) {
        unsigned int u = f2s(sc[j * 1024 + t]);
        atomicAdd(&hist[u >> 19], 1u);
    }
    __syncthreads();

    unsigned int loc[8]; unsigned int lsum = 0u;
    #pragma unroll
    for (int k = 0; k < 8; ++k) { loc[k] = hist[t * 8 + k]; lsum += loc[k]; }
    scan[t] = lsum;
    __syncthreads();
    for (int off = 1; off < 1024; off <<= 1) {
        unsigned int v = (t + off < 1024) ? scan[t + off] : 0u;
        __syncthreads();
        scan[t] += v;
        __syncthreads();
    }
    unsigned int nxt = (t < 1023) ? scan[t + 1] : 0u;  // suffix(8(t+1))
    unsigned int run = nxt;
    for (int k = 7; k >= 0; --k) {
        run += loc[k];                       // suffix(8t+k)
        unsigned int above = run - loc[k];   // suffix(8t+k+1)
        if (run >= (unsigned)NSEL && above < (unsigned)NSEL)
            smu[9216] = (unsigned int)(t * 8 + k);
    }
    __syncthreads();
    const unsigned int T = smu[9216];
    __syncthreads();   // everyone has T in a register; LDS now reusable

    unsigned long long* keys = (unsigned long long*)smu;  // [8192]
    for (int j = 0; j < 16; ++j) {
        int i = j * 1024 + t;
        unsigned int u = f2s(sc[i]);
        if ((u >> 19) >= T) {
            unsigned int p = atomicAdd(&gcnt[bb], 1u);
            if (p < 8192u)
                keys[p] = ((unsigned long long)u << 32) | (unsigned int)(~(unsigned int)i);
        }
    }
    __syncthreads();
    unsigned int cnt = gcnt[bb];
    if (cnt > 8192u) cnt = 8192u;
    for (int i = t; i < 8192; i += 1024)
        if (i >= (int)cnt) keys[i] = 0ull;
    __syncthreads();

    // bitonic sort, descending
    for (unsigned int k = 2; k <= 8192; k <<= 1) {
        for (unsigned int j = k >> 1; j > 0; j >>= 1) {
            #pragma unroll
            for (int v = 0; v < 8; ++v) {
                int i = v * 1024 + t;
                int p = i ^ (int)j;
                if (p > i) {
                    unsigned long long a = keys[i], c = keys[p];
                    bool desc = ((i & (int)k) == 0);
                    if ((a < c) == desc) { keys[i] = c; keys[p] = a; }
                }
            }
            __syncthreads();
        }
    }
    for (int p = t; p < NSEL; p += 1024) {
        unsigned int low = (unsigned int)keys[p];
        idx_out[bb * NSEL + p] = (int)(~low);
    }
}

// ---------------- gather selected rows ----------------
extern "C" __global__ __launch_bounds__(256)
void gather_kernel(const float* __restrict__ src, const float* __restrict__ pos,
                   const float* __restrict__ refw, const int* __restrict__ idx,
                   float* __restrict__ selsrc, float* __restrict__ selpos,
                   float* __restrict__ selref, float* __restrict__ qk) {
    const int s = blockIdx.x, bb = blockIdx.y, t = threadIdx.x;
    const int i = idx[bb * NSEL + s];
    const long long so = ((long long)(bb * NSEL + s)) * DIM;
    const long long go = ((long long)(bb * HW_N + i)) * DIM;
    float sv = src[go + t], pv = pos[go + t];
    selsrc[so + t] = sv;
    selpos[so + t] = pv;
    if (s < NQ) qk[((long long)(bb * NQ + s)) * DIM + t] = sv + pv;
    if (t < 7)
        selref[(long long)(bb * NSEL + s) * 7 + t] = refw[(long long)(bb * HW_N + i) * 7 + t];
}

// ---------------- generic fp32 GEMM: C = act(A @ W^T + bias) ----------------
// A: (z, M, K) with z-stride sA; W: (N, K) row-major; C: (z, M, N) stride sC.
extern "C" __global__ __launch_bounds__(256)
void gemm_kernel(const float* __restrict__ A, long long sA,
                 const float* __restrict__ W, const float* __restrict__ bias,
                 float* __restrict__ C, long long sC,
                 int M, int N, int K, int relu) {
    __shared__ float As[16][68];
    __shared__ float Bs[16][68];
    const int t = threadIdx.x;
    const int n0 = blockIdx.x * 64, m0 = blockIdx.y * 64;
    const float* Ab = A + (long long)blockIdx.z * sA;
    float* Cb = C + (long long)blockIdx.z * sC;
    const int lm = t >> 2;            // 0..63
    const int kq = (t & 3) * 4;       // 0,4,8,12
    const int tn = t & 15, tm = t >> 4;
    float acc[4][4] = {};
    for (int k0 = 0; k0 < K; k0 += 16) {
        float4 a4 = *(const float4*)(Ab + (long long)(m0 + lm) * K + k0 + kq);
        float4 w4 = make_float4(0.f, 0.f, 0.f, 0.f);
        int n = n0 + lm;
        if (n < N) w4 = *(const float4*)(W + (long long)n * K + k0 + kq);
        __syncthreads();
        As[kq + 0][lm] = a4.x; As[kq + 1][lm] = a4.y;
        As[kq + 2][lm] = a4.z; As[kq + 3][lm] = a4.w;
        Bs[kq + 0][lm] = w4.x; Bs[kq + 1][lm] = w4.y;
        Bs[kq + 2][lm] = w4.z; Bs[kq + 3][lm] = w4.w;
        __syncthreads();
        #pragma unroll
        for (int kk = 0; kk < 16; ++kk) {
            float4 av = *(const float4*)&As[kk][tm * 4];
            float4 bv = *(const float4*)&Bs[kk][tn * 4];
            float aa[4] = {av.x, av.y, av.z, av.w};
            float bb[4] = {bv.x, bv.y, bv.z, bv.w};
            #pragma unroll
            for (int i = 0; i < 4; ++i)
                #pragma unroll
                for (int j = 0; j < 4; ++j)
                    acc[i][j] += aa[i] * bb[j];
        }
    }
    #pragma unroll
    for (int i = 0; i < 4; ++i) {
        int row = m0 + tm * 4 + i;
        #pragma unroll
        for (int j = 0; j < 4; ++j) {
            int col = n0 + tn * 4 + j;
            if (col < N) {
                float v = acc[i][j] + (bias ? bias[col] : 0.f);
                if (relu) v = fmaxf(v, 0.f);
                Cb[(long long)row * N + col] = v;
            }
        }
    }
}

// ---------------- MHA over top-1024 rows: 8 queries per block ----------------
extern "C" __global__ __launch_bounds__(256)
void attn_kernel(const float* __restrict__ qkproj, const float* __restrict__ vbuf,
                 float* __restrict__ attout) {
    __shared__ float qs[8][32];
    __shared__ float scb[8][1024];
    const int t = threadIdx.x;
    const int qt = blockIdx.x, h = blockIdx.y, bb = blockIdx.z;
    const int q0 = qt * 8;
    {
        int qr = t >> 5, d = t & 31;
        qs[qr][d] = qkproj[((long long)(bb * NQ + q0 + qr)) * 512 + h * HD + d];
    }
    __syncthreads();
    const float scale = 0.17677669529663687f;  // 1/sqrt(32)
    {
        int qr = t >> 5;        // 0..7
        int c  = t & 31;        // lane-in-group
        const float4* q4 = (const float4*)qs[qr];
        float4 qv[8];
        #pragma unroll
        for (int cc = 0; cc < 8; ++cc) qv[cc] = q4[cc];
        for (int i = 0; i < 32; ++i) {
            int j = c + 32 * i;
            const float4* kp = (const float4*)(qkproj + ((long long)(bb * NQ + j)) * 512 + 256 + h * HD);
            float acc = 0.f;
            #pragma unroll
            for (int cc = 0; cc < 8; ++cc) {
                float4 kv = kp[cc];
                acc += qv[cc].x * kv.x + qv[cc].y * kv.y + qv[cc].z * kv.z + qv[cc].w * kv.w;
            }
            scb[qr][j] = acc * scale;
        }
    }
    __syncthreads();
    // softmax: each 32-lane half of a wave owns one row
    {
        int l = t & 63, w = t >> 6;
        int r = 2 * w + (l >> 5);
        int c0 = l & 31;
        float ev[32];
        float mx = -1e30f;
        #pragma unroll
        for (int i = 0; i < 32; ++i) { float v = scb[r][c0 + 32 * i]; ev[i] = v; mx = fmaxf(mx, v); }
        #pragma unroll
        for (int m = 16; m >= 1; m >>= 1) mx = fmaxf(mx, __shfl_xor(mx, m, 64));
        float sum = 0.f;
        #pragma unroll
        for (int i = 0; i < 32; ++i) { ev[i] = expf(ev[i] - mx); sum += ev[i]; }
        #pragma unroll
        for (int m = 16; m >= 1; m >>= 1) sum += __shfl_xor(sum, m, 64);
        float inv = 1.f / sum;
        #pragma unroll
        for (int i = 0; i < 32; ++i) scb[r][c0 + 32 * i] = ev[i] * inv;
    }
    __syncthreads();
    {
        int qr = t >> 5, d = t & 31;
        float acc = 0.f;
        for (int j = 0; j < 1024; ++j)
            acc += scb[qr][j] * vbuf[((long long)(bb * NQ + j)) * DIM + h * HD + d];
        attout[((long long)(bb * NQ + q0 + qr)) * DIM + h * HD + d] = acc;
    }
}

// ---------------- residual + LayerNorm (in-place capable) ----------------
extern "C" __global__ __launch_bounds__(256)
void ln_kernel(const float* __restrict__ X, long long sx,
               const float* __restrict__ R, long long sr,
               const float* __restrict__ g, const float* __restrict__ bta,
               float* __restrict__ O, long long so) {
    __shared__ float red[4];
    const int row = blockIdx.x, bb = blockIdx.y, t = threadIdx.x;
    float x = X[(long long)bb * sx + (long long)row * DIM + t]
            + R[(long long)bb * sr + (long long)row * DIM + t];
    float v = x;
    #pragma unroll
    for (int m = 32; m >= 1; m >>= 1) v += __shfl_xor(v, m, 64);
    if ((t & 63) == 0) red[t >> 6] = v;
    __syncthreads();
    float mean = (red[0] + red[1] + red[2] + red[3]) * (1.f / 256.f);
    __syncthreads();
    float d = x - mean;
    v = d * d;
    #pragma unroll
    for (int m = 32; m >= 1; m >>= 1) v += __shfl_xor(v, m, 64);
    if ((t & 63) == 0) red[t >> 6] = v;
    __syncthreads();
    float var = (red[0] + red[1] + red[2] + red[3]) * (1.f / 256.f);
    O[(long long)bb * so + (long long)row * DIM + t] = d * rsqrtf(var + 1e-5f) * g[t] + bta[t];
}

// ---------------- query = selsrc + selpos ----------------
extern "C" __global__ __launch_bounds__(256)
void addq_kernel(const float* __restrict__ a, const float* __restrict__ b2, float* __restrict__ o) {
    long long i = (long long)blockIdx.x * 256 + threadIdx.x;
    o[i] = a[i] + b2[i];
}

// ---------------- box attention: sampling + weighted sum ----------------
extern "C" __global__ __launch_bounds__(256)
void boxattn_kernel(const float* __restrict__ aw, const float* __restrict__ ob,
                    const float* __restrict__ dgrid, const float* __restrict__ selref,
                    const float* __restrict__ vproj, const float* __restrict__ kidx,
                    float* __restrict__ boxout) {
    __shared__ float aw_s[200];
    __shared__ float ob_s[32];
    __shared__ float dg_s[400];
    __shared__ float ref_s[7];
    __shared__ float ki_s[50];
    const int t = threadIdx.x;
    const int s = blockIdx.x, bb = blockIdx.y;
    const long long base = (long long)(bb * NSEL + s);
    if (t < 200) aw_s[t] = aw[base * 200 + t];
    if (t < 32)  ob_s[t] = ob[base * 32 + t];
    for (int i = t; i < 400; i += 256) dg_s[i] = dgrid[base * 400 + i] * (1.f / 188.f);
    if (t < 7)   ref_s[t] = selref[base * 7 + t];
    if (t < 50)  ki_s[t] = kidx[t];
    __syncthreads();
    const int h = t >> 5, d = t & 31;
    // softmax over 25 (redundant across the 32 channel-lanes of a head)
    float mx = -1e30f;
    #pragma unroll
    for (int p = 0; p < NP_; ++p) mx = fmaxf(mx, aw_s[h * NP_ + p]);
    float sm = 0.f;
    #pragma unroll
    for (int p = 0; p < NP_; ++p) sm += expf(aw_s[h * NP_ + p] - mx);
    const float invs = 1.f / sm;
    // box for this head
    const float r0 = ref_s[0], r1 = ref_s[1], r3 = ref_s[3], r4 = ref_s[4], r6 = ref_s[6];
    const float cx = r0 + ob_s[h * 4 + 0] * 0.125f * r3;
    const float cy = r1 + ob_s[h * 4 + 1] * 0.125f * r4;
    float sw = r3 + ob_s[h * 4 + 2] * 0.125f * r3;
    float sh = r4 + ob_s[h * 4 + 3] * 0.125f * r4;
    sw = fmaxf(sw, 0.f); sh = fmaxf(sh, 0.f);
    const float ca = cosf(r6), sa = sinf(r6);
    const float* vb = vproj + ((long long)bb * HW_N) * DIM + h * HD + d;
    float acc = 0.f;
    #pragma unroll
    for (int p = 0; p < NP_; ++p) {
        float fx = ki_s[p * 2 + 0] * sw;
        float fy = ki_s[p * 2 + 1] * sh;
        float gx = cx + ca * fx - sa * fy + dg_s[h * 50 + p * 2 + 0];
        float gy = cy + sa * fx + ca * fy + dg_s[h * 50 + p * 2 + 1];
        float x = gx * 128.f - 0.5f;
        float y = gy * 128.f - 0.5f;
        float x0f = floorf(x), y0f = floorf(y);
        float lx = x - x0f, ly = y - y0f;
        int x0 = (int)x0f, y0 = (int)y0f;
        float sampled = 0.f;
        #pragma unroll
        for (int c = 0; c < 4; ++c) {
            int xi = x0 + (c & 1);
            int yi = y0 + (c >> 1);
            float wgt = ((c & 1) ? lx : 1.f - lx) * ((c >> 1) ? ly : 1.f - ly);
            bool valid = (xi >= 0) & (xi < 128) & (yi >= 0) & (yi < 128);
            int cxi = min(max(xi, 0), 127);
            int cyi = min(max(yi, 0), 127);
            float sv = vb[(long long)(cyi * 128 + cxi) * DIM];
            sampled += sv * (valid ? wgt : 0.f);
        }
        acc += expf(aw_s[h * NP_ + p] - mx) * invs * sampled;
    }
    boxout[base * DIM + h * HD + d] = acc;
}

// ---------------- scatter final rows back into out ----------------
extern "C" __global__ __launch_bounds__(256)
void scatter_kernel(const int* __restrict__ idx, const float* __restrict__ sel,
                    float* __restrict__ out) {
    const int s = blockIdx.x, bb = blockIdx.y, t = threadIdx.x;
    const int i = idx[bb * NSEL + s];
    out[((long long)(bb * HW_N + i)) * DIM + t] = sel[((long long)(bb * NSEL + s)) * DIM + t];
}

extern "C" void kernel_launch(void* const* d_in, const int* in_sizes, int n_in,
                              void* d_out, int out_size, void* d_ws, size_t ws_size,
                              hipStream_t stream) {
    const float* src          = (const float*)d_in[0];
    const float* pos          = (const float*)d_in[1];
    const float* refw         = (const float*)d_in[4];
    const float* score        = (const float*)d_in[5];
    const float* in_proj_w    = (const float*)d_in[6];
    const float* in_proj_b    = (const float*)d_in[7];
    const float* mha_out_w    = (const float*)d_in[8];
    const float* mha_out_b    = (const float*)d_in[9];
    const float* value_proj_w = (const float*)d_in[10];
    const float* value_proj_b = (const float*)d_in[11];
    const float* lin_attn_w   = (const float*)d_in[12];
    const float* lin_attn_b   = (const float*)d_in[13];
    const float* lin_box_w    = (const float*)d_in[14];
    const float* lin_box_b    = (const float*)d_in[15];
    const float* samp_off_w   = (const float*)d_in[16];
    const float* samp_off_b   = (const float*)d_in[17];
    const float* ca_out_w     = (const float*)d_in[18];
    const float* ca_out_b     = (const float*)d_in[19];
    const float* lin1_w       = (const float*)d_in[20];
    const float* lin1_b       = (const float*)d_in[21];
    const float* lin2_w       = (const float*)d_in[22];
    const float* lin2_b       = (const float*)d_in[23];
    const float* qn_g         = (const float*)d_in[24];
    const float* qn_b         = (const float*)d_in[25];
    const float* n1_g         = (const float*)d_in[26];
    const float* n1_b         = (const float*)d_in[27];
    const float* n2_g         = (const float*)d_in[28];
    const float* n2_b         = (const float*)d_in[29];
    const float* kidx         = (const float*)d_in[30];

    float* w = (float*)d_ws;
    int* idxp = (int*)d_ws;
    unsigned int* gcnt = (unsigned int*)d_ws + OFF_CNT;
    float* selref = w + OFF_SELREF;
    float* selsrc = w + OFF_SELSRC;
    float* selpos = w + OFF_SELPOS;
    float* boxout = w + OFF_SELPOS;   // reuse after selpos dead
    float* query  = w + OFF_QUERY;
    float* src2   = w + OFF_QUERY;    // reuse after query dead
    float* vproj  = w + OFF_BIG;
    float* ffnt   = w + OFF_BIG;      // reuse after vproj dead
    float* qk     = w + OFF_F;
    float* qkproj = w + OFF_F + 524288;
    float* vbuf   = w + OFF_F + 1572864;
    float* attout = w + OFF_F + 2097152;
    float* q2     = w + OFF_F + 2621440;
    float* aw     = w + OFF_F;              // reuse after MHA dead
    float* obuf   = w + OFF_F + 1638400;
    float* dgrid  = w + OFF_F + 1900544;
    float* ff     = w + OFF_F;              // reuse after box-attn dead
    float* out    = (float*)d_out;

    // out starts as a copy of src; selected rows overwritten at the end
    hipMemcpyAsync(d_out, src, (size_t)2 * HW_N * DIM * sizeof(float),
                   hipMemcpyDeviceToDevice, stream);

    topk_kernel<<<2, 1024, 65536, stream>>>(score, idxp, gcnt);
    gather_kernel<<<dim3(NSEL, 2), 256, 0, stream>>>(src, pos, refw, idxp,
                                                     selsrc, selpos, selref, qk);
    // MHA projections: [q|k] from qk, v from selsrc(first 1024 rows)
    gemm_kernel<<<dim3(8, 16, 2), 256, 0, stream>>>(qk, 262144LL, in_proj_w, in_proj_b,
                                                    qkproj, 524288LL, NQ, 512, 256, 0);
    gemm_kernel<<<dim3(4, 16, 2), 256, 0, stream>>>(selsrc, 1048576LL, in_proj_w + 512 * 256,
                                                    in_proj_b + 512, vbuf, 262144LL, NQ, 256, 256, 0);
    attn_kernel<<<dim3(128, 8, 2), 256, 0, stream>>>(qkproj, vbuf, attout);
    gemm_kernel<<<dim3(4, 16, 2), 256, 0, stream>>>(attout, 262144LL, mha_out_w, mha_out_b,
                                                    q2, 262144LL, NQ, 256, 256, 0);
    ln_kernel<<<dim3(NQ, 2), 256, 0, stream>>>(selsrc, 1048576LL, q2, 262144LL,
                                               qn_g, qn_b, selsrc, 1048576LL);
    addq_kernel<<<8192, 256, 0, stream>>>(selsrc, selpos, query);
    // box attention inputs
    gemm_kernel<<<dim3(4, 256, 2), 256, 0, stream>>>(src, 4194304LL, value_proj_w, value_proj_b,
                                                     vproj, 4194304LL, HW_N, 256, 256, 0);
    gemm_kernel<<<dim3(4, 64, 2), 256, 0, stream>>>(query, 1048576LL, lin_attn_w, lin_attn_b,
                                                    aw, 819200LL, NSEL, 200, 256, 0);
    gemm_kernel<<<dim3(1, 64, 2), 256, 0, stream>>>(query, 1048576LL, lin_box_w, lin_box_b,
                                                    obuf, 131072LL, NSEL, 32, 256, 0);
    gemm_kernel<<<dim3(7, 64, 2), 256, 0, stream>>>(query, 1048576LL, samp_off_w, samp_off_b,
                                                    dgrid, 1638400LL, NSEL, 400, 256, 0);
    boxattn_kernel<<<dim3(NSEL, 2), 256, 0, stream>>>(aw, obuf, dgrid, selref, vproj, kidx, boxout);
    gemm_kernel<<<dim3(4, 64, 2), 256, 0, stream>>>(boxout, 1048576LL, ca_out_w, ca_out_b,
                                                    src2, 1048576LL, NSEL, 256, 256, 0);
    ln_kernel<<<dim3(NSEL, 2), 256, 0, stream>>>(selsrc, 1048576LL, src2, 1048576LL,
                                                 n1_g, n1_b, selsrc, 1048576LL);
    // FFN
    gemm_kernel<<<dim3(16, 64, 2), 256, 0, stream>>>(selsrc, 1048576LL, lin1_w, lin1_b,
                                                     ffnt, 4194304LL, NSEL, DFF_, 256, 1);
    gemm_kernel<<<dim3(4, 64, 2), 256, 0, stream>>>(ffnt, 4194304LL, lin2_w, lin2_b,
                                                    ff, 1048576LL, NSEL, 256, DFF_, 0);
    ln_kernel<<<dim3(NSEL, 2), 256, 0, stream>>>(selsrc, 1048576LL, ff, 1048576LL,
                                                 n2_g, n2_b, selsrc, 1048576LL);
    scatter_kernel<<<dim3(NSEL, 2), 256, 0, stream>>>(idxp, selsrc, out);
}

// Round 2
// 874.756 us; speedup vs baseline: 1.2255x; 1.2255x over previous
//
#include <hip/hip_runtime.h>
#include <math.h>

// Problem constants
#define HW_N   16384
#define DIM    256
#define NSEL   4096
#define NQ     1024
#define NHEAD  8
#define HD     32
#define NP_    25
#define DFF_   1024

// Workspace layout (float offsets). Total ~19.93M floats ~= 76 MB.
#define OFF_CNT     8192LL          // 2 uints (global atomic counters for topk)
#define OFF_SELREF  8448LL          // 2*4096*7
#define OFF_SELSRC  65792LL         // 2*4096*256
#define OFF_SELPOS  2162944LL       // 2*4096*256 (later reused as boxout)
#define OFF_QUERY   4260096LL       // 2*4096*256 (later reused as src2)
#define OFF_BIG     6357248LL       // 2*16384*256 (vproj, later ffn hidden)
#define OFF_F       14745856LL      // multi-use region, 5177344 floats

__device__ __forceinline__ unsigned int f2s(float f) {
    unsigned int u = __float_as_uint(f);
    return (u & 0x80000000u) ? ~u : (u | 0x80000000u);
}

// ---------------- top-k: histogram select + 8192-wide 64-bit bitonic sort ----
extern "C" __global__ __launch_bounds__(1024)
void topk_kernel(const float* __restrict__ score, int* __restrict__ idx_out,
                 unsigned int* __restrict__ gcnt) {
    extern __shared__ unsigned int smu[];   // 65536 B = 16384 u32
    const int t = threadIdx.x;
    const int bb = blockIdx.x;
    const float* sc = score + (long long)bb * HW_N;

    unsigned int* hist = smu;          // [8192]
    unsigned int* scan = smu + 8192;   // [1024]
    // smu[9216] = threshold bin T

    for (int i = t; i < 8192; i += 1024) hist[i] = 0u;
    if (t == 0) gcnt[bb] = 0u;
    __syncthreads();

    for (int j = 0; j < 16; ++j) {
        unsigned int u = f2s(sc[j * 1024 + t]);
        atomicAdd(&hist[u >> 19], 1u);
    }
    __syncthreads();

    unsigned int loc[8]; unsigned int lsum = 0u;
    #pragma unroll
    for (int k = 0; k < 8; ++k) { loc[k] = hist[t * 8 + k]; lsum += loc[k]; }
    scan[t] = lsum;
    __syncthreads();
    for (int off = 1; off < 1024; off <<= 1) {
        unsigned int v = (t + off < 1024) ? scan[t + off] : 0u;
        __syncthreads();
        scan[t] += v;
        __syncthreads();
    }
    unsigned int nxt = (t < 1023) ? scan[t + 1] : 0u;  // suffix(8(t+1))
    unsigned int run = nxt;
    for (int k = 7; k >= 0; --k) {
        run += loc[k];                       // suffix(8t+k)
        unsigned int above = run - loc[k];   // suffix(8t+k+1)
        if (run >= (unsigned)NSEL && above < (unsigned)NSEL)
            smu[9216] = (unsigned int)(t * 8 + k);
    }
    __syncthreads();
    const unsigned int T = smu[9216];
    __syncthreads();   // everyone has T in a register; LDS now reusable

    unsigned long long* keys = (unsigned long long*)smu;  // [8192]
    for (int j = 0; j < 16; ++j) {
        int i = j * 1024 + t;
        unsigned int u = f2s(sc[i]);
        if ((u >> 19) >= T) {
            unsigned int p = atomicAdd(&gcnt[bb], 1u);
            if (p < 8192u)
                keys[p] = ((unsigned long long)u << 32) | (unsigned int)(~(unsigned int)i);
        }
    }
    __syncthreads();
    unsigned int cnt = gcnt[bb];
    if (cnt > 8192u) cnt = 8192u;
    for (int i = t; i < 8192; i += 1024)
        if (i >= (int)cnt) keys[i] = 0ull;
    __syncthreads();

    // bitonic sort, descending
    for (unsigned int k = 2; k <= 8192; k <<= 1) {
        for (unsigned int j = k >> 1; j > 0; j >>= 1) {
            #pragma unroll
            for (int v = 0; v < 8; ++v) {
                int i = v * 1024 + t;
                int p = i ^ (int)j;
                if (p > i) {
                    unsigned long long a = keys[i], c = keys[p];
                    bool desc = ((i & (int)k) == 0);
                    if ((a < c) == desc) { keys[i] = c; keys[p] = a; }
                }
            }
            __syncthreads();
        }
    }
    for (int p = t; p < NSEL; p += 1024) {
        unsigned int low = (unsigned int)keys[p];
        idx_out[bb * NSEL + p] = (int)(~low);
    }
}

// ---------------- gather selected rows ----------------
extern "C" __global__ __launch_bounds__(256)
void gather_kernel(const float* __restrict__ src, const float* __restrict__ pos,
                   const float* __restrict__ refw, const int* __restrict__ idx,
                   float* __restrict__ selsrc, float* __restrict__ selpos,
                   float* __restrict__ selref, float* __restrict__ qk) {
    const int s = blockIdx.x, bb = blockIdx.y, t = threadIdx.x;
    const int i = idx[bb * NSEL + s];
    const long long so = ((long long)(bb * NSEL + s)) * DIM;
    const long long go = ((long long)(bb * HW_N + i)) * DIM;
    float sv = src[go + t], pv = pos[go + t];
    selsrc[so + t] = sv;
    selpos[so + t] = pv;
    if (s < NQ) qk[((long long)(bb * NQ + s)) * DIM + t] = sv + pv;
    if (t < 7)
        selref[(long long)(bb * NSEL + s) * 7 + t] = refw[(long long)(bb * HW_N + i) * 7 + t];
}

// ---------------- generic fp32 GEMM: C = act(A @ W^T + bias) ----------------
// A: (z, M, K) with z-stride sA; W: (N, K) row-major; C: (z, M, N) stride sC.
extern "C" __global__ __launch_bounds__(256)
void gemm_kernel(const float* __restrict__ A, long long sA,
                 const float* __restrict__ W, const float* __restrict__ bias,
                 float* __restrict__ C, long long sC,
                 int M, int N, int K, int relu) {
    __shared__ float As[16][68];
    __shared__ float Bs[16][68];
    const int t = threadIdx.x;
    const int n0 = blockIdx.x * 64, m0 = blockIdx.y * 64;
    const float* Ab = A + (long long)blockIdx.z * sA;
    float* Cb = C + (long long)blockIdx.z * sC;
    const int lm = t >> 2;            // 0..63
    const int kq = (t & 3) * 4;       // 0,4,8,12
    const int tn = t & 15, tm = t >> 4;
    float acc[4][4] = {};
    for (int k0 = 0; k0 < K; k0 += 16) {
        float4 a4 = *(const float4*)(Ab + (long long)(m0 + lm) * K + k0 + kq);
        float4 w4 = make_float4(0.f, 0.f, 0.f, 0.f);
        int n = n0 + lm;
        if (n < N) w4 = *(const float4*)(W + (long long)n * K + k0 + kq);
        __syncthreads();
        As[kq + 0][lm] = a4.x; As[kq + 1][lm] = a4.y;
        As[kq + 2][lm] = a4.z; As[kq + 3][lm] = a4.w;
        Bs[kq + 0][lm] = w4.x; Bs[kq + 1][lm] = w4.y;
        Bs[kq + 2][lm] = w4.z; Bs[kq + 3][lm] = w4.w;
        __syncthreads();
        #pragma unroll
        for (int kk = 0; kk < 16; ++kk) {
            float4 av = *(const float4*)&As[kk][tm * 4];
            float4 bv = *(const float4*)&Bs[kk][tn * 4];
            float aa[4] = {av.x, av.y, av.z, av.w};
            float bb[4] = {bv.x, bv.y, bv.z, bv.w};
            #pragma unroll
            for (int i = 0; i < 4; ++i)
                #pragma unroll
                for (int j = 0; j < 4; ++j)
                    acc[i][j] += aa[i] * bb[j];
        }
    }
    #pragma unroll
    for (int i = 0; i < 4; ++i) {
        int row = m0 + tm * 4 + i;
        #pragma unroll
        for (int j = 0; j < 4; ++j) {
            int col = n0 + tn * 4 + j;
            if (col < N) {
                float v = acc[i][j] + (bias ? bias[col] : 0.f);
                if (relu) v = fmaxf(v, 0.f);
                Cb[(long long)row * N + col] = v;
            }
        }
    }
}

// ---------------- MHA over top-1024 rows: 8 queries per block ----------------
// LDS-staged K (row-major, pad 36) and V (transposed, pad 68); scores in LDS.
extern "C" __global__ __launch_bounds__(256)
void attn_kernel(const float* __restrict__ qkproj, const float* __restrict__ vbuf,
                 float* __restrict__ attout) {
    __shared__ float qs[8][32];
    __shared__ float scb[8][1024];
    __shared__ float kt[64][36];     // K tile, row-major, +4 pad (16B aligned, conflict-free-ish)
    __shared__ float vt[32][68];     // V tile transposed: vt[d][j], +4 pad
    const int t = threadIdx.x;
    const int qt = blockIdx.x, h = blockIdx.y, bb = blockIdx.z;
    const int q0 = qt * 8;
    const int qr = t >> 5, c = t & 31;
    const int sr = t >> 2;            // stage row 0..63
    const int sc4 = (t & 3) * 2;      // stage quad 0,2,4,6

    qs[qr][c] = qkproj[((long long)(bb * NQ + q0 + qr)) * 512 + h * HD + c];
    __syncthreads();
    float4 qv[8];
    #pragma unroll
    for (int i = 0; i < 8; ++i) qv[i] = ((const float4*)qs[qr])[i];
    const float scale = 0.17677669529663687f;  // 1/sqrt(32)

    // ---- QK^T: 16 tiles of 64 keys ----
    for (int tt = 0; tt < 16; ++tt) {
        const int j0 = tt * 64;
        {
            const float4* g = (const float4*)(qkproj + ((long long)(bb * NQ + j0 + sr)) * 512 + 256 + h * HD);
            float4 a = g[sc4], b = g[sc4 + 1];
            *(float4*)&kt[sr][sc4 * 4] = a;
            *(float4*)&kt[sr][sc4 * 4 + 4] = b;
        }
        __syncthreads();
        float s1 = 0.f, s2 = 0.f;
        #pragma unroll
        for (int i = 0; i < 8; ++i) {
            float4 k1 = *(const float4*)&kt[c][i * 4];
            float4 k2 = *(const float4*)&kt[c + 32][i * 4];
            s1 += qv[i].x * k1.x + qv[i].y * k1.y + qv[i].z * k1.z + qv[i].w * k1.w;
            s2 += qv[i].x * k2.x + qv[i].y * k2.y + qv[i].z * k2.z + qv[i].w * k2.w;
        }
        scb[qr][j0 + c] = s1 * scale;
        scb[qr][j0 + c + 32] = s2 * scale;
        __syncthreads();
    }

    // ---- softmax: each 32-lane half of a wave owns one row ----
    {
        int l = t & 63, w = t >> 6;
        int r = 2 * w + (l >> 5);
        int c0 = l & 31;
        float ev[32];
        float mx = -1e30f;
        #pragma unroll
        for (int i = 0; i < 32; ++i) { float v = scb[r][c0 + 32 * i]; ev[i] = v; mx = fmaxf(mx, v); }
        #pragma unroll
        for (int m = 16; m >= 1; m >>= 1) mx = fmaxf(mx, __shfl_xor(mx, m, 64));
        float sum = 0.f;
        #pragma unroll
        for (int i = 0; i < 32; ++i) { ev[i] = expf(ev[i] - mx); sum += ev[i]; }
        #pragma unroll
        for (int m = 16; m >= 1; m >>= 1) sum += __shfl_xor(sum, m, 64);
        float inv = 1.f / sum;
        #pragma unroll
        for (int i = 0; i < 32; ++i) scb[r][c0 + 32 * i] = ev[i] * inv;
    }
    __syncthreads();

    // ---- P @ V: 16 tiles of 64 keys, V staged transposed ----
    float acc = 0.f;
    for (int tt = 0; tt < 16; ++tt) {
        const int j0 = tt * 64;
        {
            const float4* g = (const float4*)(vbuf + ((long long)(bb * NQ + j0 + sr)) * DIM + h * HD);
            float4 a = g[sc4], b = g[sc4 + 1];
            int d0 = sc4 * 4;
            vt[d0 + 0][sr] = a.x; vt[d0 + 1][sr] = a.y; vt[d0 + 2][sr] = a.z; vt[d0 + 3][sr] = a.w;
            vt[d0 + 4][sr] = b.x; vt[d0 + 5][sr] = b.y; vt[d0 + 6][sr] = b.z; vt[d0 + 7][sr] = b.w;
        }
        __syncthreads();
        #pragma unroll
        for (int i = 0; i < 16; ++i) {
            float4 p = *(const float4*)&scb[qr][j0 + i * 4];
            float4 v = *(const float4*)&vt[c][i * 4];
            acc += p.x * v.x + p.y * v.y + p.z * v.z + p.w * v.w;
        }
        __syncthreads();
    }
    attout[((long long)(bb * NQ + q0 + qr)) * DIM + h * HD + c] = acc;
}

// ---------------- residual + LayerNorm (in-place capable) ----------------
extern "C" __global__ __launch_bounds__(256)
void ln_kernel(const float* __restrict__ X, long long sx,
               const float* __restrict__ R, long long sr,
               const float* __restrict__ g, const float* __restrict__ bta,
               float* __restrict__ O, long long so) {
    __shared__ float red[4];
    const int row = blockIdx.x, bb = blockIdx.y, t = threadIdx.x;
    float x = X[(long long)bb * sx + (long long)row * DIM + t]
            + R[(long long)bb * sr + (long long)row * DIM + t];
    float v = x;
    #pragma unroll
    for (int m = 32; m >= 1; m >>= 1) v += __shfl_xor(v, m, 64);
    if ((t & 63) == 0) red[t >> 6] = v;
    __syncthreads();
    float mean = (red[0] + red[1] + red[2] + red[3]) * (1.f / 256.f);
    __syncthreads();
    float d = x - mean;
    v = d * d;
    #pragma unroll
    for (int m = 32; m >= 1; m >>= 1) v += __shfl_xor(v, m, 64);
    if ((t & 63) == 0) red[t >> 6] = v;
    __syncthreads();
    float var = (red[0] + red[1] + red[2] + red[3]) * (1.f / 256.f);
    O[(long long)bb * so + (long long)row * DIM + t] = d * rsqrtf(var + 1e-5f) * g[t] + bta[t];
}

// ---------------- query = selsrc + selpos ----------------
extern "C" __global__ __launch_bounds__(256)
void addq_kernel(const float* __restrict__ a, const float* __restrict__ b2, float* __restrict__ o) {
    long long i = (long long)blockIdx.x * 256 + threadIdx.x;
    o[i] = a[i] + b2[i];
}

// ---------------- box attention: sampling + weighted sum ----------------
extern "C" __global__ __launch_bounds__(256)
void boxattn_kernel(const float* __restrict__ aw, const float* __restrict__ ob,
                    const float* __restrict__ dgrid, const float* __restrict__ selref,
                    const float* __restrict__ vproj, const float* __restrict__ kidx,
                    float* __restrict__ boxout) {
    __shared__ float aw_s[200];
    __shared__ float ob_s[32];
    __shared__ float dg_s[400];
    __shared__ float ref_s[7];
    __shared__ float ki_s[50];
    const int t = threadIdx.x;
    const int s = blockIdx.x, bb = blockIdx.y;
    const long long base = (long long)(bb * NSEL + s);
    if (t < 200) aw_s[t] = aw[base * 200 + t];
    if (t < 32)  ob_s[t] = ob[base * 32 + t];
    for (int i = t; i < 400; i += 256) dg_s[i] = dgrid[base * 400 + i] * (1.f / 188.f);
    if (t < 7)   ref_s[t] = selref[base * 7 + t];
    if (t < 50)  ki_s[t] = kidx[t];
    __syncthreads();
    const int h = t >> 5, d = t & 31;
    // softmax over 25 (redundant across the 32 channel-lanes of a head)
    float mx = -1e30f;
    #pragma unroll
    for (int p = 0; p < NP_; ++p) mx = fmaxf(mx, aw_s[h * NP_ + p]);
    float sm = 0.f;
    #pragma unroll
    for (int p = 0; p < NP_; ++p) sm += expf(aw_s[h * NP_ + p] - mx);
    const float invs = 1.f / sm;
    // box for this head
    const float r0 = ref_s[0], r1 = ref_s[1], r3 = ref_s[3], r4 = ref_s[4], r6 = ref_s[6];
    const float cx = r0 + ob_s[h * 4 + 0] * 0.125f * r3;
    const float cy = r1 + ob_s[h * 4 + 1] * 0.125f * r4;
    float sw = r3 + ob_s[h * 4 + 2] * 0.125f * r3;
    float sh = r4 + ob_s[h * 4 + 3] * 0.125f * r4;
    sw = fmaxf(sw, 0.f); sh = fmaxf(sh, 0.f);
    const float ca = cosf(r6), sa = sinf(r6);
    const float* vb = vproj + ((long long)bb * HW_N) * DIM + h * HD + d;
    float acc = 0.f;
    #pragma unroll
    for (int p = 0; p < NP_; ++p) {
        float fx = ki_s[p * 2 + 0] * sw;
        float fy = ki_s[p * 2 + 1] * sh;
        float gx = cx + ca * fx - sa * fy + dg_s[h * 50 + p * 2 + 0];
        float gy = cy + sa * fx + ca * fy + dg_s[h * 50 + p * 2 + 1];
        float x = gx * 128.f - 0.5f;
        float y = gy * 128.f - 0.5f;
        float x0f = floorf(x), y0f = floorf(y);
        float lx = x - x0f, ly = y - y0f;
        int x0 = (int)x0f, y0 = (int)y0f;
        float sampled = 0.f;
        #pragma unroll
        for (int c = 0; c < 4; ++c) {
            int xi = x0 + (c & 1);
            int yi = y0 + (c >> 1);
            float wgt = ((c & 1) ? lx : 1.f - lx) * ((c >> 1) ? ly : 1.f - ly);
            bool valid = (xi >= 0) & (xi < 128) & (yi >= 0) & (yi < 128);
            int cxi = min(max(xi, 0), 127);
            int cyi = min(max(yi, 0), 127);
            float sv = vb[(long long)(cyi * 128 + cxi) * DIM];
            sampled += sv * (valid ? wgt : 0.f);
        }
        acc += expf(aw_s[h * NP_ + p] - mx) * invs * sampled;
    }
    boxout[base * DIM + h * HD + d] = acc;
}

// ---------------- scatter final rows back into out ----------------
extern "C" __global__ __launch_bounds__(256)
void scatter_kernel(const int* __restrict__ idx, const float* __restrict__ sel,
                    float* __restrict__ out) {
    const int s = blockIdx.x, bb = blockIdx.y, t = threadIdx.x;
    const int i = idx[bb * NSEL + s];
    out[((long long)(bb * HW_N + i)) * DIM + t] = sel[((long long)(bb * NSEL + s)) * DIM + t];
}

extern "C" void kernel_launch(void* const* d_in, const int* in_sizes, int n_in,
                              void* d_out, int out_size, void* d_ws, size_t ws_size,
                              hipStream_t stream) {
    const float* src          = (const float*)d_in[0];
    const float* pos          = (const float*)d_in[1];
    const float* refw         = (const float*)d_in[4];
    const float* score        = (const float*)d_in[5];
    const float* in_proj_w    = (const float*)d_in[6];
    const float* in_proj_b    = (const float*)d_in[7];
    const float* mha_out_w    = (const float*)d_in[8];
    const float* mha_out_b    = (const float*)d_in[9];
    const float* value_proj_w = (const float*)d_in[10];
    const float* value_proj_b = (const float*)d_in[11];
    const float* lin_attn_w   = (const float*)d_in[12];
    const float* lin_attn_b   = (const float*)d_in[13];
    const float* lin_box_w    = (const float*)d_in[14];
    const float* lin_box_b    = (const float*)d_in[15];
    const float* samp_off_w   = (const float*)d_in[16];
    const float* samp_off_b   = (const float*)d_in[17];
    const float* ca_out_w     = (const float*)d_in[18];
    const float* ca_out_b     = (const float*)d_in[19];
    const float* lin1_w       = (const float*)d_in[20];
    const float* lin1_b       = (const float*)d_in[21];
    const float* lin2_w       = (const float*)d_in[22];
    const float* lin2_b       = (const float*)d_in[23];
    const float* qn_g         = (const float*)d_in[24];
    const float* qn_b         = (const float*)d_in[25];
    const float* n1_g         = (const float*)d_in[26];
    const float* n1_b         = (const float*)d_in[27];
    const float* n2_g         = (const float*)d_in[28];
    const float* n2_b         = (const float*)d_in[29];
    const float* kidx         = (const float*)d_in[30];

    float* w = (float*)d_ws;
    int* idxp = (int*)d_ws;
    unsigned int* gcnt = (unsigned int*)d_ws + OFF_CNT;
    float* selref = w + OFF_SELREF;
    float* selsrc = w + OFF_SELSRC;
    float* selpos = w + OFF_SELPOS;
    float* boxout = w + OFF_SELPOS;   // reuse after selpos dead
    float* query  = w + OFF_QUERY;
    float* src2   = w + OFF_QUERY;    // reuse after query dead
    float* vproj  = w + OFF_BIG;
    float* ffnt   = w + OFF_BIG;      // reuse after vproj dead
    float* qk     = w + OFF_F;
    float* qkproj = w + OFF_F + 524288;
    float* vbuf   = w + OFF_F + 1572864;
    float* attout = w + OFF_F + 2097152;
    float* q2     = w + OFF_F + 2621440;
    float* aw     = w + OFF_F;              // reuse after MHA dead
    float* obuf   = w + OFF_F + 1638400;
    float* dgrid  = w + OFF_F + 1900544;
    float* ff     = w + OFF_F;              // reuse after box-attn dead
    float* out    = (float*)d_out;

    // out starts as a copy of src; selected rows overwritten at the end
    hipMemcpyAsync(d_out, src, (size_t)2 * HW_N * DIM * sizeof(float),
                   hipMemcpyDeviceToDevice, stream);

    topk_kernel<<<2, 1024, 65536, stream>>>(score, idxp, gcnt);
    gather_kernel<<<dim3(NSEL, 2), 256, 0, stream>>>(src, pos, refw, idxp,
                                                     selsrc, selpos, selref, qk);
    // MHA projections: [q|k] from qk, v from selsrc(first 1024 rows)
    gemm_kernel<<<dim3(8, 16, 2), 256, 0, stream>>>(qk, 262144LL, in_proj_w, in_proj_b,
                                                    qkproj, 524288LL, NQ, 512, 256, 0);
    gemm_kernel<<<dim3(4, 16, 2), 256, 0, stream>>>(selsrc, 1048576LL, in_proj_w + 512 * 256,
                                                    in_proj_b + 512, vbuf, 262144LL, NQ, 256, 256, 0);
    attn_kernel<<<dim3(128, 8, 2), 256, 0, stream>>>(qkproj, vbuf, attout);
    gemm_kernel<<<dim3(4, 16, 2), 256, 0, stream>>>(attout, 262144LL, mha_out_w, mha_out_b,
                                                    q2, 262144LL, NQ, 256, 256, 0);
    ln_kernel<<<dim3(NQ, 2), 256, 0, stream>>>(selsrc, 1048576LL, q2, 262144LL,
                                               qn_g, qn_b, selsrc, 1048576LL);
    addq_kernel<<<8192, 256, 0, stream>>>(selsrc, selpos, query);
    // box attention inputs
    gemm_kernel<<<dim3(4, 256, 2), 256, 0, stream>>>(src, 4194304LL, value_proj_w, value_proj_b,
                                                     vproj, 4194304LL, HW_N, 256, 256, 0);
    gemm_kernel<<<dim3(4, 64, 2), 256, 0, stream>>>(query, 1048576LL, lin_attn_w, lin_attn_b,
                                                    aw, 819200LL, NSEL, 200, 256, 0);
    gemm_kernel<<<dim3(1, 64, 2), 256, 0, stream>>>(query, 1048576LL, lin_box_w, lin_box_b,
                                                    obuf, 131072LL, NSEL, 32, 256, 0);
    gemm_kernel<<<dim3(7, 64, 2), 256, 0, stream>>>(query, 1048576LL, samp_off_w, samp_off_b,
                                                    dgrid, 1638400LL, NSEL, 400, 256, 0);
    boxattn_kernel<<<dim3(NSEL, 2), 256, 0, stream>>>(aw, obuf, dgrid, selref, vproj, kidx, boxout);
    gemm_kernel<<<dim3(4, 64, 2), 256, 0, stream>>>(boxout, 1048576LL, ca_out_w, ca_out_b,
                                                    src2, 1048576LL, NSEL, 256, 256, 0);
    ln_kernel<<<dim3(NSEL, 2), 256, 0, stream>>>(selsrc, 1048576LL, src2, 1048576LL,
                                                 n1_g, n1_b, selsrc, 1048576LL);
    // FFN
    gemm_kernel<<<dim3(16, 64, 2), 256, 0, stream>>>(selsrc, 1048576LL, lin1_w, lin1_b,
                                                     ffnt, 4194304LL, NSEL, DFF_, 256, 1);
    gemm_kernel<<<dim3(4, 64, 2), 256, 0, stream>>>(ffnt, 4194304LL, lin2_w, lin2_b,
                                                    ff, 1048576LL, NSEL, 256, DFF_, 0);
    ln_kernel<<<dim3(NSEL, 2), 256, 0, stream>>>(selsrc, 1048576LL, ff, 1048576LL,
                                                 n2_g, n2_b, selsrc, 1048576LL);
    scatter_kernel<<<dim3(NSEL, 2), 256, 0, stream>>>(idxp, selsrc, out);
}

// Round 3
// 843.793 us; speedup vs baseline: 1.2705x; 1.0367x over previous
//
#include <hip/hip_runtime.h>
#include <hip/hip_bf16.h>
#include <math.h>

// Problem constants
#define HW_N   16384
#define DIM    256
#define NSEL   4096
#define NQ     1024
#define NHEAD  8
#define HD     32
#define NP_    25
#define DFF_   1024

// Workspace layout (float offsets). Total ~19.93M floats ~= 76 MB.
#define OFF_CNT     8192LL          // 2 uints (global atomic counters for topk)
#define OFF_SELREF  8448LL          // 2*4096*7
#define OFF_SELSRC  65792LL         // 2*4096*256
#define OFF_SELPOS  2162944LL       // 2*4096*256 (later reused as boxout)
#define OFF_QUERY   4260096LL       // 2*4096*256 (later reused as src2)
#define OFF_BIG     6357248LL       // 2*16384*256 (vproj bf16, later ffn hidden fp32)
#define OFF_F       14745856LL      // multi-use region, 5177344 floats

__device__ __forceinline__ unsigned int f2s(float f) {
    unsigned int u = __float_as_uint(f);
    return (u & 0x80000000u) ? ~u : (u | 0x80000000u);
}

// ---------------- top-k: histogram select + 8192-wide 64-bit bitonic sort ----
extern "C" __global__ __launch_bounds__(1024)
void topk_kernel(const float* __restrict__ score, int* __restrict__ idx_out,
                 unsigned int* __restrict__ gcnt) {
    extern __shared__ unsigned int smu[];   // 65536 B = 16384 u32
    const int t = threadIdx.x;
    const int bb = blockIdx.x;
    const float* sc = score + (long long)bb * HW_N;

    unsigned int* hist = smu;          // [8192]
    unsigned int* scan = smu + 8192;   // [1024]
    // smu[9216] = threshold bin T

    for (int i = t; i < 8192; i += 1024) hist[i] = 0u;
    if (t == 0) gcnt[bb] = 0u;
    __syncthreads();

    for (int j = 0; j < 16; ++j) {
        unsigned int u = f2s(sc[j * 1024 + t]);
        atomicAdd(&hist[u >> 19], 1u);
    }
    __syncthreads();

    unsigned int loc[8]; unsigned int lsum = 0u;
    #pragma unroll
    for (int k = 0; k < 8; ++k) { loc[k] = hist[t * 8 + k]; lsum += loc[k]; }
    scan[t] = lsum;
    __syncthreads();
    for (int off = 1; off < 1024; off <<= 1) {
        unsigned int v = (t + off < 1024) ? scan[t + off] : 0u;
        __syncthreads();
        scan[t] += v;
        __syncthreads();
    }
    unsigned int nxt = (t < 1023) ? scan[t + 1] : 0u;  // suffix(8(t+1))
    unsigned int run = nxt;
    for (int k = 7; k >= 0; --k) {
        run += loc[k];                       // suffix(8t+k)
        unsigned int above = run - loc[k];   // suffix(8t+k+1)
        if (run >= (unsigned)NSEL && above < (unsigned)NSEL)
            smu[9216] = (unsigned int)(t * 8 + k);
    }
    __syncthreads();
    const unsigned int T = smu[9216];
    __syncthreads();   // everyone has T in a register; LDS now reusable

    unsigned long long* keys = (unsigned long long*)smu;  // [8192]
    for (int j = 0; j < 16; ++j) {
        int i = j * 1024 + t;
        unsigned int u = f2s(sc[i]);
        if ((u >> 19) >= T) {
            unsigned int p = atomicAdd(&gcnt[bb], 1u);
            if (p < 8192u)
                keys[p] = ((unsigned long long)u << 32) | (unsigned int)(~(unsigned int)i);
        }
    }
    __syncthreads();
    unsigned int cnt = gcnt[bb];
    if (cnt > 8192u) cnt = 8192u;
    for (int i = t; i < 8192; i += 1024)
        if (i >= (int)cnt) keys[i] = 0ull;
    __syncthreads();

    // bitonic sort, descending
    for (unsigned int k = 2; k <= 8192; k <<= 1) {
        for (unsigned int j = k >> 1; j > 0; j >>= 1) {
            #pragma unroll
            for (int v = 0; v < 8; ++v) {
                int i = v * 1024 + t;
                int p = i ^ (int)j;
                if (p > i) {
                    unsigned long long a = keys[i], c = keys[p];
                    bool desc = ((i & (int)k) == 0);
                    if ((a < c) == desc) { keys[i] = c; keys[p] = a; }
                }
            }
            __syncthreads();
        }
    }
    for (int p = t; p < NSEL; p += 1024) {
        unsigned int low = (unsigned int)keys[p];
        idx_out[bb * NSEL + p] = (int)(~low);
    }
}

// ---------------- gather selected rows ----------------
extern "C" __global__ __launch_bounds__(256)
void gather_kernel(const float* __restrict__ src, const float* __restrict__ pos,
                   const float* __restrict__ refw, const int* __restrict__ idx,
                   float* __restrict__ selsrc, float* __restrict__ selpos,
                   float* __restrict__ selref, float* __restrict__ qk) {
    const int s = blockIdx.x, bb = blockIdx.y, t = threadIdx.x;
    const int i = idx[bb * NSEL + s];
    const long long so = ((long long)(bb * NSEL + s)) * DIM;
    const long long go = ((long long)(bb * HW_N + i)) * DIM;
    float sv = src[go + t], pv = pos[go + t];
    selsrc[so + t] = sv;
    selpos[so + t] = pv;
    if (s < NQ) qk[((long long)(bb * NQ + s)) * DIM + t] = sv + pv;
    if (t < 7)
        selref[(long long)(bb * NSEL + s) * 7 + t] = refw[(long long)(bb * HW_N + i) * 7 + t];
}

// ---------------- generic fp32 GEMM: C = act(A @ W^T + bias) ----------------
// A: (z, M, K) with z-stride sA; W: (N, K) row-major; C: (z, M, N) stride sC.
// obf: store output as bf16 (C reinterpreted as __hip_bfloat16*).
extern "C" __global__ __launch_bounds__(256)
void gemm_kernel(const float* __restrict__ A, long long sA,
                 const float* __restrict__ W, const float* __restrict__ bias,
                 float* __restrict__ C, long long sC,
                 int M, int N, int K, int relu, int obf) {
    __shared__ float As[16][68];
    __shared__ float Bs[16][68];
    const int t = threadIdx.x;
    const int n0 = blockIdx.x * 64, m0 = blockIdx.y * 64;
    const float* Ab = A + (long long)blockIdx.z * sA;
    const long long zoff = (long long)blockIdx.z * sC;
    const int lm = t >> 2;            // 0..63
    const int kq = (t & 3) * 4;       // 0,4,8,12
    const int tn = t & 15, tm = t >> 4;
    float acc[4][4] = {};
    for (int k0 = 0; k0 < K; k0 += 16) {
        float4 a4 = *(const float4*)(Ab + (long long)(m0 + lm) * K + k0 + kq);
        float4 w4 = make_float4(0.f, 0.f, 0.f, 0.f);
        int n = n0 + lm;
        if (n < N) w4 = *(const float4*)(W + (long long)n * K + k0 + kq);
        __syncthreads();
        As[kq + 0][lm] = a4.x; As[kq + 1][lm] = a4.y;
        As[kq + 2][lm] = a4.z; As[kq + 3][lm] = a4.w;
        Bs[kq + 0][lm] = w4.x; Bs[kq + 1][lm] = w4.y;
        Bs[kq + 2][lm] = w4.z; Bs[kq + 3][lm] = w4.w;
        __syncthreads();
        #pragma unroll
        for (int kk = 0; kk < 16; ++kk) {
            float4 av = *(const float4*)&As[kk][tm * 4];
            float4 bv = *(const float4*)&Bs[kk][tn * 4];
            float aa[4] = {av.x, av.y, av.z, av.w};
            float bb[4] = {bv.x, bv.y, bv.z, bv.w};
            #pragma unroll
            for (int i = 0; i < 4; ++i)
                #pragma unroll
                for (int j = 0; j < 4; ++j)
                    acc[i][j] += aa[i] * bb[j];
        }
    }
    #pragma unroll
    for (int i = 0; i < 4; ++i) {
        int row = m0 + tm * 4 + i;
        #pragma unroll
        for (int j = 0; j < 4; ++j) {
            int col = n0 + tn * 4 + j;
            if (col < N) {
                float v = acc[i][j] + (bias ? bias[col] : 0.f);
                if (relu) v = fmaxf(v, 0.f);
                long long off = zoff + (long long)row * N + col;
                if (obf) ((__hip_bfloat16*)C)[off] = __float2bfloat16(v);
                else C[off] = v;
            }
        }
    }
}

// ---------------- MHA over top-1024 rows: 8 queries per block ----------------
// LDS-staged K (row-major, pad 36) and V (transposed, pad 68); scores in LDS.
extern "C" __global__ __launch_bounds__(256)
void attn_kernel(const float* __restrict__ qkproj, const float* __restrict__ vbuf,
                 float* __restrict__ attout) {
    __shared__ float qs[8][32];
    __shared__ float scb[8][1024];
    __shared__ float kt[64][36];     // K tile, row-major, +4 pad
    __shared__ float vt[32][68];     // V tile transposed: vt[d][j], +4 pad
    const int t = threadIdx.x;
    const int qt = blockIdx.x, h = blockIdx.y, bb = blockIdx.z;
    const int q0 = qt * 8;
    const int qr = t >> 5, c = t & 31;
    const int sr = t >> 2;            // stage row 0..63
    const int sc4 = (t & 3) * 2;      // stage quad 0,2,4,6

    qs[qr][c] = qkproj[((long long)(bb * NQ + q0 + qr)) * 512 + h * HD + c];
    __syncthreads();
    float4 qv[8];
    #pragma unroll
    for (int i = 0; i < 8; ++i) qv[i] = ((const float4*)qs[qr])[i];
    const float scale = 0.17677669529663687f;  // 1/sqrt(32)

    // ---- QK^T: 16 tiles of 64 keys ----
    for (int tt = 0; tt < 16; ++tt) {
        const int j0 = tt * 64;
        {
            const float4* g = (const float4*)(qkproj + ((long long)(bb * NQ + j0 + sr)) * 512 + 256 + h * HD);
            float4 a = g[sc4], b = g[sc4 + 1];
            *(float4*)&kt[sr][sc4 * 4] = a;
            *(float4*)&kt[sr][sc4 * 4 + 4] = b;
        }
        __syncthreads();
        float s1 = 0.f, s2 = 0.f;
        #pragma unroll
        for (int i = 0; i < 8; ++i) {
            float4 k1 = *(const float4*)&kt[c][i * 4];
            float4 k2 = *(const float4*)&kt[c + 32][i * 4];
            s1 += qv[i].x * k1.x + qv[i].y * k1.y + qv[i].z * k1.z + qv[i].w * k1.w;
            s2 += qv[i].x * k2.x + qv[i].y * k2.y + qv[i].z * k2.z + qv[i].w * k2.w;
        }
        scb[qr][j0 + c] = s1 * scale;
        scb[qr][j0 + c + 32] = s2 * scale;
        __syncthreads();
    }

    // ---- softmax: each 32-lane half of a wave owns one row ----
    {
        int l = t & 63, w = t >> 6;
        int r = 2 * w + (l >> 5);
        int c0 = l & 31;
        float ev[32];
        float mx = -1e30f;
        #pragma unroll
        for (int i = 0; i < 32; ++i) { float v = scb[r][c0 + 32 * i]; ev[i] = v; mx = fmaxf(mx, v); }
        #pragma unroll
        for (int m = 16; m >= 1; m >>= 1) mx = fmaxf(mx, __shfl_xor(mx, m, 64));
        float sum = 0.f;
        #pragma unroll
        for (int i = 0; i < 32; ++i) { ev[i] = expf(ev[i] - mx); sum += ev[i]; }
        #pragma unroll
        for (int m = 16; m >= 1; m >>= 1) sum += __shfl_xor(sum, m, 64);
        float inv = 1.f / sum;
        #pragma unroll
        for (int i = 0; i < 32; ++i) scb[r][c0 + 32 * i] = ev[i] * inv;
    }
    __syncthreads();

    // ---- P @ V: 16 tiles of 64 keys, V staged transposed ----
    float acc = 0.f;
    for (int tt = 0; tt < 16; ++tt) {
        const int j0 = tt * 64;
        {
            const float4* g = (const float4*)(vbuf + ((long long)(bb * NQ + j0 + sr)) * DIM + h * HD);
            float4 a = g[sc4], b = g[sc4 + 1];
            int d0 = sc4 * 4;
            vt[d0 + 0][sr] = a.x; vt[d0 + 1][sr] = a.y; vt[d0 + 2][sr] = a.z; vt[d0 + 3][sr] = a.w;
            vt[d0 + 4][sr] = b.x; vt[d0 + 5][sr] = b.y; vt[d0 + 6][sr] = b.z; vt[d0 + 7][sr] = b.w;
        }
        __syncthreads();
        #pragma unroll
        for (int i = 0; i < 16; ++i) {
            float4 p = *(const float4*)&scb[qr][j0 + i * 4];
            float4 v = *(const float4*)&vt[c][i * 4];
            acc += p.x * v.x + p.y * v.y + p.z * v.z + p.w * v.w;
        }
        __syncthreads();
    }
    attout[((long long)(bb * NQ + q0 + qr)) * DIM + h * HD + c] = acc;
}

// ---------------- residual + LayerNorm (in-place capable) ----------------
extern "C" __global__ __launch_bounds__(256)
void ln_kernel(const float* __restrict__ X, long long sx,
               const float* __restrict__ R, long long sr,
               const float* __restrict__ g, const float* __restrict__ bta,
               float* __restrict__ O, long long so) {
    __shared__ float red[4];
    const int row = blockIdx.x, bb = blockIdx.y, t = threadIdx.x;
    float x = X[(long long)bb * sx + (long long)row * DIM + t]
            + R[(long long)bb * sr + (long long)row * DIM + t];
    float v = x;
    #pragma unroll
    for (int m = 32; m >= 1; m >>= 1) v += __shfl_xor(v, m, 64);
    if ((t & 63) == 0) red[t >> 6] = v;
    __syncthreads();
    float mean = (red[0] + red[1] + red[2] + red[3]) * (1.f / 256.f);
    __syncthreads();
    float d = x - mean;
    v = d * d;
    #pragma unroll
    for (int m = 32; m >= 1; m >>= 1) v += __shfl_xor(v, m, 64);
    if ((t & 63) == 0) red[t >> 6] = v;
    __syncthreads();
    float var = (red[0] + red[1] + red[2] + red[3]) * (1.f / 256.f);
    O[(long long)bb * so + (long long)row * DIM + t] = d * rsqrtf(var + 1e-5f) * g[t] + bta[t];
}

// ---------------- query = selsrc + selpos ----------------
extern "C" __global__ __launch_bounds__(256)
void addq_kernel(const float* __restrict__ a, const float* __restrict__ b2, float* __restrict__ o) {
    long long i = (long long)blockIdx.x * 256 + threadIdx.x;
    o[i] = a[i] + b2[i];
}

// ---------------- box attention: phase-A geometry to LDS, phase-B pure gather ----
extern "C" __global__ __launch_bounds__(256)
void boxattn_kernel(const float* __restrict__ aw, const float* __restrict__ ob,
                    const float* __restrict__ dgrid, const float* __restrict__ selref,
                    const __hip_bfloat16* __restrict__ vproj, const float* __restrict__ kidx,
                    float* __restrict__ boxout) {
    __shared__ float aw_s[200];
    __shared__ float ob_s[32];
    __shared__ float ref_s[7];
    __shared__ float ki_s[50];
    __shared__ float box_s[8][6];   // cx, cy, sw, sh, ca, sa
    __shared__ float mx_s[8];
    __shared__ float inv_s[8];
    __shared__ float wq_s[200];
    __shared__ int   i4_s[800];     // corner linear pixel index per (h,p,corner)
    __shared__ float w4_s[800];     // fused weight: exp(aw-mx) * bilinear * valid
    const int t = threadIdx.x;
    const int s = blockIdx.x, bb = blockIdx.y;
    const long long base = (long long)(bb * NSEL + s);
    if (t < 200) aw_s[t] = aw[base * 200 + t];
    if (t < 32)  ob_s[t] = ob[base * 32 + t];
    if (t < 7)   ref_s[t] = selref[base * 7 + t];
    if (t < 50)  ki_s[t] = kidx[t];
    __syncthreads();

    // per-head scalars: softmax max + box geometry (once, not 32x)
    if (t < 8) {
        float mx = -1e30f;
        #pragma unroll
        for (int p = 0; p < NP_; ++p) mx = fmaxf(mx, aw_s[t * NP_ + p]);
        mx_s[t] = mx;
        const float r0 = ref_s[0], r1 = ref_s[1], r3 = ref_s[3], r4 = ref_s[4], r6 = ref_s[6];
        box_s[t][0] = r0 + ob_s[t * 4 + 0] * 0.125f * r3;
        box_s[t][1] = r1 + ob_s[t * 4 + 1] * 0.125f * r4;
        box_s[t][2] = fmaxf(r3 + ob_s[t * 4 + 2] * 0.125f * r3, 0.f);
        box_s[t][3] = fmaxf(r4 + ob_s[t * 4 + 3] * 0.125f * r4, 0.f);
        box_s[t][4] = cosf(r6);
        box_s[t][5] = sinf(r6);
    }
    __syncthreads();

    // per-(h,p): softmax numerator + grid point -> 4 corner (index, weight)
    if (t < 200) {
        const int h = t / NP_, p = t - h * NP_;
        const float w = expf(aw_s[t] - mx_s[h]);
        wq_s[t] = w;
        const float cx = box_s[h][0], cy = box_s[h][1];
        const float sw = box_s[h][2], sh = box_s[h][3];
        const float ca = box_s[h][4], sa = box_s[h][5];
        const float fx = ki_s[p * 2 + 0] * sw;
        const float fy = ki_s[p * 2 + 1] * sh;
        const float gx = cx + ca * fx - sa * fy + dgrid[base * 400 + 2 * t + 0] * (1.f / 188.f);
        const float gy = cy + sa * fx + ca * fy + dgrid[base * 400 + 2 * t + 1] * (1.f / 188.f);
        const float x = gx * 128.f - 0.5f;
        const float y = gy * 128.f - 0.5f;
        const float x0f = floorf(x), y0f = floorf(y);
        const float lx = x - x0f, ly = y - y0f;
        const int x0 = (int)x0f, y0 = (int)y0f;
        #pragma unroll
        for (int c = 0; c < 4; ++c) {
            const int xi = x0 + (c & 1);
            const int yi = y0 + (c >> 1);
            const float wgt = ((c & 1) ? lx : 1.f - lx) * ((c >> 1) ? ly : 1.f - ly);
            const bool valid = (xi >= 0) & (xi < 128) & (yi >= 0) & (yi < 128);
            const int cxi = min(max(xi, 0), 127);
            const int cyi = min(max(yi, 0), 127);
            i4_s[t * 4 + c] = cyi * 128 + cxi;
            w4_s[t * 4 + c] = w * (valid ? wgt : 0.f);
        }
    }
    __syncthreads();
    if (t < 8) {
        float sm = 0.f;
        #pragma unroll
        for (int p = 0; p < NP_; ++p) sm += wq_s[t * NP_ + p];
        inv_s[t] = 1.f / sm;
    }
    __syncthreads();

    // phase B: pure gather-accumulate (bf16 value reads, weights broadcast from LDS)
    const int h = t >> 5, d = t & 31;
    const __hip_bfloat16* vb = vproj + ((long long)bb * HW_N) * DIM + h * HD + d;
    float acc = 0.f;
    for (int p = 0; p < NP_; ++p) {
        const int q = (h * NP_ + p) * 4;
        #pragma unroll
        for (int c = 0; c < 4; ++c) {
            acc += w4_s[q + c] * __bfloat162float(vb[(long long)i4_s[q + c] * DIM]);
        }
    }
    boxout[base * DIM + h * HD + d] = acc * inv_s[h];
}

// ---------------- scatter final rows back into out ----------------
extern "C" __global__ __launch_bounds__(256)
void scatter_kernel(const int* __restrict__ idx, const float* __restrict__ sel,
                    float* __restrict__ out) {
    const int s = blockIdx.x, bb = blockIdx.y, t = threadIdx.x;
    const int i = idx[bb * NSEL + s];
    out[((long long)(bb * HW_N + i)) * DIM + t] = sel[((long long)(bb * NSEL + s)) * DIM + t];
}

extern "C" void kernel_launch(void* const* d_in, const int* in_sizes, int n_in,
                              void* d_out, int out_size, void* d_ws, size_t ws_size,
                              hipStream_t stream) {
    const float* src          = (const float*)d_in[0];
    const float* pos          = (const float*)d_in[1];
    const float* refw         = (const float*)d_in[4];
    const float* score        = (const float*)d_in[5];
    const float* in_proj_w    = (const float*)d_in[6];
    const float* in_proj_b    = (const float*)d_in[7];
    const float* mha_out_w    = (const float*)d_in[8];
    const float* mha_out_b    = (const float*)d_in[9];
    const float* value_proj_w = (const float*)d_in[10];
    const float* value_proj_b = (const float*)d_in[11];
    const float* lin_attn_w   = (const float*)d_in[12];
    const float* lin_attn_b   = (const float*)d_in[13];
    const float* lin_box_w    = (const float*)d_in[14];
    const float* lin_box_b    = (const float*)d_in[15];
    const float* samp_off_w   = (const float*)d_in[16];
    const float* samp_off_b   = (const float*)d_in[17];
    const float* ca_out_w     = (const float*)d_in[18];
    const float* ca_out_b     = (const float*)d_in[19];
    const float* lin1_w       = (const float*)d_in[20];
    const float* lin1_b       = (const float*)d_in[21];
    const float* lin2_w       = (const float*)d_in[22];
    const float* lin2_b       = (const float*)d_in[23];
    const float* qn_g         = (const float*)d_in[24];
    const float* qn_b         = (const float*)d_in[25];
    const float* n1_g         = (const float*)d_in[26];
    const float* n1_b         = (const float*)d_in[27];
    const float* n2_g         = (const float*)d_in[28];
    const float* n2_b         = (const float*)d_in[29];
    const float* kidx         = (const float*)d_in[30];

    float* w = (float*)d_ws;
    int* idxp = (int*)d_ws;
    unsigned int* gcnt = (unsigned int*)d_ws + OFF_CNT;
    float* selref = w + OFF_SELREF;
    float* selsrc = w + OFF_SELSRC;
    float* selpos = w + OFF_SELPOS;
    float* boxout = w + OFF_SELPOS;   // reuse after selpos dead
    float* query  = w + OFF_QUERY;
    float* src2   = w + OFF_QUERY;    // reuse after query dead
    __hip_bfloat16* vproj = (__hip_bfloat16*)(w + OFF_BIG);  // bf16 now
    float* ffnt   = w + OFF_BIG;      // reuse after vproj dead
    float* qk     = w + OFF_F;
    float* qkproj = w + OFF_F + 524288;
    float* vbuf   = w + OFF_F + 1572864;
    float* attout = w + OFF_F + 2097152;
    float* q2     = w + OFF_F + 2621440;
    float* aw     = w + OFF_F;              // reuse after MHA dead
    float* obuf   = w + OFF_F + 1638400;
    float* dgrid  = w + OFF_F + 1900544;
    float* ff     = w + OFF_F;              // reuse after box-attn dead
    float* out    = (float*)d_out;

    // out starts as a copy of src; selected rows overwritten at the end
    hipMemcpyAsync(d_out, src, (size_t)2 * HW_N * DIM * sizeof(float),
                   hipMemcpyDeviceToDevice, stream);

    topk_kernel<<<2, 1024, 65536, stream>>>(score, idxp, gcnt);
    gather_kernel<<<dim3(NSEL, 2), 256, 0, stream>>>(src, pos, refw, idxp,
                                                     selsrc, selpos, selref, qk);
    // MHA projections: [q|k] from qk, v from selsrc(first 1024 rows)
    gemm_kernel<<<dim3(8, 16, 2), 256, 0, stream>>>(qk, 262144LL, in_proj_w, in_proj_b,
                                                    qkproj, 524288LL, NQ, 512, 256, 0, 0);
    gemm_kernel<<<dim3(4, 16, 2), 256, 0, stream>>>(selsrc, 1048576LL, in_proj_w + 512 * 256,
                                                    in_proj_b + 512, vbuf, 262144LL, NQ, 256, 256, 0, 0);
    attn_kernel<<<dim3(128, 8, 2), 256, 0, stream>>>(qkproj, vbuf, attout);
    gemm_kernel<<<dim3(4, 16, 2), 256, 0, stream>>>(attout, 262144LL, mha_out_w, mha_out_b,
                                                    q2, 262144LL, NQ, 256, 256, 0, 0);
    ln_kernel<<<dim3(NQ, 2), 256, 0, stream>>>(selsrc, 1048576LL, q2, 262144LL,
                                               qn_g, qn_b, selsrc, 1048576LL);
    addq_kernel<<<8192, 256, 0, stream>>>(selsrc, selpos, query);
    // box attention inputs (vproj stored bf16)
    gemm_kernel<<<dim3(4, 256, 2), 256, 0, stream>>>(src, 4194304LL, value_proj_w, value_proj_b,
                                                     (float*)vproj, 4194304LL, HW_N, 256, 256, 0, 1);
    gemm_kernel<<<dim3(4, 64, 2), 256, 0, stream>>>(query, 1048576LL, lin_attn_w, lin_attn_b,
                                                    aw, 819200LL, NSEL, 200, 256, 0, 0);
    gemm_kernel<<<dim3(1, 64, 2), 256, 0, stream>>>(query, 1048576LL, lin_box_w, lin_box_b,
                                                    obuf, 131072LL, NSEL, 32, 256, 0, 0);
    gemm_kernel<<<dim3(7, 64, 2), 256, 0, stream>>>(query, 1048576LL, samp_off_w, samp_off_b,
                                                    dgrid, 1638400LL, NSEL, 400, 256, 0, 0);
    boxattn_kernel<<<dim3(NSEL, 2), 256, 0, stream>>>(aw, obuf, dgrid, selref, vproj, kidx, boxout);
    gemm_kernel<<<dim3(4, 64, 2), 256, 0, stream>>>(boxout, 1048576LL, ca_out_w, ca_out_b,
                                                    src2, 1048576LL, NSEL, 256, 256, 0, 0);
    ln_kernel<<<dim3(NSEL, 2), 256, 0, stream>>>(selsrc, 1048576LL, src2, 1048576LL,
                                                 n1_g, n1_b, selsrc, 1048576LL);
    // FFN
    gemm_kernel<<<dim3(16, 64, 2), 256, 0, stream>>>(selsrc, 1048576LL, lin1_w, lin1_b,
                                                     ffnt, 4194304LL, NSEL, DFF_, 256, 1, 0);
    gemm_kernel<<<dim3(4, 64, 2), 256, 0, stream>>>(ffnt, 4194304LL, lin2_w, lin2_b,
                                                    ff, 1048576LL, NSEL, 256, DFF_, 0, 0);
    ln_kernel<<<dim3(NSEL, 2), 256, 0, stream>>>(selsrc, 1048576LL, ff, 1048576LL,
                                                 n2_g, n2_b, selsrc, 1048576LL);
    scatter_kernel<<<dim3(NSEL, 2), 256, 0, stream>>>(idxp, selsrc, out);
}

// Round 4
// 580.324 us; speedup vs baseline: 1.8473x; 1.4540x over previous
//
#include <hip/hip_runtime.h>
#include <hip/hip_bf16.h>
#include <math.h>

// Problem constants
#define HW_N   16384
#define DIM    256
#define NSEL   4096
#define NQ     1024
#define NHEAD  8
#define HD     32
#define NP_    25
#define DFF_   1024

// Workspace layout (float offsets). Total ~19.93M floats ~= 76 MB.
#define OFF_CNT     8192LL
#define OFF_SELREF  8448LL          // 2*4096*7
#define OFF_SELSRC  65792LL         // 2*4096*256
#define OFF_SELPOS  2162944LL       // 2*4096*256 (later reused as boxout)
#define OFF_QUERY   4260096LL       // 2*4096*256 (later reused as src2)
#define OFF_BIG     6357248LL       // 2*16384*256 (vproj bf16, later ffn hidden fp32)
#define OFF_F       14745856LL      // multi-use region, 5177344 floats

__device__ __forceinline__ unsigned int f2s(float f) {
    unsigned int u = __float_as_uint(f);
    return (u & 0x80000000u) ? ~u : (u | 0x80000000u);
}

// ---------------- top-k: histogram select, set-classification (no sort) ----
// Exactness: downstream is permutation-equivariant within the top-1024 group
// (slots 0..1023) and the rest (1024..4095); only the SETS must match jax
// top_k (ties broken by lower index). Key = (sortable(val)<<32)|~idx gives
// the exact jax total order; boundary bins resolved by rank over candidates.
extern "C" __global__ __launch_bounds__(1024)
void topk_kernel(const float* __restrict__ score, int* __restrict__ idx_out) {
    extern __shared__ unsigned int smu[];
    unsigned int* hist = smu;           // [8192]
    unsigned int* scan = smu + 8192;    // [1024]
    unsigned int* ctrl = smu + 9216;    // [8]: T1,need1,T2,need2,c1,c2,cntA,cntB
    unsigned long long* list1 = (unsigned long long*)smu;           // cap 2048 (overlaps hist)
    unsigned long long* list2 = (unsigned long long*)(smu + 4096);  // cap 2048
    const int t = threadIdx.x;
    const int bb = blockIdx.x;
    const float* sc = score + (long long)bb * HW_N;

    for (int i = t; i < 8192; i += 1024) hist[i] = 0u;
    if (t == 0) { ctrl[4] = 0u; ctrl[5] = 0u; ctrl[6] = 0u; ctrl[7] = 0u; }
    __syncthreads();

    for (int j = 0; j < 16; ++j) {
        unsigned int u = f2s(sc[j * 1024 + t]);
        atomicAdd(&hist[u >> 19], 1u);
    }
    __syncthreads();

    unsigned int loc[8]; unsigned int lsum = 0u;
    #pragma unroll
    for (int k = 0; k < 8; ++k) { loc[k] = hist[t * 8 + k]; lsum += loc[k]; }
    scan[t] = lsum;
    __syncthreads();
    for (int off = 1; off < 1024; off <<= 1) {
        unsigned int v = (t + off < 1024) ? scan[t + off] : 0u;
        __syncthreads();
        scan[t] += v;
        __syncthreads();
    }
    // scan[t] = suffix count over bins >= 8t. Find boundary bins for k=1024, 4096.
    {
        unsigned int nxt = (t < 1023) ? scan[t + 1] : 0u;
        unsigned int run = nxt;
        for (int k = 7; k >= 0; --k) {
            run += loc[k];                       // suffix(8t+k)
            unsigned int above = run - loc[k];   // suffix(8t+k+1)
            if (run >= 1024u && above < 1024u) { ctrl[0] = (unsigned)(t * 8 + k); ctrl[1] = 1024u - above; }
            if (run >= 4096u && above < 4096u) { ctrl[2] = (unsigned)(t * 8 + k); ctrl[3] = 4096u - above; }
        }
    }
    __syncthreads();
    const unsigned int T1 = ctrl[0], need1 = ctrl[1];
    const unsigned int T2 = ctrl[2], need2 = ctrl[3];

    // collect boundary-bin candidates (hist region now dead; lists overlap it)
    for (int j = 0; j < 16; ++j) {
        int i = j * 1024 + t;
        unsigned int u = f2s(sc[i]);
        unsigned int bin = u >> 19;
        unsigned long long key = ((unsigned long long)u << 32) | (unsigned int)(~(unsigned int)i);
        if (bin == T1) {
            unsigned int p = atomicAdd(&ctrl[4], 1u);
            if (p < 2048u) list1[p] = key;
        }
        if (bin == T2 && T2 != T1) {
            unsigned int p = atomicAdd(&ctrl[5], 1u);
            if (p < 2048u) list2[p] = key;
        }
    }
    __syncthreads();
    const unsigned int c1 = min(ctrl[4], 2048u);
    const unsigned int c2 = min(ctrl[5], 2048u);

    // classify: group A (top-1024) -> slots [0,1024); group B -> [1024,4096)
    for (int j = 0; j < 16; ++j) {
        int i = j * 1024 + t;
        unsigned int u = f2s(sc[i]);
        unsigned int bin = u >> 19;
        unsigned long long key = ((unsigned long long)u << 32) | (unsigned int)(~(unsigned int)i);
        bool inA = false, inB = false;
        if (bin > T1) {
            inA = true;
        } else if (bin == T1) {
            unsigned int r = 0;
            for (unsigned int q = 0; q < c1; ++q) r += (list1[q] > key) ? 1u : 0u;
            if (r < need1) inA = true;
            else if (T2 == T1) inB = (r < need2);
            else inB = true;                     // bin == T1 > T2
        } else if (bin > T2) {
            inB = true;
        } else if (bin == T2) {
            unsigned int r = 0;
            for (unsigned int q = 0; q < c2; ++q) r += (list2[q] > key) ? 1u : 0u;
            inB = (r < need2);
        }
        if (inA) {
            unsigned int p = atomicAdd(&ctrl[6], 1u);
            idx_out[bb * NSEL + p] = i;
        } else if (inB) {
            unsigned int p = atomicAdd(&ctrl[7], 1u);
            idx_out[bb * NSEL + 1024 + p] = i;
        }
    }
}

// ---------------- gather selected rows ----------------
extern "C" __global__ __launch_bounds__(256)
void gather_kernel(const float* __restrict__ src, const float* __restrict__ pos,
                   const float* __restrict__ refw, const int* __restrict__ idx,
                   float* __restrict__ selsrc, float* __restrict__ selpos,
                   float* __restrict__ selref, float* __restrict__ qk) {
    const int s = blockIdx.x, bb = blockIdx.y, t = threadIdx.x;
    const int i = idx[bb * NSEL + s];
    const long long so = ((long long)(bb * NSEL + s)) * DIM;
    const long long go = ((long long)(bb * HW_N + i)) * DIM;
    float sv = src[go + t], pv = pos[go + t];
    selsrc[so + t] = sv;
    selpos[so + t] = pv;
    if (s < NQ) qk[((long long)(bb * NQ + s)) * DIM + t] = sv + pv;
    if (t < 7)
        selref[(long long)(bb * NSEL + s) * 7 + t] = refw[(long long)(bb * HW_N + i) * 7 + t];
}

// ---------------- bf16 MFMA GEMM: C = act(A @ W^T + bias) ----------------
// A: (z, M, K) fp32, converted to bf16 in LDS staging; W: (N, K) fp32 row-major.
// M % 64 == 0, K % 64 == 0; N arbitrary (guarded). obf: bf16 output.
typedef __bf16 bf16x8 __attribute__((ext_vector_type(8)));
typedef float  f32x4  __attribute__((ext_vector_type(4)));

extern "C" __global__ __launch_bounds__(256)
void gemm_kernel(const float* __restrict__ A, long long sA,
                 const float* __restrict__ W, const float* __restrict__ bias,
                 float* __restrict__ C, long long sC,
                 int M, int N, int K, int relu, int obf) {
    __shared__ __hip_bfloat16 As[64][72];   // stride 72 bf16 = 144 B (16B-aligned)
    __shared__ __hip_bfloat16 Ws[64][72];
    const int t = threadIdx.x;
    const int n0 = blockIdx.x * 64, m0 = blockIdx.y * 64;
    const float* Ab = A + (long long)blockIdx.z * sA;
    const long long zoff = (long long)blockIdx.z * sC;
    const int lane = t & 63, wv = t >> 6;
    const int mw = (wv >> 1) * 32, nw = (wv & 1) * 32;
    const int fr = lane & 15;           // fragment row (A) / col (B)
    const int fk = (lane >> 4) * 8;     // fragment k offset
    const int sr = t >> 2;              // staging row 0..63
    const int sk = (t & 3) * 16;        // staging k offset

    f32x4 acc[2][2];
    #pragma unroll
    for (int i = 0; i < 2; ++i)
        #pragma unroll
        for (int j = 0; j < 2; ++j) acc[i][j] = {0.f, 0.f, 0.f, 0.f};

    const bool wok = (n0 + sr) < N;
    for (int k0 = 0; k0 < K; k0 += 64) {
        const float* ap = Ab + (long long)(m0 + sr) * K + k0 + sk;
        float av[16];
        #pragma unroll
        for (int q = 0; q < 4; ++q) {
            float4 v = *(const float4*)(ap + q * 4);
            av[q * 4 + 0] = v.x; av[q * 4 + 1] = v.y; av[q * 4 + 2] = v.z; av[q * 4 + 3] = v.w;
        }
        float wvv[16];
        if (wok) {
            const float* wp = W + (long long)(n0 + sr) * K + k0 + sk;
            #pragma unroll
            for (int q = 0; q < 4; ++q) {
                float4 v = *(const float4*)(wp + q * 4);
                wvv[q * 4 + 0] = v.x; wvv[q * 4 + 1] = v.y; wvv[q * 4 + 2] = v.z; wvv[q * 4 + 3] = v.w;
            }
        } else {
            #pragma unroll
            for (int q = 0; q < 16; ++q) wvv[q] = 0.f;
        }
        __syncthreads();   // previous iteration's LDS reads complete
        #pragma unroll
        for (int q = 0; q < 16; ++q) {
            As[sr][sk + q] = __float2bfloat16(av[q]);
            Ws[sr][sk + q] = __float2bfloat16(wvv[q]);
        }
        __syncthreads();
        #pragma unroll
        for (int kk = 0; kk < 64; kk += 32) {
            bf16x8 a0 = *(const bf16x8*)&As[mw + fr][kk + fk];
            bf16x8 a1 = *(const bf16x8*)&As[mw + 16 + fr][kk + fk];
            bf16x8 b0 = *(const bf16x8*)&Ws[nw + fr][kk + fk];
            bf16x8 b1 = *(const bf16x8*)&Ws[nw + 16 + fr][kk + fk];
            acc[0][0] = __builtin_amdgcn_mfma_f32_16x16x32_bf16(a0, b0, acc[0][0], 0, 0, 0);
            acc[0][1] = __builtin_amdgcn_mfma_f32_16x16x32_bf16(a0, b1, acc[0][1], 0, 0, 0);
            acc[1][0] = __builtin_amdgcn_mfma_f32_16x16x32_bf16(a1, b0, acc[1][0], 0, 0, 0);
            acc[1][1] = __builtin_amdgcn_mfma_f32_16x16x32_bf16(a1, b1, acc[1][1], 0, 0, 0);
        }
    }
    const int crow = (lane >> 4) * 4;
    #pragma unroll
    for (int mi = 0; mi < 2; ++mi) {
        #pragma unroll
        for (int ni = 0; ni < 2; ++ni) {
            const int col = n0 + nw + ni * 16 + fr;
            if (col < N) {
                const float bv = bias ? bias[col] : 0.f;
                #pragma unroll
                for (int r = 0; r < 4; ++r) {
                    const int row = m0 + mw + mi * 16 + crow + r;
                    float v = acc[mi][ni][r] + bv;
                    if (relu) v = fmaxf(v, 0.f);
                    long long off = zoff + (long long)row * N + col;
                    if (obf) ((__hip_bfloat16*)C)[off] = __float2bfloat16(v);
                    else C[off] = v;
                }
            }
        }
    }
}

// ---------------- MHA over top-1024 rows: 8 queries per block ----------------
extern "C" __global__ __launch_bounds__(256)
void attn_kernel(const float* __restrict__ qkproj, const float* __restrict__ vbuf,
                 float* __restrict__ attout) {
    __shared__ float qs[8][32];
    __shared__ float scb[8][1024];
    __shared__ float kt[64][36];
    __shared__ float vt[32][68];
    const int t = threadIdx.x;
    const int qt = blockIdx.x, h = blockIdx.y, bb = blockIdx.z;
    const int q0 = qt * 8;
    const int qr = t >> 5, c = t & 31;
    const int sr = t >> 2;
    const int sc4 = (t & 3) * 2;

    qs[qr][c] = qkproj[((long long)(bb * NQ + q0 + qr)) * 512 + h * HD + c];
    __syncthreads();
    float4 qv[8];
    #pragma unroll
    for (int i = 0; i < 8; ++i) qv[i] = ((const float4*)qs[qr])[i];
    const float scale = 0.17677669529663687f;

    for (int tt = 0; tt < 16; ++tt) {
        const int j0 = tt * 64;
        {
            const float4* g = (const float4*)(qkproj + ((long long)(bb * NQ + j0 + sr)) * 512 + 256 + h * HD);
            float4 a = g[sc4], b = g[sc4 + 1];
            *(float4*)&kt[sr][sc4 * 4] = a;
            *(float4*)&kt[sr][sc4 * 4 + 4] = b;
        }
        __syncthreads();
        float s1 = 0.f, s2 = 0.f;
        #pragma unroll
        for (int i = 0; i < 8; ++i) {
            float4 k1 = *(const float4*)&kt[c][i * 4];
            float4 k2 = *(const float4*)&kt[c + 32][i * 4];
            s1 += qv[i].x * k1.x + qv[i].y * k1.y + qv[i].z * k1.z + qv[i].w * k1.w;
            s2 += qv[i].x * k2.x + qv[i].y * k2.y + qv[i].z * k2.z + qv[i].w * k2.w;
        }
        scb[qr][j0 + c] = s1 * scale;
        scb[qr][j0 + c + 32] = s2 * scale;
        __syncthreads();
    }
    {
        int l = t & 63, w = t >> 6;
        int r = 2 * w + (l >> 5);
        int c0 = l & 31;
        float ev[32];
        float mx = -1e30f;
        #pragma unroll
        for (int i = 0; i < 32; ++i) { float v = scb[r][c0 + 32 * i]; ev[i] = v; mx = fmaxf(mx, v); }
        #pragma unroll
        for (int m = 16; m >= 1; m >>= 1) mx = fmaxf(mx, __shfl_xor(mx, m, 64));
        float sum = 0.f;
        #pragma unroll
        for (int i = 0; i < 32; ++i) { ev[i] = expf(ev[i] - mx); sum += ev[i]; }
        #pragma unroll
        for (int m = 16; m >= 1; m >>= 1) sum += __shfl_xor(sum, m, 64);
        float inv = 1.f / sum;
        #pragma unroll
        for (int i = 0; i < 32; ++i) scb[r][c0 + 32 * i] = ev[i] * inv;
    }
    __syncthreads();
    float acc = 0.f;
    for (int tt = 0; tt < 16; ++tt) {
        const int j0 = tt * 64;
        {
            const float4* g = (const float4*)(vbuf + ((long long)(bb * NQ + j0 + sr)) * DIM + h * HD);
            float4 a = g[sc4], b = g[sc4 + 1];
            int d0 = sc4 * 4;
            vt[d0 + 0][sr] = a.x; vt[d0 + 1][sr] = a.y; vt[d0 + 2][sr] = a.z; vt[d0 + 3][sr] = a.w;
            vt[d0 + 4][sr] = b.x; vt[d0 + 5][sr] = b.y; vt[d0 + 6][sr] = b.z; vt[d0 + 7][sr] = b.w;
        }
        __syncthreads();
        #pragma unroll
        for (int i = 0; i < 16; ++i) {
            float4 p = *(const float4*)&scb[qr][j0 + i * 4];
            float4 v = *(const float4*)&vt[c][i * 4];
            acc += p.x * v.x + p.y * v.y + p.z * v.z + p.w * v.w;
        }
        __syncthreads();
    }
    attout[((long long)(bb * NQ + q0 + qr)) * DIM + h * HD + c] = acc;
}

// ---------------- residual + LayerNorm (in-place capable) ----------------
extern "C" __global__ __launch_bounds__(256)
void ln_kernel(const float* __restrict__ X, long long sx,
               const float* __restrict__ R, long long sr,
               const float* __restrict__ g, const float* __restrict__ bta,
               float* __restrict__ O, long long so) {
    __shared__ float red[4];
    const int row = blockIdx.x, bb = blockIdx.y, t = threadIdx.x;
    float x = X[(long long)bb * sx + (long long)row * DIM + t]
            + R[(long long)bb * sr + (long long)row * DIM + t];
    float v = x;
    #pragma unroll
    for (int m = 32; m >= 1; m >>= 1) v += __shfl_xor(v, m, 64);
    if ((t & 63) == 0) red[t >> 6] = v;
    __syncthreads();
    float mean = (red[0] + red[1] + red[2] + red[3]) * (1.f / 256.f);
    __syncthreads();
    float d = x - mean;
    v = d * d;
    #pragma unroll
    for (int m = 32; m >= 1; m >>= 1) v += __shfl_xor(v, m, 64);
    if ((t & 63) == 0) red[t >> 6] = v;
    __syncthreads();
    float var = (red[0] + red[1] + red[2] + red[3]) * (1.f / 256.f);
    O[(long long)bb * so + (long long)row * DIM + t] = d * rsqrtf(var + 1e-5f) * g[t] + bta[t];
}

// ---------------- query = selsrc + selpos ----------------
extern "C" __global__ __launch_bounds__(256)
void addq_kernel(const float* __restrict__ a, const float* __restrict__ b2, float* __restrict__ o) {
    long long i = (long long)blockIdx.x * 256 + threadIdx.x;
    o[i] = a[i] + b2[i];
}

// ---------------- box attention: phase-A geometry to LDS, phase-B pure gather ----
extern "C" __global__ __launch_bounds__(256)
void boxattn_kernel(const float* __restrict__ aw, const float* __restrict__ ob,
                    const float* __restrict__ dgrid, const float* __restrict__ selref,
                    const __hip_bfloat16* __restrict__ vproj, const float* __restrict__ kidx,
                    float* __restrict__ boxout) {
    __shared__ float aw_s[200];
    __shared__ float ob_s[32];
    __shared__ float ref_s[7];
    __shared__ float ki_s[50];
    __shared__ float box_s[8][6];
    __shared__ float mx_s[8];
    __shared__ float inv_s[8];
    __shared__ float wq_s[200];
    __shared__ int   i4_s[800];
    __shared__ float w4_s[800];
    const int t = threadIdx.x;
    const int s = blockIdx.x, bb = blockIdx.y;
    const long long base = (long long)(bb * NSEL + s);
    if (t < 200) aw_s[t] = aw[base * 200 + t];
    if (t < 32)  ob_s[t] = ob[base * 32 + t];
    if (t < 7)   ref_s[t] = selref[base * 7 + t];
    if (t < 50)  ki_s[t] = kidx[t];
    __syncthreads();

    if (t < 8) {
        float mx = -1e30f;
        #pragma unroll
        for (int p = 0; p < NP_; ++p) mx = fmaxf(mx, aw_s[t * NP_ + p]);
        mx_s[t] = mx;
        const float r0 = ref_s[0], r1 = ref_s[1], r3 = ref_s[3], r4 = ref_s[4], r6 = ref_s[6];
        box_s[t][0] = r0 + ob_s[t * 4 + 0] * 0.125f * r3;
        box_s[t][1] = r1 + ob_s[t * 4 + 1] * 0.125f * r4;
        box_s[t][2] = fmaxf(r3 + ob_s[t * 4 + 2] * 0.125f * r3, 0.f);
        box_s[t][3] = fmaxf(r4 + ob_s[t * 4 + 3] * 0.125f * r4, 0.f);
        box_s[t][4] = cosf(r6);
        box_s[t][5] = sinf(r6);
    }
    __syncthreads();

    if (t < 200) {
        const int h = t / NP_, p = t - h * NP_;
        const float w = expf(aw_s[t] - mx_s[h]);
        wq_s[t] = w;
        const float cx = box_s[h][0], cy = box_s[h][1];
        const float sw = box_s[h][2], sh = box_s[h][3];
        const float ca = box_s[h][4], sa = box_s[h][5];
        const float fx = ki_s[p * 2 + 0] * sw;
        const float fy = ki_s[p * 2 + 1] * sh;
        const float gx = cx + ca * fx - sa * fy + dgrid[base * 400 + 2 * t + 0] * (1.f / 188.f);
        const float gy = cy + sa * fx + ca * fy + dgrid[base * 400 + 2 * t + 1] * (1.f / 188.f);
        const float x = gx * 128.f - 0.5f;
        const float y = gy * 128.f - 0.5f;
        const float x0f = floorf(x), y0f = floorf(y);
        const float lx = x - x0f, ly = y - y0f;
        const int x0 = (int)x0f, y0 = (int)y0f;
        #pragma unroll
        for (int c = 0; c < 4; ++c) {
            const int xi = x0 + (c & 1);
            const int yi = y0 + (c >> 1);
            const float wgt = ((c & 1) ? lx : 1.f - lx) * ((c >> 1) ? ly : 1.f - ly);
            const bool valid = (xi >= 0) & (xi < 128) & (yi >= 0) & (yi < 128);
            const int cxi = min(max(xi, 0), 127);
            const int cyi = min(max(yi, 0), 127);
            i4_s[t * 4 + c] = cyi * 128 + cxi;
            w4_s[t * 4 + c] = w * (valid ? wgt : 0.f);
        }
    }
    __syncthreads();
    if (t < 8) {
        float sm = 0.f;
        #pragma unroll
        for (int p = 0; p < NP_; ++p) sm += wq_s[t * NP_ + p];
        inv_s[t] = 1.f / sm;
    }
    __syncthreads();

    const int h = t >> 5, d = t & 31;
    const __hip_bfloat16* vb = vproj + ((long long)bb * HW_N) * DIM + h * HD + d;
    float acc = 0.f;
    for (int p = 0; p < NP_; ++p) {
        const int q = (h * NP_ + p) * 4;
        #pragma unroll
        for (int c = 0; c < 4; ++c) {
            acc += w4_s[q + c] * __bfloat162float(vb[(long long)i4_s[q + c] * DIM]);
        }
    }
    boxout[base * DIM + h * HD + d] = acc * inv_s[h];
}

// ---------------- scatter final rows back into out ----------------
extern "C" __global__ __launch_bounds__(256)
void scatter_kernel(const int* __restrict__ idx, const float* __restrict__ sel,
                    float* __restrict__ out) {
    const int s = blockIdx.x, bb = blockIdx.y, t = threadIdx.x;
    const int i = idx[bb * NSEL + s];
    out[((long long)(bb * HW_N + i)) * DIM + t] = sel[((long long)(bb * NSEL + s)) * DIM + t];
}

extern "C" void kernel_launch(void* const* d_in, const int* in_sizes, int n_in,
                              void* d_out, int out_size, void* d_ws, size_t ws_size,
                              hipStream_t stream) {
    const float* src          = (const float*)d_in[0];
    const float* pos          = (const float*)d_in[1];
    const float* refw         = (const float*)d_in[4];
    const float* score        = (const float*)d_in[5];
    const float* in_proj_w    = (const float*)d_in[6];
    const float* in_proj_b    = (const float*)d_in[7];
    const float* mha_out_w    = (const float*)d_in[8];
    const float* mha_out_b    = (const float*)d_in[9];
    const float* value_proj_w = (const float*)d_in[10];
    const float* value_proj_b = (const float*)d_in[11];
    const float* lin_attn_w   = (const float*)d_in[12];
    const float* lin_attn_b   = (const float*)d_in[13];
    const float* lin_box_w    = (const float*)d_in[14];
    const float* lin_box_b    = (const float*)d_in[15];
    const float* samp_off_w   = (const float*)d_in[16];
    const float* samp_off_b   = (const float*)d_in[17];
    const float* ca_out_w     = (const float*)d_in[18];
    const float* ca_out_b     = (const float*)d_in[19];
    const float* lin1_w       = (const float*)d_in[20];
    const float* lin1_b       = (const float*)d_in[21];
    const float* lin2_w       = (const float*)d_in[22];
    const float* lin2_b       = (const float*)d_in[23];
    const float* qn_g         = (const float*)d_in[24];
    const float* qn_b         = (const float*)d_in[25];
    const float* n1_g         = (const float*)d_in[26];
    const float* n1_b         = (const float*)d_in[27];
    const float* n2_g         = (const float*)d_in[28];
    const float* n2_b         = (const float*)d_in[29];
    const float* kidx         = (const float*)d_in[30];

    float* w = (float*)d_ws;
    int* idxp = (int*)d_ws;
    float* selref = w + OFF_SELREF;
    float* selsrc = w + OFF_SELSRC;
    float* selpos = w + OFF_SELPOS;
    float* boxout = w + OFF_SELPOS;   // reuse after selpos dead
    float* query  = w + OFF_QUERY;
    float* src2   = w + OFF_QUERY;    // reuse after query dead
    __hip_bfloat16* vproj = (__hip_bfloat16*)(w + OFF_BIG);
    float* ffnt   = w + OFF_BIG;      // reuse after vproj dead
    float* qk     = w + OFF_F;
    float* qkproj = w + OFF_F + 524288;
    float* vbuf   = w + OFF_F + 1572864;
    float* attout = w + OFF_F + 2097152;
    float* q2     = w + OFF_F + 2621440;
    float* aw     = w + OFF_F;              // reuse after MHA dead
    float* obuf   = w + OFF_F + 1638400;
    float* dgrid  = w + OFF_F + 1900544;
    float* ff     = w + OFF_F;              // reuse after box-attn dead
    float* out    = (float*)d_out;

    hipMemcpyAsync(d_out, src, (size_t)2 * HW_N * DIM * sizeof(float),
                   hipMemcpyDeviceToDevice, stream);

    topk_kernel<<<2, 1024, 40960, stream>>>(score, idxp);
    gather_kernel<<<dim3(NSEL, 2), 256, 0, stream>>>(src, pos, refw, idxp,
                                                     selsrc, selpos, selref, qk);
    gemm_kernel<<<dim3(8, 16, 2), 256, 0, stream>>>(qk, 262144LL, in_proj_w, in_proj_b,
                                                    qkproj, 524288LL, NQ, 512, 256, 0, 0);
    gemm_kernel<<<dim3(4, 16, 2), 256, 0, stream>>>(selsrc, 1048576LL, in_proj_w + 512 * 256,
                                                    in_proj_b + 512, vbuf, 262144LL, NQ, 256, 256, 0, 0);
    attn_kernel<<<dim3(128, 8, 2), 256, 0, stream>>>(qkproj, vbuf, attout);
    gemm_kernel<<<dim3(4, 16, 2), 256, 0, stream>>>(attout, 262144LL, mha_out_w, mha_out_b,
                                                    q2, 262144LL, NQ, 256, 256, 0, 0);
    ln_kernel<<<dim3(NQ, 2), 256, 0, stream>>>(selsrc, 1048576LL, q2, 262144LL,
                                               qn_g, qn_b, selsrc, 1048576LL);
    addq_kernel<<<8192, 256, 0, stream>>>(selsrc, selpos, query);
    gemm_kernel<<<dim3(4, 256, 2), 256, 0, stream>>>(src, 4194304LL, value_proj_w, value_proj_b,
                                                     (float*)vproj, 4194304LL, HW_N, 256, 256, 0, 1);
    gemm_kernel<<<dim3(4, 64, 2), 256, 0, stream>>>(query, 1048576LL, lin_attn_w, lin_attn_b,
                                                    aw, 819200LL, NSEL, 200, 256, 0, 0);
    gemm_kernel<<<dim3(1, 64, 2), 256, 0, stream>>>(query, 1048576LL, lin_box_w, lin_box_b,
                                                    obuf, 131072LL, NSEL, 32, 256, 0, 0);
    gemm_kernel<<<dim3(7, 64, 2), 256, 0, stream>>>(query, 1048576LL, samp_off_w, samp_off_b,
                                                    dgrid, 1638400LL, NSEL, 400, 256, 0, 0);
    boxattn_kernel<<<dim3(NSEL, 2), 256, 0, stream>>>(aw, obuf, dgrid, selref, vproj, kidx, boxout);
    gemm_kernel<<<dim3(4, 64, 2), 256, 0, stream>>>(boxout, 1048576LL, ca_out_w, ca_out_b,
                                                    src2, 1048576LL, NSEL, 256, 256, 0, 0);
    ln_kernel<<<dim3(NSEL, 2), 256, 0, stream>>>(selsrc, 1048576LL, src2, 1048576LL,
                                                 n1_g, n1_b, selsrc, 1048576LL);
    gemm_kernel<<<dim3(16, 64, 2), 256, 0, stream>>>(selsrc, 1048576LL, lin1_w, lin1_b,
                                                     ffnt, 4194304LL, NSEL, DFF_, 256, 1, 0);
    gemm_kernel<<<dim3(4, 64, 2), 256, 0, stream>>>(ffnt, 4194304LL, lin2_w, lin2_b,
                                                    ff, 1048576LL, NSEL, 256, DFF_, 0, 0);
    ln_kernel<<<dim3(NSEL, 2), 256, 0, stream>>>(selsrc, 1048576LL, ff, 1048576LL,
                                                 n2_g, n2_b, selsrc, 1048576LL);
    scatter_kernel<<<dim3(NSEL, 2), 256, 0, stream>>>(idxp, selsrc, out);
}

// Round 5
// 517.975 us; speedup vs baseline: 2.0696x; 1.1204x over previous
//
#include <hip/hip_runtime.h>
#include <hip/hip_bf16.h>
#include <math.h>

// Problem constants
#define HW_N   16384
#define DIM    256
#define NSEL   4096
#define NQ     1024
#define NHEAD  8
#define HD     32
#define NP_    25
#define DFF_   1024

// Workspace layout (float offsets). Total ~19.93M floats ~= 76 MB.
#define OFF_CNT     8192LL
#define OFF_SELREF  8448LL          // 2*4096*7
#define OFF_SELSRC  65792LL         // 2*4096*256
#define OFF_SELPOS  2162944LL       // 2*4096*256 (later reused as boxout)
#define OFF_QUERY   4260096LL       // 2*4096*256 (later reused as src2)
#define OFF_BIG     6357248LL       // 2*16384*256 (vproj bf16, later ffn hidden fp32)
#define OFF_F       14745856LL      // multi-use region, 5177344 floats

__device__ __forceinline__ unsigned int f2s(float f) {
    unsigned int u = __float_as_uint(f);
    return (u & 0x80000000u) ? ~u : (u | 0x80000000u);
}

// ---------------- top-k: histogram select, set-classification (no sort) ----
extern "C" __global__ __launch_bounds__(1024)
void topk_kernel(const float* __restrict__ score, int* __restrict__ idx_out) {
    extern __shared__ unsigned int smu[];
    unsigned int* hist = smu;           // [8192]
    unsigned int* scan = smu + 8192;    // [1024]
    unsigned int* ctrl = smu + 9216;    // [8]: T1,need1,T2,need2,c1,c2,cntA,cntB
    unsigned long long* list1 = (unsigned long long*)smu;           // cap 2048
    unsigned long long* list2 = (unsigned long long*)(smu + 4096);  // cap 2048
    const int t = threadIdx.x;
    const int bb = blockIdx.x;
    const float* sc = score + (long long)bb * HW_N;

    for (int i = t; i < 8192; i += 1024) hist[i] = 0u;
    if (t == 0) { ctrl[4] = 0u; ctrl[5] = 0u; ctrl[6] = 0u; ctrl[7] = 0u; }
    __syncthreads();

    for (int j = 0; j < 16; ++j) {
        unsigned int u = f2s(sc[j * 1024 + t]);
        atomicAdd(&hist[u >> 19], 1u);
    }
    __syncthreads();

    unsigned int loc[8]; unsigned int lsum = 0u;
    #pragma unroll
    for (int k = 0; k < 8; ++k) { loc[k] = hist[t * 8 + k]; lsum += loc[k]; }
    scan[t] = lsum;
    __syncthreads();
    for (int off = 1; off < 1024; off <<= 1) {
        unsigned int v = (t + off < 1024) ? scan[t + off] : 0u;
        __syncthreads();
        scan[t] += v;
        __syncthreads();
    }
    {
        unsigned int nxt = (t < 1023) ? scan[t + 1] : 0u;
        unsigned int run = nxt;
        for (int k = 7; k >= 0; --k) {
            run += loc[k];
            unsigned int above = run - loc[k];
            if (run >= 1024u && above < 1024u) { ctrl[0] = (unsigned)(t * 8 + k); ctrl[1] = 1024u - above; }
            if (run >= 4096u && above < 4096u) { ctrl[2] = (unsigned)(t * 8 + k); ctrl[3] = 4096u - above; }
        }
    }
    __syncthreads();
    const unsigned int T1 = ctrl[0], need1 = ctrl[1];
    const unsigned int T2 = ctrl[2], need2 = ctrl[3];

    for (int j = 0; j < 16; ++j) {
        int i = j * 1024 + t;
        unsigned int u = f2s(sc[i]);
        unsigned int bin = u >> 19;
        unsigned long long key = ((unsigned long long)u << 32) | (unsigned int)(~(unsigned int)i);
        if (bin == T1) {
            unsigned int p = atomicAdd(&ctrl[4], 1u);
            if (p < 2048u) list1[p] = key;
        }
        if (bin == T2 && T2 != T1) {
            unsigned int p = atomicAdd(&ctrl[5], 1u);
            if (p < 2048u) list2[p] = key;
        }
    }
    __syncthreads();
    const unsigned int c1 = min(ctrl[4], 2048u);
    const unsigned int c2 = min(ctrl[5], 2048u);

    for (int j = 0; j < 16; ++j) {
        int i = j * 1024 + t;
        unsigned int u = f2s(sc[i]);
        unsigned int bin = u >> 19;
        unsigned long long key = ((unsigned long long)u << 32) | (unsigned int)(~(unsigned int)i);
        bool inA = false, inB = false;
        if (bin > T1) {
            inA = true;
        } else if (bin == T1) {
            unsigned int r = 0;
            for (unsigned int q = 0; q < c1; ++q) r += (list1[q] > key) ? 1u : 0u;
            if (r < need1) inA = true;
            else if (T2 == T1) inB = (r < need2);
            else inB = true;
        } else if (bin > T2) {
            inB = true;
        } else if (bin == T2) {
            unsigned int r = 0;
            for (unsigned int q = 0; q < c2; ++q) r += (list2[q] > key) ? 1u : 0u;
            inB = (r < need2);
        }
        if (inA) {
            unsigned int p = atomicAdd(&ctrl[6], 1u);
            idx_out[bb * NSEL + p] = i;
        } else if (inB) {
            unsigned int p = atomicAdd(&ctrl[7], 1u);
            idx_out[bb * NSEL + 1024 + p] = i;
        }
    }
}

// ---------------- gather selected rows ----------------
extern "C" __global__ __launch_bounds__(256)
void gather_kernel(const float* __restrict__ src, const float* __restrict__ pos,
                   const float* __restrict__ refw, const int* __restrict__ idx,
                   float* __restrict__ selsrc, float* __restrict__ selpos,
                   float* __restrict__ selref, float* __restrict__ qk) {
    const int s = blockIdx.x, bb = blockIdx.y, t = threadIdx.x;
    const int i = idx[bb * NSEL + s];
    const long long so = ((long long)(bb * NSEL + s)) * DIM;
    const long long go = ((long long)(bb * HW_N + i)) * DIM;
    float sv = src[go + t], pv = pos[go + t];
    selsrc[so + t] = sv;
    selpos[so + t] = pv;
    if (s < NQ) qk[((long long)(bb * NQ + s)) * DIM + t] = sv + pv;
    if (t < 7)
        selref[(long long)(bb * NSEL + s) * 7 + t] = refw[(long long)(bb * HW_N + i) * 7 + t];
}

// ---------------- bf16 MFMA GEMM: C = act(A @ W^T + bias) ----------------
// omode: 0 = fp32 out; 1 = bf16 out (flat); 2 = bf16 out TRANSPOSED:
//   off = zoff + col*M + row   (used to build V^T [dim][key] for attention).
typedef __bf16 bf16x8 __attribute__((ext_vector_type(8)));
typedef float  f32x4  __attribute__((ext_vector_type(4)));

extern "C" __global__ __launch_bounds__(256)
void gemm_kernel(const float* __restrict__ A, long long sA,
                 const float* __restrict__ W, const float* __restrict__ bias,
                 float* __restrict__ C, long long sC,
                 int M, int N, int K, int relu, int omode) {
    __shared__ __hip_bfloat16 As[64][72];
    __shared__ __hip_bfloat16 Ws[64][72];
    const int t = threadIdx.x;
    const int n0 = blockIdx.x * 64, m0 = blockIdx.y * 64;
    const float* Ab = A + (long long)blockIdx.z * sA;
    const long long zoff = (long long)blockIdx.z * sC;
    const int lane = t & 63, wv = t >> 6;
    const int mw = (wv >> 1) * 32, nw = (wv & 1) * 32;
    const int fr = lane & 15;
    const int fk = (lane >> 4) * 8;
    const int sr = t >> 2;
    const int sk = (t & 3) * 16;

    f32x4 acc[2][2];
    #pragma unroll
    for (int i = 0; i < 2; ++i)
        #pragma unroll
        for (int j = 0; j < 2; ++j) acc[i][j] = {0.f, 0.f, 0.f, 0.f};

    const bool wok = (n0 + sr) < N;
    for (int k0 = 0; k0 < K; k0 += 64) {
        const float* ap = Ab + (long long)(m0 + sr) * K + k0 + sk;
        float av[16];
        #pragma unroll
        for (int q = 0; q < 4; ++q) {
            float4 v = *(const float4*)(ap + q * 4);
            av[q * 4 + 0] = v.x; av[q * 4 + 1] = v.y; av[q * 4 + 2] = v.z; av[q * 4 + 3] = v.w;
        }
        float wvv[16];
        if (wok) {
            const float* wp = W + (long long)(n0 + sr) * K + k0 + sk;
            #pragma unroll
            for (int q = 0; q < 4; ++q) {
                float4 v = *(const float4*)(wp + q * 4);
                wvv[q * 4 + 0] = v.x; wvv[q * 4 + 1] = v.y; wvv[q * 4 + 2] = v.z; wvv[q * 4 + 3] = v.w;
            }
        } else {
            #pragma unroll
            for (int q = 0; q < 16; ++q) wvv[q] = 0.f;
        }
        __syncthreads();
        #pragma unroll
        for (int q = 0; q < 16; ++q) {
            As[sr][sk + q] = __float2bfloat16(av[q]);
            Ws[sr][sk + q] = __float2bfloat16(wvv[q]);
        }
        __syncthreads();
        #pragma unroll
        for (int kk = 0; kk < 64; kk += 32) {
            bf16x8 a0 = *(const bf16x8*)&As[mw + fr][kk + fk];
            bf16x8 a1 = *(const bf16x8*)&As[mw + 16 + fr][kk + fk];
            bf16x8 b0 = *(const bf16x8*)&Ws[nw + fr][kk + fk];
            bf16x8 b1 = *(const bf16x8*)&Ws[nw + 16 + fr][kk + fk];
            acc[0][0] = __builtin_amdgcn_mfma_f32_16x16x32_bf16(a0, b0, acc[0][0], 0, 0, 0);
            acc[0][1] = __builtin_amdgcn_mfma_f32_16x16x32_bf16(a0, b1, acc[0][1], 0, 0, 0);
            acc[1][0] = __builtin_amdgcn_mfma_f32_16x16x32_bf16(a1, b0, acc[1][0], 0, 0, 0);
            acc[1][1] = __builtin_amdgcn_mfma_f32_16x16x32_bf16(a1, b1, acc[1][1], 0, 0, 0);
        }
    }
    const int crow = (lane >> 4) * 4;
    #pragma unroll
    for (int mi = 0; mi < 2; ++mi) {
        #pragma unroll
        for (int ni = 0; ni < 2; ++ni) {
            const int col = n0 + nw + ni * 16 + fr;
            if (col < N) {
                const float bv = bias ? bias[col] : 0.f;
                #pragma unroll
                for (int r = 0; r < 4; ++r) {
                    const int row = m0 + mw + mi * 16 + crow + r;
                    float v = acc[mi][ni][r] + bv;
                    if (relu) v = fmaxf(v, 0.f);
                    if (omode == 0) {
                        C[zoff + (long long)row * N + col] = v;
                    } else if (omode == 1) {
                        ((__hip_bfloat16*)C)[zoff + (long long)row * N + col] = __float2bfloat16(v);
                    } else {
                        ((__hip_bfloat16*)C)[zoff + (long long)col * M + row] = __float2bfloat16(v);
                    }
                }
            }
        }
    }
}

// ---------------- MHA via MFMA: 16 queries/block, S & softmax in registers ----
// qkb: bf16 [b][1024][512] (cols 0-255 Q-proj, 256-511 K-proj)
// vT:  bf16 [b][256 dims][1024 keys]  (head h = dims h*32..h*32+31)
extern "C" __global__ __launch_bounds__(256)
void attn_kernel(const __hip_bfloat16* __restrict__ qkb,
                 const __hip_bfloat16* __restrict__ vT,
                 float* __restrict__ attout) {
    __shared__ __hip_bfloat16 pb[16][1048];    // P bf16, row stride 2096 B (16B mult)
    __shared__ float redm[4][16];
    __shared__ float reds[4][16];
    __shared__ float redo[4][16][33];
    const int t = threadIdx.x;
    const int qt = blockIdx.x, h = blockIdx.y, bb = blockIdx.z;
    const int q0 = qt * 16;
    const int lane = t & 63, wv = t >> 6;
    const int fr = lane & 15, g = lane >> 4;
    const int kbase = wv * 256;
    const float scale = 0.17677669529663687f;  // 1/sqrt(32)

    // Q fragment: A[m = q0+fr][k = g*8 + j]
    bf16x8 qfrag = *(const bf16x8*)(qkb + ((long long)(bb * NQ + q0 + fr)) * 512 + h * HD + g * 8);

    // ---- QK^T: 16 key-tiles of 16 for this wave, S kept in registers ----
    f32x4 sfr[16];
    #pragma unroll
    for (int kt = 0; kt < 16; ++kt) {
        const int key0 = kbase + kt * 16;
        bf16x8 kf = *(const bf16x8*)(qkb + ((long long)(bb * NQ + key0 + fr)) * 512 + 256 + h * HD + g * 8);
        f32x4 z = {0.f, 0.f, 0.f, 0.f};
        sfr[kt] = __builtin_amdgcn_mfma_f32_16x16x32_bf16(qfrag, kf, z, 0, 0, 0);
    }
    #pragma unroll
    for (int kt = 0; kt < 16; ++kt)
        #pragma unroll
        for (int r = 0; r < 4; ++r) sfr[kt][r] *= scale;

    // ---- per-wave row stats (rows 4g+r over this wave's 256 keys) ----
    #pragma unroll
    for (int r = 0; r < 4; ++r) {
        float mx = -1e30f;
        #pragma unroll
        for (int kt = 0; kt < 16; ++kt) mx = fmaxf(mx, sfr[kt][r]);
        #pragma unroll
        for (int mm = 1; mm <= 8; mm <<= 1) mx = fmaxf(mx, __shfl_xor(mx, mm, 64));
        float sm = 0.f;
        #pragma unroll
        for (int kt = 0; kt < 16; ++kt) sm += expf(sfr[kt][r] - mx);
        #pragma unroll
        for (int mm = 1; mm <= 8; mm <<= 1) sm += __shfl_xor(sm, mm, 64);
        if (fr == 0) { redm[wv][4 * g + r] = mx; reds[wv][4 * g + r] = sm; }
    }
    __syncthreads();

    // ---- combine stats, write normalized bf16 P to LDS (own slice only) ----
    float gm[4], gl[4];
    #pragma unroll
    for (int r = 0; r < 4; ++r) {
        const int q = 4 * g + r;
        float mm = fmaxf(fmaxf(redm[0][q], redm[1][q]), fmaxf(redm[2][q], redm[3][q]));
        float ll = 0.f;
        #pragma unroll
        for (int w2 = 0; w2 < 4; ++w2) ll += reds[w2][q] * expf(redm[w2][q] - mm);
        gm[r] = mm; gl[r] = 1.f / ll;
    }
    #pragma unroll
    for (int kt = 0; kt < 16; ++kt) {
        #pragma unroll
        for (int r = 0; r < 4; ++r) {
            float p = expf(sfr[kt][r] - gm[r]) * gl[r];
            pb[4 * g + r][kbase + kt * 16 + fr] = __float2bfloat16(p);
        }
    }

    // ---- P @ V over this wave's key slice (reads only own pb writes) ----
    f32x4 o0 = {0.f, 0.f, 0.f, 0.f}, o1 = {0.f, 0.f, 0.f, 0.f};
    const __hip_bfloat16* vbase = vT + ((long long)bb * DIM + h * HD) * 1024;
    #pragma unroll
    for (int ks = 0; ks < 8; ++ks) {
        const int key0 = kbase + ks * 32 + g * 8;
        bf16x8 pf = *(const bf16x8*)&pb[fr][key0];
        bf16x8 v0 = *(const bf16x8*)(vbase + (long long)fr * 1024 + key0);
        bf16x8 v1 = *(const bf16x8*)(vbase + (long long)(16 + fr) * 1024 + key0);
        o0 = __builtin_amdgcn_mfma_f32_16x16x32_bf16(pf, v0, o0, 0, 0, 0);
        o1 = __builtin_amdgcn_mfma_f32_16x16x32_bf16(pf, v1, o1, 0, 0, 0);
    }

    // ---- cross-wave O reduction ----
    #pragma unroll
    for (int r = 0; r < 4; ++r) {
        redo[wv][4 * g + r][fr] = o0[r];
        redo[wv][4 * g + r][16 + fr] = o1[r];
    }
    __syncthreads();
    #pragma unroll
    for (int i = 0; i < 2; ++i) {
        const int idx = t + i * 256;
        const int q = idx >> 5, d = idx & 31;
        float v = redo[0][q][d] + redo[1][q][d] + redo[2][q][d] + redo[3][q][d];
        attout[((long long)(bb * NQ + q0 + q)) * DIM + h * HD + d] = v;
    }
}

// ---------------- residual + LayerNorm (in-place capable) ----------------
extern "C" __global__ __launch_bounds__(256)
void ln_kernel(const float* __restrict__ X, long long sx,
               const float* __restrict__ R, long long sr,
               const float* __restrict__ g, const float* __restrict__ bta,
               float* __restrict__ O, long long so) {
    __shared__ float red[4];
    const int row = blockIdx.x, bb = blockIdx.y, t = threadIdx.x;
    float x = X[(long long)bb * sx + (long long)row * DIM + t]
            + R[(long long)bb * sr + (long long)row * DIM + t];
    float v = x;
    #pragma unroll
    for (int m = 32; m >= 1; m >>= 1) v += __shfl_xor(v, m, 64);
    if ((t & 63) == 0) red[t >> 6] = v;
    __syncthreads();
    float mean = (red[0] + red[1] + red[2] + red[3]) * (1.f / 256.f);
    __syncthreads();
    float d = x - mean;
    v = d * d;
    #pragma unroll
    for (int m = 32; m >= 1; m >>= 1) v += __shfl_xor(v, m, 64);
    if ((t & 63) == 0) red[t >> 6] = v;
    __syncthreads();
    float var = (red[0] + red[1] + red[2] + red[3]) * (1.f / 256.f);
    O[(long long)bb * so + (long long)row * DIM + t] = d * rsqrtf(var + 1e-5f) * g[t] + bta[t];
}

// ---------------- query = selsrc + selpos ----------------
extern "C" __global__ __launch_bounds__(256)
void addq_kernel(const float* __restrict__ a, const float* __restrict__ b2, float* __restrict__ o) {
    long long i = (long long)blockIdx.x * 256 + threadIdx.x;
    o[i] = a[i] + b2[i];
}

// ---------------- box attention: phase-A geometry to LDS, phase-B pure gather ----
extern "C" __global__ __launch_bounds__(256)
void boxattn_kernel(const float* __restrict__ aw, const float* __restrict__ ob,
                    const float* __restrict__ dgrid, const float* __restrict__ selref,
                    const __hip_bfloat16* __restrict__ vproj, const float* __restrict__ kidx,
                    float* __restrict__ boxout) {
    __shared__ float aw_s[200];
    __shared__ float ob_s[32];
    __shared__ float ref_s[7];
    __shared__ float ki_s[50];
    __shared__ float box_s[8][6];
    __shared__ float mx_s[8];
    __shared__ float inv_s[8];
    __shared__ float wq_s[200];
    __shared__ int   i4_s[800];
    __shared__ float w4_s[800];
    const int t = threadIdx.x;
    const int s = blockIdx.x, bb = blockIdx.y;
    const long long base = (long long)(bb * NSEL + s);
    if (t < 200) aw_s[t] = aw[base * 200 + t];
    if (t < 32)  ob_s[t] = ob[base * 32 + t];
    if (t < 7)   ref_s[t] = selref[base * 7 + t];
    if (t < 50)  ki_s[t] = kidx[t];
    __syncthreads();

    if (t < 8) {
        float mx = -1e30f;
        #pragma unroll
        for (int p = 0; p < NP_; ++p) mx = fmaxf(mx, aw_s[t * NP_ + p]);
        mx_s[t] = mx;
        const float r0 = ref_s[0], r1 = ref_s[1], r3 = ref_s[3], r4 = ref_s[4], r6 = ref_s[6];
        box_s[t][0] = r0 + ob_s[t * 4 + 0] * 0.125f * r3;
        box_s[t][1] = r1 + ob_s[t * 4 + 1] * 0.125f * r4;
        box_s[t][2] = fmaxf(r3 + ob_s[t * 4 + 2] * 0.125f * r3, 0.f);
        box_s[t][3] = fmaxf(r4 + ob_s[t * 4 + 3] * 0.125f * r4, 0.f);
        box_s[t][4] = cosf(r6);
        box_s[t][5] = sinf(r6);
    }
    __syncthreads();

    if (t < 200) {
        const int h = t / NP_, p = t - h * NP_;
        const float w = expf(aw_s[t] - mx_s[h]);
        wq_s[t] = w;
        const float cx = box_s[h][0], cy = box_s[h][1];
        const float sw = box_s[h][2], sh = box_s[h][3];
        const float ca = box_s[h][4], sa = box_s[h][5];
        const float fx = ki_s[p * 2 + 0] * sw;
        const float fy = ki_s[p * 2 + 1] * sh;
        const float gx = cx + ca * fx - sa * fy + dgrid[base * 400 + 2 * t + 0] * (1.f / 188.f);
        const float gy = cy + sa * fx + ca * fy + dgrid[base * 400 + 2 * t + 1] * (1.f / 188.f);
        const float x = gx * 128.f - 0.5f;
        const float y = gy * 128.f - 0.5f;
        const float x0f = floorf(x), y0f = floorf(y);
        const float lx = x - x0f, ly = y - y0f;
        const int x0 = (int)x0f, y0 = (int)y0f;
        #pragma unroll
        for (int c = 0; c < 4; ++c) {
            const int xi = x0 + (c & 1);
            const int yi = y0 + (c >> 1);
            const float wgt = ((c & 1) ? lx : 1.f - lx) * ((c >> 1) ? ly : 1.f - ly);
            const bool valid = (xi >= 0) & (xi < 128) & (yi >= 0) & (yi < 128);
            const int cxi = min(max(xi, 0), 127);
            const int cyi = min(max(yi, 0), 127);
            i4_s[t * 4 + c] = cyi * 128 + cxi;
            w4_s[t * 4 + c] = w * (valid ? wgt : 0.f);
        }
    }
    __syncthreads();
    if (t < 8) {
        float sm = 0.f;
        #pragma unroll
        for (int p = 0; p < NP_; ++p) sm += wq_s[t * NP_ + p];
        inv_s[t] = 1.f / sm;
    }
    __syncthreads();

    const int h = t >> 5, d = t & 31;
    const __hip_bfloat16* vb = vproj + ((long long)bb * HW_N) * DIM + h * HD + d;
    float acc = 0.f;
    for (int p = 0; p < NP_; ++p) {
        const int q = (h * NP_ + p) * 4;
        #pragma unroll
        for (int c = 0; c < 4; ++c) {
            acc += w4_s[q + c] * __bfloat162float(vb[(long long)i4_s[q + c] * DIM]);
        }
    }
    boxout[base * DIM + h * HD + d] = acc * inv_s[h];
}

// ---------------- scatter final rows back into out ----------------
extern "C" __global__ __launch_bounds__(256)
void scatter_kernel(const int* __restrict__ idx, const float* __restrict__ sel,
                    float* __restrict__ out) {
    const int s = blockIdx.x, bb = blockIdx.y, t = threadIdx.x;
    const int i = idx[bb * NSEL + s];
    out[((long long)(bb * HW_N + i)) * DIM + t] = sel[((long long)(bb * NSEL + s)) * DIM + t];
}

extern "C" void kernel_launch(void* const* d_in, const int* in_sizes, int n_in,
                              void* d_out, int out_size, void* d_ws, size_t ws_size,
                              hipStream_t stream) {
    const float* src          = (const float*)d_in[0];
    const float* pos          = (const float*)d_in[1];
    const float* refw         = (const float*)d_in[4];
    const float* score        = (const float*)d_in[5];
    const float* in_proj_w    = (const float*)d_in[6];
    const float* in_proj_b    = (const float*)d_in[7];
    const float* mha_out_w    = (const float*)d_in[8];
    const float* mha_out_b    = (const float*)d_in[9];
    const float* value_proj_w = (const float*)d_in[10];
    const float* value_proj_b = (const float*)d_in[11];
    const float* lin_attn_w   = (const float*)d_in[12];
    const float* lin_attn_b   = (const float*)d_in[13];
    const float* lin_box_w    = (const float*)d_in[14];
    const float* lin_box_b    = (const float*)d_in[15];
    const float* samp_off_w   = (const float*)d_in[16];
    const float* samp_off_b   = (const float*)d_in[17];
    const float* ca_out_w     = (const float*)d_in[18];
    const float* ca_out_b     = (const float*)d_in[19];
    const float* lin1_w       = (const float*)d_in[20];
    const float* lin1_b       = (const float*)d_in[21];
    const float* lin2_w       = (const float*)d_in[22];
    const float* lin2_b       = (const float*)d_in[23];
    const float* qn_g         = (const float*)d_in[24];
    const float* qn_b         = (const float*)d_in[25];
    const float* n1_g         = (const float*)d_in[26];
    const float* n1_b         = (const float*)d_in[27];
    const float* n2_g         = (const float*)d_in[28];
    const float* n2_b         = (const float*)d_in[29];
    const float* kidx         = (const float*)d_in[30];

    float* w = (float*)d_ws;
    int* idxp = (int*)d_ws;
    float* selref = w + OFF_SELREF;
    float* selsrc = w + OFF_SELSRC;
    float* selpos = w + OFF_SELPOS;
    float* boxout = w + OFF_SELPOS;   // reuse after selpos dead
    float* query  = w + OFF_QUERY;
    float* src2   = w + OFF_QUERY;    // reuse after query dead
    __hip_bfloat16* vproj = (__hip_bfloat16*)(w + OFF_BIG);
    float* ffnt   = w + OFF_BIG;      // reuse after vproj dead
    float* qk     = w + OFF_F;
    __hip_bfloat16* qkb = (__hip_bfloat16*)(w + OFF_F + 524288);   // bf16 [b][1024][512]
    __hip_bfloat16* vT  = (__hip_bfloat16*)(w + OFF_F + 1572864);  // bf16 [b][256][1024]
    float* attout = w + OFF_F + 2097152;
    float* q2     = w + OFF_F + 2621440;
    float* aw     = w + OFF_F;              // reuse after MHA dead
    float* obuf   = w + OFF_F + 1638400;
    float* dgrid  = w + OFF_F + 1900544;
    float* ff     = w + OFF_F;              // reuse after box-attn dead
    float* out    = (float*)d_out;

    hipMemcpyAsync(d_out, src, (size_t)2 * HW_N * DIM * sizeof(float),
                   hipMemcpyDeviceToDevice, stream);

    topk_kernel<<<2, 1024, 40960, stream>>>(score, idxp);
    gather_kernel<<<dim3(NSEL, 2), 256, 0, stream>>>(src, pos, refw, idxp,
                                                     selsrc, selpos, selref, qk);
    // MHA projections -> bf16 qkproj and bf16 transposed V
    gemm_kernel<<<dim3(8, 16, 2), 256, 0, stream>>>(qk, 262144LL, in_proj_w, in_proj_b,
                                                    (float*)qkb, 524288LL, NQ, 512, 256, 0, 1);
    gemm_kernel<<<dim3(4, 16, 2), 256, 0, stream>>>(selsrc, 1048576LL, in_proj_w + 512 * 256,
                                                    in_proj_b + 512, (float*)vT, 262144LL, NQ, 256, 256, 0, 2);
    attn_kernel<<<dim3(64, 8, 2), 256, 0, stream>>>(qkb, vT, attout);
    gemm_kernel<<<dim3(4, 16, 2), 256, 0, stream>>>(attout, 262144LL, mha_out_w, mha_out_b,
                                                    q2, 262144LL, NQ, 256, 256, 0, 0);
    ln_kernel<<<dim3(NQ, 2), 256, 0, stream>>>(selsrc, 1048576LL, q2, 262144LL,
                                               qn_g, qn_b, selsrc, 1048576LL);
    addq_kernel<<<8192, 256, 0, stream>>>(selsrc, selpos, query);
    gemm_kernel<<<dim3(4, 256, 2), 256, 0, stream>>>(src, 4194304LL, value_proj_w, value_proj_b,
                                                     (float*)vproj, 4194304LL, HW_N, 256, 256, 0, 1);
    gemm_kernel<<<dim3(4, 64, 2), 256, 0, stream>>>(query, 1048576LL, lin_attn_w, lin_attn_b,
                                                    aw, 819200LL, NSEL, 200, 256, 0, 0);
    gemm_kernel<<<dim3(1, 64, 2), 256, 0, stream>>>(query, 1048576LL, lin_box_w, lin_box_b,
                                                    obuf, 131072LL, NSEL, 32, 256, 0, 0);
    gemm_kernel<<<dim3(7, 64, 2), 256, 0, stream>>>(query, 1048576LL, samp_off_w, samp_off_b,
                                                    dgrid, 1638400LL, NSEL, 400, 256, 0, 0);
    boxattn_kernel<<<dim3(NSEL, 2), 256, 0, stream>>>(aw, obuf, dgrid, selref, vproj, kidx, boxout);
    gemm_kernel<<<dim3(4, 64, 2), 256, 0, stream>>>(boxout, 1048576LL, ca_out_w, ca_out_b,
                                                    src2, 1048576LL, NSEL, 256, 256, 0, 0);
    ln_kernel<<<dim3(NSEL, 2), 256, 0, stream>>>(selsrc, 1048576LL, src2, 1048576LL,
                                                 n1_g, n1_b, selsrc, 1048576LL);
    gemm_kernel<<<dim3(16, 64, 2), 256, 0, stream>>>(selsrc, 1048576LL, lin1_w, lin1_b,
                                                     ffnt, 4194304LL, NSEL, DFF_, 256, 1, 0);
    gemm_kernel<<<dim3(4, 64, 2), 256, 0, stream>>>(ffnt, 4194304LL, lin2_w, lin2_b,
                                                    ff, 1048576LL, NSEL, 256, DFF_, 0, 0);
    ln_kernel<<<dim3(NSEL, 2), 256, 0, stream>>>(selsrc, 1048576LL, ff, 1048576LL,
                                                 n2_g, n2_b, selsrc, 1048576LL);
    scatter_kernel<<<dim3(NSEL, 2), 256, 0, stream>>>(idxp, selsrc, out);
}

// Round 6
// 479.601 us; speedup vs baseline: 2.2352x; 1.0800x over previous
//
#include <hip/hip_runtime.h>
#include <hip/hip_bf16.h>
#include <math.h>

// Problem constants
#define HW_N   16384
#define DIM    256
#define NSEL   4096
#define NQ     1024
#define NHEAD  8
#define HD     32
#define NP_    25
#define DFF_   1024

// Workspace layout (float offsets). Total ~19.93M floats ~= 76 MB.
#define OFF_SELREF  8448LL          // 2*4096*7
#define OFF_SELSRC  65792LL         // 2*4096*256
#define OFF_SELPOS  2162944LL       // 2*4096*256 (later reused as boxout)
#define OFF_QUERY   4260096LL       // 2*4096*256 (later reused as src2)
#define OFF_BIG     6357248LL       // 2*16384*256 (vproj bf16, later ffn hidden fp32)
#define OFF_F       14745856LL      // multi-use region, 5177344 floats

__device__ __forceinline__ unsigned int f2s(float f) {
    unsigned int u = __float_as_uint(f);
    return (u & 0x80000000u) ? ~u : (u | 0x80000000u);
}

// ================= top-k, grid-parallel (4 kernels) =================
// Scratch (u32 view at w+OFF_F): hist[2][8192]; ctrl[2][16]
// (T1,need1,T2,need2,c1,c2,cntA,cntB); then u64 list1[2][2048], list2[2][2048].
// Exactness: groups are the exact jax top-1024 / top-4096 SETS (key order
// (value, lower idx)); slot order within each group is arbitrary, which is
// safe because downstream is permutation-equivariant within groups.

extern "C" __global__ __launch_bounds__(512)
void topk_hist_kernel(const float* __restrict__ score, unsigned int* __restrict__ hist) {
    const int t = threadIdx.x, bx = blockIdx.x, bb = blockIdx.y;
    const int i = bx * 512 + t;
    unsigned int u = f2s(score[(long long)bb * HW_N + i]);
    atomicAdd(&hist[bb * 8192 + (u >> 19)], 1u);
}

extern "C" __global__ __launch_bounds__(1024)
void topk_scan_kernel(const unsigned int* __restrict__ hist, unsigned int* __restrict__ ctrl) {
    __shared__ unsigned int scan[1024];
    const int t = threadIdx.x, bb = blockIdx.x;
    unsigned int loc[8]; unsigned int lsum = 0u;
    #pragma unroll
    for (int k = 0; k < 8; ++k) { loc[k] = hist[bb * 8192 + t * 8 + k]; lsum += loc[k]; }
    scan[t] = lsum;
    __syncthreads();
    for (int off = 1; off < 1024; off <<= 1) {
        unsigned int v = (t + off < 1024) ? scan[t + off] : 0u;
        __syncthreads();
        scan[t] += v;
        __syncthreads();
    }
    unsigned int nxt = (t < 1023) ? scan[t + 1] : 0u;
    unsigned int run = nxt;
    for (int k = 7; k >= 0; --k) {
        run += loc[k];                       // suffix(8t+k)
        unsigned int above = run - loc[k];   // suffix(8t+k+1)
        if (run >= 1024u && above < 1024u) { ctrl[bb * 16 + 0] = (unsigned)(t * 8 + k); ctrl[bb * 16 + 1] = 1024u - above; }
        if (run >= 4096u && above < 4096u) { ctrl[bb * 16 + 2] = (unsigned)(t * 8 + k); ctrl[bb * 16 + 3] = 4096u - above; }
    }
}

extern "C" __global__ __launch_bounds__(1024)
void topk_collect_kernel(const float* __restrict__ score, unsigned int* __restrict__ ctrl,
                         unsigned long long* __restrict__ list1,
                         unsigned long long* __restrict__ list2) {
    const int t = threadIdx.x, bx = blockIdx.x, bb = blockIdx.y;
    const int i = bx * 1024 + t;
    const unsigned int T1 = ctrl[bb * 16 + 0], T2 = ctrl[bb * 16 + 2];
    unsigned int u = f2s(score[(long long)bb * HW_N + i]);
    unsigned int bin = u >> 19;
    unsigned long long key = ((unsigned long long)u << 32) | (unsigned int)(~(unsigned int)i);
    if (bin == T1) {
        unsigned int p = atomicAdd(&ctrl[bb * 16 + 4], 1u);
        if (p < 2048u) list1[bb * 2048 + p] = key;
    }
    if (bin == T2 && T2 != T1) {
        unsigned int p = atomicAdd(&ctrl[bb * 16 + 5], 1u);
        if (p < 2048u) list2[bb * 2048 + p] = key;
    }
}

extern "C" __global__ __launch_bounds__(1024)
void topk_classify_kernel(const float* __restrict__ score, unsigned int* __restrict__ ctrl,
                          const unsigned long long* __restrict__ list1,
                          const unsigned long long* __restrict__ list2,
                          int* __restrict__ idx_out) {
    __shared__ unsigned int cA, cB, baseA, baseB;
    const int t = threadIdx.x, bx = blockIdx.x, bb = blockIdx.y;
    const int i = bx * 1024 + t;
    if (t == 0) { cA = 0u; cB = 0u; }
    __syncthreads();
    const unsigned int T1 = ctrl[bb * 16 + 0], need1 = ctrl[bb * 16 + 1];
    const unsigned int T2 = ctrl[bb * 16 + 2], need2 = ctrl[bb * 16 + 3];
    const unsigned int c1 = min(ctrl[bb * 16 + 4], 2048u);
    const unsigned int c2 = min(ctrl[bb * 16 + 5], 2048u);
    unsigned int u = f2s(score[(long long)bb * HW_N + i]);
    unsigned int bin = u >> 19;
    unsigned long long key = ((unsigned long long)u << 32) | (unsigned int)(~(unsigned int)i);
    bool inA = false, inB = false;
    if (bin > T1) {
        inA = true;
    } else if (bin == T1) {
        unsigned int r = 0;
        for (unsigned int q = 0; q < c1; ++q) r += (list1[bb * 2048 + q] > key) ? 1u : 0u;
        if (r < need1) inA = true;
        else if (T2 == T1) inB = (r < need2);
        else inB = true;
    } else if (bin > T2) {
        inB = true;
    } else if (bin == T2) {
        unsigned int r = 0;
        for (unsigned int q = 0; q < c2; ++q) r += (list2[bb * 2048 + q] > key) ? 1u : 0u;
        inB = (r < need2);
    }
    unsigned int sA = 0u, sB = 0u;
    if (inA) sA = atomicAdd(&cA, 1u);
    if (inB) sB = atomicAdd(&cB, 1u);
    __syncthreads();
    if (t == 0) {
        baseA = atomicAdd(&ctrl[bb * 16 + 6], cA);
        baseB = atomicAdd(&ctrl[bb * 16 + 7], cB);
    }
    __syncthreads();
    if (inA) idx_out[bb * NSEL + baseA + sA] = i;
    if (inB) idx_out[bb * NSEL + 1024 + baseB + sB] = i;
}

// ---------------- gather selected rows ----------------
extern "C" __global__ __launch_bounds__(256)
void gather_kernel(const float* __restrict__ src, const float* __restrict__ pos,
                   const float* __restrict__ refw, const int* __restrict__ idx,
                   float* __restrict__ selsrc, float* __restrict__ selpos,
                   float* __restrict__ selref, float* __restrict__ qk) {
    const int s = blockIdx.x, bb = blockIdx.y, t = threadIdx.x;
    const int i = idx[bb * NSEL + s];
    const long long so = ((long long)(bb * NSEL + s)) * DIM;
    const long long go = ((long long)(bb * HW_N + i)) * DIM;
    float sv = src[go + t], pv = pos[go + t];
    selsrc[so + t] = sv;
    selpos[so + t] = pv;
    if (s < NQ) qk[((long long)(bb * NQ + s)) * DIM + t] = sv + pv;
    if (t < 7)
        selref[(long long)(bb * NSEL + s) * 7 + t] = refw[(long long)(bb * HW_N + i) * 7 + t];
}

// ---------------- bf16 MFMA GEMM: C = act(A @ W^T + bias) ----------------
// omode: 0 = fp32 out; 1 = bf16 out (flat); 2 = bf16 out TRANSPOSED (col*M+row).
typedef __bf16 bf16x8 __attribute__((ext_vector_type(8)));
typedef float  f32x4  __attribute__((ext_vector_type(4)));

extern "C" __global__ __launch_bounds__(256)
void gemm_kernel(const float* __restrict__ A, long long sA,
                 const float* __restrict__ W, const float* __restrict__ bias,
                 float* __restrict__ C, long long sC,
                 int M, int N, int K, int relu, int omode) {
    __shared__ __hip_bfloat16 As[64][72];
    __shared__ __hip_bfloat16 Ws[64][72];
    const int t = threadIdx.x;
    const int n0 = blockIdx.x * 64, m0 = blockIdx.y * 64;
    const float* Ab = A + (long long)blockIdx.z * sA;
    const long long zoff = (long long)blockIdx.z * sC;
    const int lane = t & 63, wv = t >> 6;
    const int mw = (wv >> 1) * 32, nw = (wv & 1) * 32;
    const int fr = lane & 15;
    const int fk = (lane >> 4) * 8;
    const int sr = t >> 2;
    const int sk = (t & 3) * 16;

    f32x4 acc[2][2];
    #pragma unroll
    for (int i = 0; i < 2; ++i)
        #pragma unroll
        for (int j = 0; j < 2; ++j) acc[i][j] = {0.f, 0.f, 0.f, 0.f};

    const bool wok = (n0 + sr) < N;
    for (int k0 = 0; k0 < K; k0 += 64) {
        const float* ap = Ab + (long long)(m0 + sr) * K + k0 + sk;
        float av[16];
        #pragma unroll
        for (int q = 0; q < 4; ++q) {
            float4 v = *(const float4*)(ap + q * 4);
            av[q * 4 + 0] = v.x; av[q * 4 + 1] = v.y; av[q * 4 + 2] = v.z; av[q * 4 + 3] = v.w;
        }
        float wvv[16];
        if (wok) {
            const float* wp = W + (long long)(n0 + sr) * K + k0 + sk;
            #pragma unroll
            for (int q = 0; q < 4; ++q) {
                float4 v = *(const float4*)(wp + q * 4);
                wvv[q * 4 + 0] = v.x; wvv[q * 4 + 1] = v.y; wvv[q * 4 + 2] = v.z; wvv[q * 4 + 3] = v.w;
            }
        } else {
            #pragma unroll
            for (int q = 0; q < 16; ++q) wvv[q] = 0.f;
        }
        __syncthreads();
        #pragma unroll
        for (int q = 0; q < 16; ++q) {
            As[sr][sk + q] = __float2bfloat16(av[q]);
            Ws[sr][sk + q] = __float2bfloat16(wvv[q]);
        }
        __syncthreads();
        #pragma unroll
        for (int kk = 0; kk < 64; kk += 32) {
            bf16x8 a0 = *(const bf16x8*)&As[mw + fr][kk + fk];
            bf16x8 a1 = *(const bf16x8*)&As[mw + 16 + fr][kk + fk];
            bf16x8 b0 = *(const bf16x8*)&Ws[nw + fr][kk + fk];
            bf16x8 b1 = *(const bf16x8*)&Ws[nw + 16 + fr][kk + fk];
            acc[0][0] = __builtin_amdgcn_mfma_f32_16x16x32_bf16(a0, b0, acc[0][0], 0, 0, 0);
            acc[0][1] = __builtin_amdgcn_mfma_f32_16x16x32_bf16(a0, b1, acc[0][1], 0, 0, 0);
            acc[1][0] = __builtin_amdgcn_mfma_f32_16x16x32_bf16(a1, b0, acc[1][0], 0, 0, 0);
            acc[1][1] = __builtin_amdgcn_mfma_f32_16x16x32_bf16(a1, b1, acc[1][1], 0, 0, 0);
        }
    }
    const int crow = (lane >> 4) * 4;
    #pragma unroll
    for (int mi = 0; mi < 2; ++mi) {
        #pragma unroll
        for (int ni = 0; ni < 2; ++ni) {
            const int col = n0 + nw + ni * 16 + fr;
            if (col < N) {
                const float bv = bias ? bias[col] : 0.f;
                #pragma unroll
                for (int r = 0; r < 4; ++r) {
                    const int row = m0 + mw + mi * 16 + crow + r;
                    float v = acc[mi][ni][r] + bv;
                    if (relu) v = fmaxf(v, 0.f);
                    if (omode == 0) {
                        C[zoff + (long long)row * N + col] = v;
                    } else if (omode == 1) {
                        ((__hip_bfloat16*)C)[zoff + (long long)row * N + col] = __float2bfloat16(v);
                    } else {
                        ((__hip_bfloat16*)C)[zoff + (long long)col * M + row] = __float2bfloat16(v);
                    }
                }
            }
        }
    }
}

// ---------------- MHA via MFMA: 16 queries/block, S & softmax in registers ----
extern "C" __global__ __launch_bounds__(256)
void attn_kernel(const __hip_bfloat16* __restrict__ qkb,
                 const __hip_bfloat16* __restrict__ vT,
                 float* __restrict__ attout) {
    __shared__ __hip_bfloat16 pb[16][1048];
    __shared__ float redm[4][16];
    __shared__ float reds[4][16];
    __shared__ float redo[4][16][33];
    const int t = threadIdx.x;
    const int qt = blockIdx.x, h = blockIdx.y, bb = blockIdx.z;
    const int q0 = qt * 16;
    const int lane = t & 63, wv = t >> 6;
    const int fr = lane & 15, g = lane >> 4;
    const int kbase = wv * 256;
    const float scale = 0.17677669529663687f;

    bf16x8 qfrag = *(const bf16x8*)(qkb + ((long long)(bb * NQ + q0 + fr)) * 512 + h * HD + g * 8);

    f32x4 sfr[16];
    #pragma unroll
    for (int kt = 0; kt < 16; ++kt) {
        const int key0 = kbase + kt * 16;
        bf16x8 kf = *(const bf16x8*)(qkb + ((long long)(bb * NQ + key0 + fr)) * 512 + 256 + h * HD + g * 8);
        f32x4 z = {0.f, 0.f, 0.f, 0.f};
        sfr[kt] = __builtin_amdgcn_mfma_f32_16x16x32_bf16(qfrag, kf, z, 0, 0, 0);
    }
    #pragma unroll
    for (int kt = 0; kt < 16; ++kt)
        #pragma unroll
        for (int r = 0; r < 4; ++r) sfr[kt][r] *= scale;

    #pragma unroll
    for (int r = 0; r < 4; ++r) {
        float mx = -1e30f;
        #pragma unroll
        for (int kt = 0; kt < 16; ++kt) mx = fmaxf(mx, sfr[kt][r]);
        #pragma unroll
        for (int mm = 1; mm <= 8; mm <<= 1) mx = fmaxf(mx, __shfl_xor(mx, mm, 64));
        float sm = 0.f;
        #pragma unroll
        for (int kt = 0; kt < 16; ++kt) sm += expf(sfr[kt][r] - mx);
        #pragma unroll
        for (int mm = 1; mm <= 8; mm <<= 1) sm += __shfl_xor(sm, mm, 64);
        if (fr == 0) { redm[wv][4 * g + r] = mx; reds[wv][4 * g + r] = sm; }
    }
    __syncthreads();

    float gm[4], gl[4];
    #pragma unroll
    for (int r = 0; r < 4; ++r) {
        const int q = 4 * g + r;
        float mm = fmaxf(fmaxf(redm[0][q], redm[1][q]), fmaxf(redm[2][q], redm[3][q]));
        float ll = 0.f;
        #pragma unroll
        for (int w2 = 0; w2 < 4; ++w2) ll += reds[w2][q] * expf(redm[w2][q] - mm);
        gm[r] = mm; gl[r] = 1.f / ll;
    }
    #pragma unroll
    for (int kt = 0; kt < 16; ++kt) {
        #pragma unroll
        for (int r = 0; r < 4; ++r) {
            float p = expf(sfr[kt][r] - gm[r]) * gl[r];
            pb[4 * g + r][kbase + kt * 16 + fr] = __float2bfloat16(p);
        }
    }

    f32x4 o0 = {0.f, 0.f, 0.f, 0.f}, o1 = {0.f, 0.f, 0.f, 0.f};
    const __hip_bfloat16* vbase = vT + ((long long)bb * DIM + h * HD) * 1024;
    #pragma unroll
    for (int ks = 0; ks < 8; ++ks) {
        const int key0 = kbase + ks * 32 + g * 8;
        bf16x8 pf = *(const bf16x8*)&pb[fr][key0];
        bf16x8 v0 = *(const bf16x8*)(vbase + (long long)fr * 1024 + key0);
        bf16x8 v1 = *(const bf16x8*)(vbase + (long long)(16 + fr) * 1024 + key0);
        o0 = __builtin_amdgcn_mfma_f32_16x16x32_bf16(pf, v0, o0, 0, 0, 0);
        o1 = __builtin_amdgcn_mfma_f32_16x16x32_bf16(pf, v1, o1, 0, 0, 0);
    }

    #pragma unroll
    for (int r = 0; r < 4; ++r) {
        redo[wv][4 * g + r][fr] = o0[r];
        redo[wv][4 * g + r][16 + fr] = o1[r];
    }
    __syncthreads();
    #pragma unroll
    for (int i = 0; i < 2; ++i) {
        const int idx = t + i * 256;
        const int q = idx >> 5, d = idx & 31;
        float v = redo[0][q][d] + redo[1][q][d] + redo[2][q][d] + redo[3][q][d];
        attout[((long long)(bb * NQ + q0 + q)) * DIM + h * HD + d] = v;
    }
}

// ---------------- residual + LayerNorm (in-place capable) ----------------
extern "C" __global__ __launch_bounds__(256)
void ln_kernel(const float* __restrict__ X, long long sx,
               const float* __restrict__ R, long long sr,
               const float* __restrict__ g, const float* __restrict__ bta,
               float* __restrict__ O, long long so) {
    __shared__ float red[4];
    const int row = blockIdx.x, bb = blockIdx.y, t = threadIdx.x;
    float x = X[(long long)bb * sx + (long long)row * DIM + t]
            + R[(long long)bb * sr + (long long)row * DIM + t];
    float v = x;
    #pragma unroll
    for (int m = 32; m >= 1; m >>= 1) v += __shfl_xor(v, m, 64);
    if ((t & 63) == 0) red[t >> 6] = v;
    __syncthreads();
    float mean = (red[0] + red[1] + red[2] + red[3]) * (1.f / 256.f);
    __syncthreads();
    float d = x - mean;
    v = d * d;
    #pragma unroll
    for (int m = 32; m >= 1; m >>= 1) v += __shfl_xor(v, m, 64);
    if ((t & 63) == 0) red[t >> 6] = v;
    __syncthreads();
    float var = (red[0] + red[1] + red[2] + red[3]) * (1.f / 256.f);
    O[(long long)bb * so + (long long)row * DIM + t] = d * rsqrtf(var + 1e-5f) * g[t] + bta[t];
}

// ---------------- query = selsrc + selpos ----------------
extern "C" __global__ __launch_bounds__(256)
void addq_kernel(const float* __restrict__ a, const float* __restrict__ b2, float* __restrict__ o) {
    long long i = (long long)blockIdx.x * 256 + threadIdx.x;
    o[i] = a[i] + b2[i];
}

// ---------------- box attention: phase-A geometry to LDS, phase-B pure gather ----
extern "C" __global__ __launch_bounds__(256)
void boxattn_kernel(const float* __restrict__ aw, const float* __restrict__ ob,
                    const float* __restrict__ dgrid, const float* __restrict__ selref,
                    const __hip_bfloat16* __restrict__ vproj, const float* __restrict__ kidx,
                    float* __restrict__ boxout) {
    __shared__ float aw_s[200];
    __shared__ float ob_s[32];
    __shared__ float ref_s[7];
    __shared__ float ki_s[50];
    __shared__ float box_s[8][6];
    __shared__ float mx_s[8];
    __shared__ float inv_s[8];
    __shared__ float wq_s[200];
    __shared__ int   i4_s[800];
    __shared__ float w4_s[800];
    const int t = threadIdx.x;
    const int s = blockIdx.x, bb = blockIdx.y;
    const long long base = (long long)(bb * NSEL + s);
    if (t < 200) aw_s[t] = aw[base * 200 + t];
    if (t < 32)  ob_s[t] = ob[base * 32 + t];
    if (t < 7)   ref_s[t] = selref[base * 7 + t];
    if (t < 50)  ki_s[t] = kidx[t];
    __syncthreads();

    if (t < 8) {
        float mx = -1e30f;
        #pragma unroll
        for (int p = 0; p < NP_; ++p) mx = fmaxf(mx, aw_s[t * NP_ + p]);
        mx_s[t] = mx;
        const float r0 = ref_s[0], r1 = ref_s[1], r3 = ref_s[3], r4 = ref_s[4], r6 = ref_s[6];
        box_s[t][0] = r0 + ob_s[t * 4 + 0] * 0.125f * r3;
        box_s[t][1] = r1 + ob_s[t * 4 + 1] * 0.125f * r4;
        box_s[t][2] = fmaxf(r3 + ob_s[t * 4 + 2] * 0.125f * r3, 0.f);
        box_s[t][3] = fmaxf(r4 + ob_s[t * 4 + 3] * 0.125f * r4, 0.f);
        box_s[t][4] = cosf(r6);
        box_s[t][5] = sinf(r6);
    }
    __syncthreads();

    if (t < 200) {
        const int h = t / NP_, p = t - h * NP_;
        const float w = expf(aw_s[t] - mx_s[h]);
        wq_s[t] = w;
        const float cx = box_s[h][0], cy = box_s[h][1];
        const float sw = box_s[h][2], sh = box_s[h][3];
        const float ca = box_s[h][4], sa = box_s[h][5];
        const float fx = ki_s[p * 2 + 0] * sw;
        const float fy = ki_s[p * 2 + 1] * sh;
        const float gx = cx + ca * fx - sa * fy + dgrid[base * 400 + 2 * t + 0] * (1.f / 188.f);
        const float gy = cy + sa * fx + ca * fy + dgrid[base * 400 + 2 * t + 1] * (1.f / 188.f);
        const float x = gx * 128.f - 0.5f;
        const float y = gy * 128.f - 0.5f;
        const float x0f = floorf(x), y0f = floorf(y);
        const float lx = x - x0f, ly = y - y0f;
        const int x0 = (int)x0f, y0 = (int)y0f;
        #pragma unroll
        for (int c = 0; c < 4; ++c) {
            const int xi = x0 + (c & 1);
            const int yi = y0 + (c >> 1);
            const float wgt = ((c & 1) ? lx : 1.f - lx) * ((c >> 1) ? ly : 1.f - ly);
            const bool valid = (xi >= 0) & (xi < 128) & (yi >= 0) & (yi < 128);
            const int cxi = min(max(xi, 0), 127);
            const int cyi = min(max(yi, 0), 127);
            i4_s[t * 4 + c] = cyi * 128 + cxi;
            w4_s[t * 4 + c] = w * (valid ? wgt : 0.f);
        }
    }
    __syncthreads();
    if (t < 8) {
        float sm = 0.f;
        #pragma unroll
        for (int p = 0; p < NP_; ++p) sm += wq_s[t * NP_ + p];
        inv_s[t] = 1.f / sm;
    }
    __syncthreads();

    const int h = t >> 5, d = t & 31;
    const __hip_bfloat16* vb = vproj + ((long long)bb * HW_N) * DIM + h * HD + d;
    float acc = 0.f;
    for (int p = 0; p < NP_; ++p) {
        const int q = (h * NP_ + p) * 4;
        #pragma unroll
        for (int c = 0; c < 4; ++c) {
            acc += w4_s[q + c] * __bfloat162float(vb[(long long)i4_s[q + c] * DIM]);
        }
    }
    boxout[base * DIM + h * HD + d] = acc * inv_s[h];
}

// ---------------- scatter final rows back into out ----------------
extern "C" __global__ __launch_bounds__(256)
void scatter_kernel(const int* __restrict__ idx, const float* __restrict__ sel,
                    float* __restrict__ out) {
    const int s = blockIdx.x, bb = blockIdx.y, t = threadIdx.x;
    const int i = idx[bb * NSEL + s];
    out[((long long)(bb * HW_N + i)) * DIM + t] = sel[((long long)(bb * NSEL + s)) * DIM + t];
}

extern "C" void kernel_launch(void* const* d_in, const int* in_sizes, int n_in,
                              void* d_out, int out_size, void* d_ws, size_t ws_size,
                              hipStream_t stream) {
    const float* src          = (const float*)d_in[0];
    const float* pos          = (const float*)d_in[1];
    const float* refw         = (const float*)d_in[4];
    const float* score        = (const float*)d_in[5];
    const float* in_proj_w    = (const float*)d_in[6];
    const float* in_proj_b    = (const float*)d_in[7];
    const float* mha_out_w    = (const float*)d_in[8];
    const float* mha_out_b    = (const float*)d_in[9];
    const float* value_proj_w = (const float*)d_in[10];
    const float* value_proj_b = (const float*)d_in[11];
    const float* lin_attn_w   = (const float*)d_in[12];
    const float* lin_attn_b   = (const float*)d_in[13];
    const float* lin_box_w    = (const float*)d_in[14];
    const float* lin_box_b    = (const float*)d_in[15];
    const float* samp_off_w   = (const float*)d_in[16];
    const float* samp_off_b   = (const float*)d_in[17];
    const float* ca_out_w     = (const float*)d_in[18];
    const float* ca_out_b     = (const float*)d_in[19];
    const float* lin1_w       = (const float*)d_in[20];
    const float* lin1_b       = (const float*)d_in[21];
    const float* lin2_w       = (const float*)d_in[22];
    const float* lin2_b       = (const float*)d_in[23];
    const float* qn_g         = (const float*)d_in[24];
    const float* qn_b         = (const float*)d_in[25];
    const float* n1_g         = (const float*)d_in[26];
    const float* n1_b         = (const float*)d_in[27];
    const float* n2_g         = (const float*)d_in[28];
    const float* n2_b         = (const float*)d_in[29];
    const float* kidx         = (const float*)d_in[30];

    float* w = (float*)d_ws;
    int* idxp = (int*)d_ws;
    float* selref = w + OFF_SELREF;
    float* selsrc = w + OFF_SELSRC;
    float* selpos = w + OFF_SELPOS;
    float* boxout = w + OFF_SELPOS;   // reuse after selpos dead
    float* query  = w + OFF_QUERY;
    float* src2   = w + OFF_QUERY;    // reuse after query dead
    __hip_bfloat16* vproj = (__hip_bfloat16*)(w + OFF_BIG);
    float* ffnt   = w + OFF_BIG;      // reuse after vproj dead
    float* qk     = w + OFF_F;
    __hip_bfloat16* qkb = (__hip_bfloat16*)(w + OFF_F + 524288);
    __hip_bfloat16* vT  = (__hip_bfloat16*)(w + OFF_F + 1572864);
    float* attout = w + OFF_F + 2097152;
    float* q2     = w + OFF_F + 2621440;
    float* aw     = w + OFF_F;              // reuse after MHA dead
    float* obuf   = w + OFF_F + 1638400;
    float* dgrid  = w + OFF_F + 1900544;
    float* ff     = w + OFF_F;              // reuse after box-attn dead
    // topk scratch (dead before gather writes qk at OFF_F)
    unsigned int* hist2 = (unsigned int*)(w + OFF_F);
    unsigned int* ctrl2 = hist2 + 16384;
    unsigned long long* list1 = (unsigned long long*)(hist2 + 16448);
    unsigned long long* list2 = list1 + 2 * 2048;
    float* out    = (float*)d_out;

    hipMemcpyAsync(d_out, src, (size_t)2 * HW_N * DIM * sizeof(float),
                   hipMemcpyDeviceToDevice, stream);

    hipMemsetAsync(hist2, 0, 16448 * sizeof(unsigned int), stream);
    topk_hist_kernel<<<dim3(32, 2), 512, 0, stream>>>(score, hist2);
    topk_scan_kernel<<<2, 1024, 0, stream>>>(hist2, ctrl2);
    topk_collect_kernel<<<dim3(16, 2), 1024, 0, stream>>>(score, ctrl2, list1, list2);
    topk_classify_kernel<<<dim3(16, 2), 1024, 0, stream>>>(score, ctrl2, list1, list2, idxp);

    gather_kernel<<<dim3(NSEL, 2), 256, 0, stream>>>(src, pos, refw, idxp,
                                                     selsrc, selpos, selref, qk);
    gemm_kernel<<<dim3(8, 16, 2), 256, 0, stream>>>(qk, 262144LL, in_proj_w, in_proj_b,
                                                    (float*)qkb, 524288LL, NQ, 512, 256, 0, 1);
    gemm_kernel<<<dim3(4, 16, 2), 256, 0, stream>>>(selsrc, 1048576LL, in_proj_w + 512 * 256,
                                                    in_proj_b + 512, (float*)vT, 262144LL, NQ, 256, 256, 0, 2);
    attn_kernel<<<dim3(64, 8, 2), 256, 0, stream>>>(qkb, vT, attout);
    gemm_kernel<<<dim3(4, 16, 2), 256, 0, stream>>>(attout, 262144LL, mha_out_w, mha_out_b,
                                                    q2, 262144LL, NQ, 256, 256, 0, 0);
    ln_kernel<<<dim3(NQ, 2), 256, 0, stream>>>(selsrc, 1048576LL, q2, 262144LL,
                                               qn_g, qn_b, selsrc, 1048576LL);
    addq_kernel<<<8192, 256, 0, stream>>>(selsrc, selpos, query);
    gemm_kernel<<<dim3(4, 256, 2), 256, 0, stream>>>(src, 4194304LL, value_proj_w, value_proj_b,
                                                     (float*)vproj, 4194304LL, HW_N, 256, 256, 0, 1);
    gemm_kernel<<<dim3(4, 64, 2), 256, 0, stream>>>(query, 1048576LL, lin_attn_w, lin_attn_b,
                                                    aw, 819200LL, NSEL, 200, 256, 0, 0);
    gemm_kernel<<<dim3(1, 64, 2), 256, 0, stream>>>(query, 1048576LL, lin_box_w, lin_box_b,
                                                    obuf, 131072LL, NSEL, 32, 256, 0, 0);
    gemm_kernel<<<dim3(7, 64, 2), 256, 0, stream>>>(query, 1048576LL, samp_off_w, samp_off_b,
                                                    dgrid, 1638400LL, NSEL, 400, 256, 0, 0);
    boxattn_kernel<<<dim3(NSEL, 2), 256, 0, stream>>>(aw, obuf, dgrid, selref, vproj, kidx, boxout);
    gemm_kernel<<<dim3(4, 64, 2), 256, 0, stream>>>(boxout, 1048576LL, ca_out_w, ca_out_b,
                                                    src2, 1048576LL, NSEL, 256, 256, 0, 0);
    ln_kernel<<<dim3(NSEL, 2), 256, 0, stream>>>(selsrc, 1048576LL, src2, 1048576LL,
                                                 n1_g, n1_b, selsrc, 1048576LL);
    gemm_kernel<<<dim3(16, 64, 2), 256, 0, stream>>>(selsrc, 1048576LL, lin1_w, lin1_b,
                                                     ffnt, 4194304LL, NSEL, DFF_, 256, 1, 0);
    gemm_kernel<<<dim3(4, 64, 2), 256, 0, stream>>>(ffnt, 4194304LL, lin2_w, lin2_b,
                                                    ff, 1048576LL, NSEL, 256, DFF_, 0, 0);
    ln_kernel<<<dim3(NSEL, 2), 256, 0, stream>>>(selsrc, 1048576LL, ff, 1048576LL,
                                                 n2_g, n2_b, selsrc, 1048576LL);
    scatter_kernel<<<dim3(NSEL, 2), 256, 0, stream>>>(idxp, selsrc, out);
}

// Round 7
// 457.854 us; speedup vs baseline: 2.3414x; 1.0475x over previous
//
#include <hip/hip_runtime.h>
#include <hip/hip_bf16.h>
#include <math.h>

// Problem constants
#define HW_N   16384
#define DIM    256
#define NSEL   4096
#define NQ     1024
#define NHEAD  8
#define HD     32
#define NP_    25
#define DFF_   1024

// Workspace layout (float offsets). ~76 MB total.
#define OFF_SELREF  8448LL          // 2*4096*7
#define OFF_SELSRC  65792LL         // 2*4096*256
#define OFF_SELPOS  2162944LL       // 2*4096*256 (later reused as boxout)
#define OFF_QUERY   4260096LL       // 2*4096*256 (later reused as src2)
#define OFF_BIG     6357248LL       // vproj bf16 [0,4194304) then ffnt bf16 same slot
#define OFF_WBF     10551552LL      // OFF_BIG+4194304: bf16 weights, 1079296 bf16
#define OFF_F       14745856LL      // multi-use region, 5177344 floats

__device__ __forceinline__ unsigned int f2s(float f) {
    unsigned int u = __float_as_uint(f);
    return (u & 0x80000000u) ? ~u : (u | 0x80000000u);
}

typedef __bf16 bf16x8 __attribute__((ext_vector_type(8)));
typedef __bf16 bf16x4 __attribute__((ext_vector_type(4)));
typedef float  f32x4  __attribute__((ext_vector_type(4)));

// ============ weight preconversion: 9 fp32 matrices -> one bf16 pool ============
// Segments (elems): in_proj 196608 | mha_out 65536 | value 65536 | lin_attn 51200
// | lin_box 8192 | samp_off 102400 | ca_out 65536 | lin1 262144 | lin2 262144
extern "C" __global__ __launch_bounds__(256)
void wcvt_kernel(const float* __restrict__ s0, const float* __restrict__ s1,
                 const float* __restrict__ s2, const float* __restrict__ s3,
                 const float* __restrict__ s4, const float* __restrict__ s5,
                 const float* __restrict__ s6, const float* __restrict__ s7,
                 const float* __restrict__ s8, __hip_bfloat16* __restrict__ dst) {
    const long long g = (long long)blockIdx.x * 256 + threadIdx.x;
    const float* s; long long base;
    if      (g < 196608)  { s = s0; base = 0; }
    else if (g < 262144)  { s = s1; base = 196608; }
    else if (g < 327680)  { s = s2; base = 262144; }
    else if (g < 378880)  { s = s3; base = 327680; }
    else if (g < 387072)  { s = s4; base = 378880; }
    else if (g < 489472)  { s = s5; base = 387072; }
    else if (g < 555008)  { s = s6; base = 489472; }
    else if (g < 817152)  { s = s7; base = 555008; }
    else                  { s = s8; base = 817152; }
    dst[g] = __float2bfloat16(s[g - base]);
}

// ================= top-k, grid-parallel (4 kernels) =================
extern "C" __global__ __launch_bounds__(512)
void topk_hist_kernel(const float* __restrict__ score, unsigned int* __restrict__ hist) {
    const int t = threadIdx.x, bx = blockIdx.x, bb = blockIdx.y;
    const int i = bx * 512 + t;
    unsigned int u = f2s(score[(long long)bb * HW_N + i]);
    atomicAdd(&hist[bb * 8192 + (u >> 19)], 1u);
}

extern "C" __global__ __launch_bounds__(1024)
void topk_scan_kernel(const unsigned int* __restrict__ hist, unsigned int* __restrict__ ctrl) {
    __shared__ unsigned int scan[1024];
    const int t = threadIdx.x, bb = blockIdx.x;
    unsigned int loc[8]; unsigned int lsum = 0u;
    #pragma unroll
    for (int k = 0; k < 8; ++k) { loc[k] = hist[bb * 8192 + t * 8 + k]; lsum += loc[k]; }
    scan[t] = lsum;
    __syncthreads();
    for (int off = 1; off < 1024; off <<= 1) {
        unsigned int v = (t + off < 1024) ? scan[t + off] : 0u;
        __syncthreads();
        scan[t] += v;
        __syncthreads();
    }
    unsigned int nxt = (t < 1023) ? scan[t + 1] : 0u;
    unsigned int run = nxt;
    for (int k = 7; k >= 0; --k) {
        run += loc[k];
        unsigned int above = run - loc[k];
        if (run >= 1024u && above < 1024u) { ctrl[bb * 16 + 0] = (unsigned)(t * 8 + k); ctrl[bb * 16 + 1] = 1024u - above; }
        if (run >= 4096u && above < 4096u) { ctrl[bb * 16 + 2] = (unsigned)(t * 8 + k); ctrl[bb * 16 + 3] = 4096u - above; }
    }
}

extern "C" __global__ __launch_bounds__(1024)
void topk_collect_kernel(const float* __restrict__ score, unsigned int* __restrict__ ctrl,
                         unsigned long long* __restrict__ list1,
                         unsigned long long* __restrict__ list2) {
    const int t = threadIdx.x, bx = blockIdx.x, bb = blockIdx.y;
    const int i = bx * 1024 + t;
    const unsigned int T1 = ctrl[bb * 16 + 0], T2 = ctrl[bb * 16 + 2];
    unsigned int u = f2s(score[(long long)bb * HW_N + i]);
    unsigned int bin = u >> 19;
    unsigned long long key = ((unsigned long long)u << 32) | (unsigned int)(~(unsigned int)i);
    if (bin == T1) {
        unsigned int p = atomicAdd(&ctrl[bb * 16 + 4], 1u);
        if (p < 2048u) list1[bb * 2048 + p] = key;
    }
    if (bin == T2 && T2 != T1) {
        unsigned int p = atomicAdd(&ctrl[bb * 16 + 5], 1u);
        if (p < 2048u) list2[bb * 2048 + p] = key;
    }
}

extern "C" __global__ __launch_bounds__(1024)
void topk_classify_kernel(const float* __restrict__ score, unsigned int* __restrict__ ctrl,
                          const unsigned long long* __restrict__ list1,
                          const unsigned long long* __restrict__ list2,
                          int* __restrict__ idx_out) {
    __shared__ unsigned int cA, cB, baseA, baseB;
    const int t = threadIdx.x, bx = blockIdx.x, bb = blockIdx.y;
    const int i = bx * 1024 + t;
    if (t == 0) { cA = 0u; cB = 0u; }
    __syncthreads();
    const unsigned int T1 = ctrl[bb * 16 + 0], need1 = ctrl[bb * 16 + 1];
    const unsigned int T2 = ctrl[bb * 16 + 2], need2 = ctrl[bb * 16 + 3];
    const unsigned int c1 = min(ctrl[bb * 16 + 4], 2048u);
    const unsigned int c2 = min(ctrl[bb * 16 + 5], 2048u);
    unsigned int u = f2s(score[(long long)bb * HW_N + i]);
    unsigned int bin = u >> 19;
    unsigned long long key = ((unsigned long long)u << 32) | (unsigned int)(~(unsigned int)i);
    bool inA = false, inB = false;
    if (bin > T1) {
        inA = true;
    } else if (bin == T1) {
        unsigned int r = 0;
        for (unsigned int q = 0; q < c1; ++q) r += (list1[bb * 2048 + q] > key) ? 1u : 0u;
        if (r < need1) inA = true;
        else if (T2 == T1) inB = (r < need2);
        else inB = true;
    } else if (bin > T2) {
        inB = true;
    } else if (bin == T2) {
        unsigned int r = 0;
        for (unsigned int q = 0; q < c2; ++q) r += (list2[bb * 2048 + q] > key) ? 1u : 0u;
        inB = (r < need2);
    }
    unsigned int sA = 0u, sB = 0u;
    if (inA) sA = atomicAdd(&cA, 1u);
    if (inB) sB = atomicAdd(&cB, 1u);
    __syncthreads();
    if (t == 0) {
        baseA = atomicAdd(&ctrl[bb * 16 + 6], cA);
        baseB = atomicAdd(&ctrl[bb * 16 + 7], cB);
    }
    __syncthreads();
    if (inA) idx_out[bb * NSEL + baseA + sA] = i;
    if (inB) idx_out[bb * NSEL + 1024 + baseB + sB] = i;
}

// ---------------- gather selected rows ----------------
extern "C" __global__ __launch_bounds__(256)
void gather_kernel(const float* __restrict__ src, const float* __restrict__ pos,
                   const float* __restrict__ refw, const int* __restrict__ idx,
                   float* __restrict__ selsrc, float* __restrict__ selpos,
                   float* __restrict__ selref, float* __restrict__ qk) {
    const int s = blockIdx.x, bb = blockIdx.y, t = threadIdx.x;
    const int i = idx[bb * NSEL + s];
    const long long so = ((long long)(bb * NSEL + s)) * DIM;
    const long long go = ((long long)(bb * HW_N + i)) * DIM;
    float sv = src[go + t], pv = pos[go + t];
    selsrc[so + t] = sv;
    selpos[so + t] = pv;
    if (s < NQ) qk[((long long)(bb * NQ + s)) * DIM + t] = sv + pv;
    if (t < 7)
        selref[(long long)(bb * NSEL + s) * 7 + t] = refw[(long long)(bb * HW_N + i) * 7 + t];
}

// ---------------- bf16 MFMA GEMM: C = act(A @ W^T + bias) ----------------
// W: PRE-CONVERTED bf16 [N][K]. A: fp32 (amode 0) or bf16 (amode 1), [z][M][K].
// omode: 0 fp32 out; 1 bf16 flat; 2 bf16 transposed (col*M+row);
//        3 bf16 head-planar: off = zoff + ((col>>5)*16384 + row)*32 + (col&31).
extern "C" __global__ __launch_bounds__(256)
void gemm_kernel(const void* __restrict__ Avp, long long sA,
                 const __hip_bfloat16* __restrict__ W, const float* __restrict__ bias,
                 float* __restrict__ C, long long sC,
                 int M, int N, int K, int relu, int omode, int amode) {
    __shared__ __hip_bfloat16 As[64][72];
    __shared__ __hip_bfloat16 Ws[64][72];
    const int t = threadIdx.x;
    const int n0 = blockIdx.x * 64, m0 = blockIdx.y * 64;
    const long long zoff = (long long)blockIdx.z * sC;
    const int lane = t & 63, wv = t >> 6;
    const int mw = (wv >> 1) * 32, nw = (wv & 1) * 32;
    const int fr = lane & 15;
    const int fk = (lane >> 4) * 8;
    const int sr = t >> 2;
    const int sk = (t & 3) * 16;

    f32x4 acc[2][2];
    #pragma unroll
    for (int i = 0; i < 2; ++i)
        #pragma unroll
        for (int j = 0; j < 2; ++j) acc[i][j] = {0.f, 0.f, 0.f, 0.f};

    const bool wok = (n0 + sr) < N;
    for (int k0 = 0; k0 < K; k0 += 64) {
        // stage W: straight 32B bf16 copy
        uint4 wa = make_uint4(0u, 0u, 0u, 0u), wb = make_uint4(0u, 0u, 0u, 0u);
        if (wok) {
            const __hip_bfloat16* wp = W + (long long)(n0 + sr) * K + k0 + sk;
            wa = *(const uint4*)wp;
            wb = *(const uint4*)(wp + 8);
        }
        if (amode) {
            const __hip_bfloat16* ap = (const __hip_bfloat16*)Avp
                + (long long)blockIdx.z * sA + (long long)(m0 + sr) * K + k0 + sk;
            uint4 aa = *(const uint4*)ap;
            uint4 ab = *(const uint4*)(ap + 8);
            __syncthreads();
            *(uint4*)&As[sr][sk] = aa;
            *(uint4*)&As[sr][sk + 8] = ab;
            *(uint4*)&Ws[sr][sk] = wa;
            *(uint4*)&Ws[sr][sk + 8] = wb;
        } else {
            const float* ap = (const float*)Avp
                + (long long)blockIdx.z * sA + (long long)(m0 + sr) * K + k0 + sk;
            float av[16];
            #pragma unroll
            for (int q = 0; q < 4; ++q) {
                float4 v = *(const float4*)(ap + q * 4);
                av[q * 4 + 0] = v.x; av[q * 4 + 1] = v.y; av[q * 4 + 2] = v.z; av[q * 4 + 3] = v.w;
            }
            __syncthreads();
            #pragma unroll
            for (int q = 0; q < 16; ++q) As[sr][sk + q] = __float2bfloat16(av[q]);
            *(uint4*)&Ws[sr][sk] = wa;
            *(uint4*)&Ws[sr][sk + 8] = wb;
        }
        __syncthreads();
        #pragma unroll
        for (int kk = 0; kk < 64; kk += 32) {
            bf16x8 a0 = *(const bf16x8*)&As[mw + fr][kk + fk];
            bf16x8 a1 = *(const bf16x8*)&As[mw + 16 + fr][kk + fk];
            bf16x8 b0 = *(const bf16x8*)&Ws[nw + fr][kk + fk];
            bf16x8 b1 = *(const bf16x8*)&Ws[nw + 16 + fr][kk + fk];
            acc[0][0] = __builtin_amdgcn_mfma_f32_16x16x32_bf16(a0, b0, acc[0][0], 0, 0, 0);
            acc[0][1] = __builtin_amdgcn_mfma_f32_16x16x32_bf16(a0, b1, acc[0][1], 0, 0, 0);
            acc[1][0] = __builtin_amdgcn_mfma_f32_16x16x32_bf16(a1, b0, acc[1][0], 0, 0, 0);
            acc[1][1] = __builtin_amdgcn_mfma_f32_16x16x32_bf16(a1, b1, acc[1][1], 0, 0, 0);
        }
    }
    const int crow = (lane >> 4) * 4;
    #pragma unroll
    for (int mi = 0; mi < 2; ++mi) {
        #pragma unroll
        for (int ni = 0; ni < 2; ++ni) {
            const int col = n0 + nw + ni * 16 + fr;
            if (col < N) {
                const float bv = bias ? bias[col] : 0.f;
                #pragma unroll
                for (int r = 0; r < 4; ++r) {
                    const int row = m0 + mw + mi * 16 + crow + r;
                    float v = acc[mi][ni][r] + bv;
                    if (relu) v = fmaxf(v, 0.f);
                    if (omode == 0) {
                        C[zoff + (long long)row * N + col] = v;
                    } else if (omode == 1) {
                        ((__hip_bfloat16*)C)[zoff + (long long)row * N + col] = __float2bfloat16(v);
                    } else if (omode == 2) {
                        ((__hip_bfloat16*)C)[zoff + (long long)col * M + row] = __float2bfloat16(v);
                    } else {
                        ((__hip_bfloat16*)C)[zoff + ((long long)(col >> 5) * 16384 + row) * 32 + (col & 31)]
                            = __float2bfloat16(v);
                    }
                }
            }
        }
    }
}

// ---------------- MHA via MFMA: 16 queries/block, S & softmax in registers ----
extern "C" __global__ __launch_bounds__(256)
void attn_kernel(const __hip_bfloat16* __restrict__ qkb,
                 const __hip_bfloat16* __restrict__ vT,
                 float* __restrict__ attout) {
    __shared__ __hip_bfloat16 pb[16][1048];
    __shared__ float redm[4][16];
    __shared__ float reds[4][16];
    __shared__ float redo[4][16][33];
    const int t = threadIdx.x;
    const int qt = blockIdx.x, h = blockIdx.y, bb = blockIdx.z;
    const int q0 = qt * 16;
    const int lane = t & 63, wv = t >> 6;
    const int fr = lane & 15, g = lane >> 4;
    const int kbase = wv * 256;
    const float scale = 0.17677669529663687f;

    bf16x8 qfrag = *(const bf16x8*)(qkb + ((long long)(bb * NQ + q0 + fr)) * 512 + h * HD + g * 8);

    f32x4 sfr[16];
    #pragma unroll
    for (int kt = 0; kt < 16; ++kt) {
        const int key0 = kbase + kt * 16;
        bf16x8 kf = *(const bf16x8*)(qkb + ((long long)(bb * NQ + key0 + fr)) * 512 + 256 + h * HD + g * 8);
        f32x4 z = {0.f, 0.f, 0.f, 0.f};
        sfr[kt] = __builtin_amdgcn_mfma_f32_16x16x32_bf16(qfrag, kf, z, 0, 0, 0);
    }
    #pragma unroll
    for (int kt = 0; kt < 16; ++kt)
        #pragma unroll
        for (int r = 0; r < 4; ++r) sfr[kt][r] *= scale;

    #pragma unroll
    for (int r = 0; r < 4; ++r) {
        float mx = -1e30f;
        #pragma unroll
        for (int kt = 0; kt < 16; ++kt) mx = fmaxf(mx, sfr[kt][r]);
        #pragma unroll
        for (int mm = 1; mm <= 8; mm <<= 1) mx = fmaxf(mx, __shfl_xor(mx, mm, 64));
        float sm = 0.f;
        #pragma unroll
        for (int kt = 0; kt < 16; ++kt) sm += expf(sfr[kt][r] - mx);
        #pragma unroll
        for (int mm = 1; mm <= 8; mm <<= 1) sm += __shfl_xor(sm, mm, 64);
        if (fr == 0) { redm[wv][4 * g + r] = mx; reds[wv][4 * g + r] = sm; }
    }
    __syncthreads();

    float gm[4], gl[4];
    #pragma unroll
    for (int r = 0; r < 4; ++r) {
        const int q = 4 * g + r;
        float mm = fmaxf(fmaxf(redm[0][q], redm[1][q]), fmaxf(redm[2][q], redm[3][q]));
        float ll = 0.f;
        #pragma unroll
        for (int w2 = 0; w2 < 4; ++w2) ll += reds[w2][q] * expf(redm[w2][q] - mm);
        gm[r] = mm; gl[r] = 1.f / ll;
    }
    #pragma unroll
    for (int kt = 0; kt < 16; ++kt) {
        #pragma unroll
        for (int r = 0; r < 4; ++r) {
            float p = expf(sfr[kt][r] - gm[r]) * gl[r];
            pb[4 * g + r][kbase + kt * 16 + fr] = __float2bfloat16(p);
        }
    }

    f32x4 o0 = {0.f, 0.f, 0.f, 0.f}, o1 = {0.f, 0.f, 0.f, 0.f};
    const __hip_bfloat16* vbase = vT + ((long long)bb * DIM + h * HD) * 1024;
    #pragma unroll
    for (int ks = 0; ks < 8; ++ks) {
        const int key0 = kbase + ks * 32 + g * 8;
        bf16x8 pf = *(const bf16x8*)&pb[fr][key0];
        bf16x8 v0 = *(const bf16x8*)(vbase + (long long)fr * 1024 + key0);
        bf16x8 v1 = *(const bf16x8*)(vbase + (long long)(16 + fr) * 1024 + key0);
        o0 = __builtin_amdgcn_mfma_f32_16x16x32_bf16(pf, v0, o0, 0, 0, 0);
        o1 = __builtin_amdgcn_mfma_f32_16x16x32_bf16(pf, v1, o1, 0, 0, 0);
    }

    #pragma unroll
    for (int r = 0; r < 4; ++r) {
        redo[wv][4 * g + r][fr] = o0[r];
        redo[wv][4 * g + r][16 + fr] = o1[r];
    }
    __syncthreads();
    #pragma unroll
    for (int i = 0; i < 2; ++i) {
        const int idx = t + i * 256;
        const int q = idx >> 5, d = idx & 31;
        float v = redo[0][q][d] + redo[1][q][d] + redo[2][q][d] + redo[3][q][d];
        attout[((long long)(bb * NQ + q0 + q)) * DIM + h * HD + d] = v;
    }
}

// ---------------- residual + LayerNorm (in-place capable) ----------------
extern "C" __global__ __launch_bounds__(256)
void ln_kernel(const float* __restrict__ X, long long sx,
               const float* __restrict__ R, long long sr,
               const float* __restrict__ g, const float* __restrict__ bta,
               float* __restrict__ O, long long so) {
    __shared__ float red[4];
    const int row = blockIdx.x, bb = blockIdx.y, t = threadIdx.x;
    float x = X[(long long)bb * sx + (long long)row * DIM + t]
            + R[(long long)bb * sr + (long long)row * DIM + t];
    float v = x;
    #pragma unroll
    for (int m = 32; m >= 1; m >>= 1) v += __shfl_xor(v, m, 64);
    if ((t & 63) == 0) red[t >> 6] = v;
    __syncthreads();
    float mean = (red[0] + red[1] + red[2] + red[3]) * (1.f / 256.f);
    __syncthreads();
    float d = x - mean;
    v = d * d;
    #pragma unroll
    for (int m = 32; m >= 1; m >>= 1) v += __shfl_xor(v, m, 64);
    if ((t & 63) == 0) red[t >> 6] = v;
    __syncthreads();
    float var = (red[0] + red[1] + red[2] + red[3]) * (1.f / 256.f);
    O[(long long)bb * so + (long long)row * DIM + t] = d * rsqrtf(var + 1e-5f) * g[t] + bta[t];
}

// ---------------- query = selsrc + selpos ----------------
extern "C" __global__ __launch_bounds__(256)
void addq_kernel(const float* __restrict__ a, const float* __restrict__ b2, float* __restrict__ o) {
    long long i = (long long)blockIdx.x * 256 + threadIdx.x;
    o[i] = a[i] + b2[i];
}

// ---------------- box attention ----------------
// vp is HEAD-PLANAR bf16: vp[((b*8+h)*16384 + pix)*32 + ch].
// Phase B: 8 lanes/head x bf16x4 loads; 4 waves split the 100 (p,corner) pairs.
extern "C" __global__ __launch_bounds__(256)
void boxattn_kernel(const float* __restrict__ aw, const float* __restrict__ ob,
                    const float* __restrict__ dgrid, const float* __restrict__ selref,
                    const __hip_bfloat16* __restrict__ vp, const float* __restrict__ kidx,
                    float* __restrict__ boxout) {
    __shared__ float aw_s[200];
    __shared__ float ob_s[32];
    __shared__ float ref_s[7];
    __shared__ float ki_s[50];
    __shared__ float box_s[8][6];
    __shared__ float mx_s[8];
    __shared__ float inv_s[8];
    __shared__ float wq_s[200];
    __shared__ int   i4_s[800];
    __shared__ float w4_s[800];
    __shared__ float red4[4][8][32];
    const int t = threadIdx.x;
    const int s = blockIdx.x, bb = blockIdx.y;
    const long long base = (long long)(bb * NSEL + s);
    if (t < 200) aw_s[t] = aw[base * 200 + t];
    if (t < 32)  ob_s[t] = ob[base * 32 + t];
    if (t < 7)   ref_s[t] = selref[base * 7 + t];
    if (t < 50)  ki_s[t] = kidx[t];
    __syncthreads();

    if (t < 8) {
        float mx = -1e30f;
        #pragma unroll
        for (int p = 0; p < NP_; ++p) mx = fmaxf(mx, aw_s[t * NP_ + p]);
        mx_s[t] = mx;
        const float r0 = ref_s[0], r1 = ref_s[1], r3 = ref_s[3], r4 = ref_s[4], r6 = ref_s[6];
        box_s[t][0] = r0 + ob_s[t * 4 + 0] * 0.125f * r3;
        box_s[t][1] = r1 + ob_s[t * 4 + 1] * 0.125f * r4;
        box_s[t][2] = fmaxf(r3 + ob_s[t * 4 + 2] * 0.125f * r3, 0.f);
        box_s[t][3] = fmaxf(r4 + ob_s[t * 4 + 3] * 0.125f * r4, 0.f);
        box_s[t][4] = cosf(r6);
        box_s[t][5] = sinf(r6);
    }
    __syncthreads();

    if (t < 200) {
        const int h = t / NP_, p = t - h * NP_;
        const float w = expf(aw_s[t] - mx_s[h]);
        wq_s[t] = w;
        const float cx = box_s[h][0], cy = box_s[h][1];
        const float sw = box_s[h][2], sh = box_s[h][3];
        const float ca = box_s[h][4], sa = box_s[h][5];
        const float fx = ki_s[p * 2 + 0] * sw;
        const float fy = ki_s[p * 2 + 1] * sh;
        const float gx = cx + ca * fx - sa * fy + dgrid[base * 400 + 2 * t + 0] * (1.f / 188.f);
        const float gy = cy + sa * fx + ca * fy + dgrid[base * 400 + 2 * t + 1] * (1.f / 188.f);
        const float x = gx * 128.f - 0.5f;
        const float y = gy * 128.f - 0.5f;
        const float x0f = floorf(x), y0f = floorf(y);
        const float lx = x - x0f, ly = y - y0f;
        const int x0 = (int)x0f, y0 = (int)y0f;
        #pragma unroll
        for (int c = 0; c < 4; ++c) {
            const int xi = x0 + (c & 1);
            const int yi = y0 + (c >> 1);
            const float wgt = ((c & 1) ? lx : 1.f - lx) * ((c >> 1) ? ly : 1.f - ly);
            const bool valid = (xi >= 0) & (xi < 128) & (yi >= 0) & (yi < 128);
            const int cxi = min(max(xi, 0), 127);
            const int cyi = min(max(yi, 0), 127);
            i4_s[t * 4 + c] = cyi * 128 + cxi;
            w4_s[t * 4 + c] = w * (valid ? wgt : 0.f);
        }
    }
    __syncthreads();
    if (t < 8) {
        float sm = 0.f;
        #pragma unroll
        for (int p = 0; p < NP_; ++p) sm += wq_s[t * NP_ + p];
        inv_s[t] = 1.f / sm;
    }
    __syncthreads();

    // phase B
    {
        const int lane = t & 63, wv = t >> 6;
        const int h2 = lane >> 3, q = lane & 7;
        const __hip_bfloat16* vb = vp + ((long long)(bb * 8 + h2) * 16384) * 32 + q * 4;
        float a0 = 0.f, a1 = 0.f, a2 = 0.f, a3 = 0.f;
        for (int j = wv; j < 100; j += 4) {
            const int e = h2 * 100 + j;
            const int pix = i4_s[e];
            const float w = w4_s[e];
            bf16x4 v = *(const bf16x4*)(vb + (long long)pix * 32);
            a0 += w * (float)v[0];
            a1 += w * (float)v[1];
            a2 += w * (float)v[2];
            a3 += w * (float)v[3];
        }
        red4[wv][h2][q * 4 + 0] = a0;
        red4[wv][h2][q * 4 + 1] = a1;
        red4[wv][h2][q * 4 + 2] = a2;
        red4[wv][h2][q * 4 + 3] = a3;
    }
    __syncthreads();
    {
        const int h = t >> 5, d = t & 31;
        float v = red4[0][h][d] + red4[1][h][d] + red4[2][h][d] + red4[3][h][d];
        boxout[base * DIM + h * HD + d] = v * inv_s[h];
    }
}

// ---------------- scatter final rows back into out ----------------
extern "C" __global__ __launch_bounds__(256)
void scatter_kernel(const int* __restrict__ idx, const float* __restrict__ sel,
                    float* __restrict__ out) {
    const int s = blockIdx.x, bb = blockIdx.y, t = threadIdx.x;
    const int i = idx[bb * NSEL + s];
    out[((long long)(bb * HW_N + i)) * DIM + t] = sel[((long long)(bb * NSEL + s)) * DIM + t];
}

extern "C" void kernel_launch(void* const* d_in, const int* in_sizes, int n_in,
                              void* d_out, int out_size, void* d_ws, size_t ws_size,
                              hipStream_t stream) {
    const float* src          = (const float*)d_in[0];
    const float* pos          = (const float*)d_in[1];
    const float* refw         = (const float*)d_in[4];
    const float* score        = (const float*)d_in[5];
    const float* in_proj_w    = (const float*)d_in[6];
    const float* in_proj_b    = (const float*)d_in[7];
    const float* mha_out_w    = (const float*)d_in[8];
    const float* mha_out_b    = (const float*)d_in[9];
    const float* value_proj_w = (const float*)d_in[10];
    const float* value_proj_b = (const float*)d_in[11];
    const float* lin_attn_w   = (const float*)d_in[12];
    const float* lin_attn_b   = (const float*)d_in[13];
    const float* lin_box_w    = (const float*)d_in[14];
    const float* lin_box_b    = (const float*)d_in[15];
    const float* samp_off_w   = (const float*)d_in[16];
    const float* samp_off_b   = (const float*)d_in[17];
    const float* ca_out_w     = (const float*)d_in[18];
    const float* ca_out_b     = (const float*)d_in[19];
    const float* lin1_w       = (const float*)d_in[20];
    const float* lin1_b       = (const float*)d_in[21];
    const float* lin2_w       = (const float*)d_in[22];
    const float* lin2_b       = (const float*)d_in[23];
    const float* qn_g         = (const float*)d_in[24];
    const float* qn_b         = (const float*)d_in[25];
    const float* n1_g         = (const float*)d_in[26];
    const float* n1_b         = (const float*)d_in[27];
    const float* n2_g         = (const float*)d_in[28];
    const float* n2_b         = (const float*)d_in[29];
    const float* kidx         = (const float*)d_in[30];

    float* w = (float*)d_ws;
    int* idxp = (int*)d_ws;
    float* selref = w + OFF_SELREF;
    float* selsrc = w + OFF_SELSRC;
    float* selpos = w + OFF_SELPOS;
    float* boxout = w + OFF_SELPOS;   // reuse after selpos dead
    float* query  = w + OFF_QUERY;
    float* src2   = w + OFF_QUERY;    // reuse after query dead
    __hip_bfloat16* vproj  = (__hip_bfloat16*)(w + OFF_BIG);   // head-planar bf16
    __hip_bfloat16* ffntb  = (__hip_bfloat16*)(w + OFF_BIG);   // reuse after vproj dead
    __hip_bfloat16* wbf    = (__hip_bfloat16*)(w + OFF_WBF);   // bf16 weight pool
    float* qk     = w + OFF_F;
    __hip_bfloat16* qkb = (__hip_bfloat16*)(w + OFF_F + 524288);
    __hip_bfloat16* vT  = (__hip_bfloat16*)(w + OFF_F + 1572864);
    float* attout = w + OFF_F + 2097152;
    float* q2     = w + OFF_F + 2621440;
    float* aw     = w + OFF_F;              // reuse after MHA dead
    float* obuf   = w + OFF_F + 1638400;
    float* dgrid  = w + OFF_F + 1900544;
    float* ff     = w + OFF_F;              // reuse after box-attn dead
    unsigned int* hist2 = (unsigned int*)(w + OFF_F);          // topk scratch
    unsigned int* ctrl2 = hist2 + 16384;
    unsigned long long* list1 = (unsigned long long*)(hist2 + 16448);
    unsigned long long* list2 = list1 + 2 * 2048;
    float* out    = (float*)d_out;

    // bf16 weight pool offsets
    const long long W_INPROJ = 0, W_MHAOUT = 196608, W_VALUE = 262144,
                    W_LATTN = 327680, W_LBOX = 378880, W_SOFF = 387072,
                    W_CAOUT = 489472, W_LIN1 = 555008, W_LIN2 = 817152;

    hipMemcpyAsync(d_out, src, (size_t)2 * HW_N * DIM * sizeof(float),
                   hipMemcpyDeviceToDevice, stream);

    wcvt_kernel<<<4216, 256, 0, stream>>>(in_proj_w, mha_out_w, value_proj_w,
                                          lin_attn_w, lin_box_w, samp_off_w,
                                          ca_out_w, lin1_w, lin2_w, wbf);

    hipMemsetAsync(hist2, 0, 16448 * sizeof(unsigned int), stream);
    topk_hist_kernel<<<dim3(32, 2), 512, 0, stream>>>(score, hist2);
    topk_scan_kernel<<<2, 1024, 0, stream>>>(hist2, ctrl2);
    topk_collect_kernel<<<dim3(16, 2), 1024, 0, stream>>>(score, ctrl2, list1, list2);
    topk_classify_kernel<<<dim3(16, 2), 1024, 0, stream>>>(score, ctrl2, list1, list2, idxp);

    gather_kernel<<<dim3(NSEL, 2), 256, 0, stream>>>(src, pos, refw, idxp,
                                                     selsrc, selpos, selref, qk);
    gemm_kernel<<<dim3(8, 16, 2), 256, 0, stream>>>(qk, 262144LL, wbf + W_INPROJ, in_proj_b,
                                                    (float*)qkb, 524288LL, NQ, 512, 256, 0, 1, 0);
    gemm_kernel<<<dim3(4, 16, 2), 256, 0, stream>>>(selsrc, 1048576LL, wbf + W_INPROJ + 512 * 256,
                                                    in_proj_b + 512, (float*)vT, 262144LL, NQ, 256, 256, 0, 2, 0);
    attn_kernel<<<dim3(64, 8, 2), 256, 0, stream>>>(qkb, vT, attout);
    gemm_kernel<<<dim3(4, 16, 2), 256, 0, stream>>>(attout, 262144LL, wbf + W_MHAOUT, mha_out_b,
                                                    q2, 262144LL, NQ, 256, 256, 0, 0, 0);
    ln_kernel<<<dim3(NQ, 2), 256, 0, stream>>>(selsrc, 1048576LL, q2, 262144LL,
                                               qn_g, qn_b, selsrc, 1048576LL);
    addq_kernel<<<8192, 256, 0, stream>>>(selsrc, selpos, query);
    gemm_kernel<<<dim3(4, 256, 2), 256, 0, stream>>>(src, 4194304LL, wbf + W_VALUE, value_proj_b,
                                                     (float*)vproj, 4194304LL, HW_N, 256, 256, 0, 3, 0);
    gemm_kernel<<<dim3(4, 64, 2), 256, 0, stream>>>(query, 1048576LL, wbf + W_LATTN, lin_attn_b,
                                                    aw, 819200LL, NSEL, 200, 256, 0, 0, 0);
    gemm_kernel<<<dim3(1, 64, 2), 256, 0, stream>>>(query, 1048576LL, wbf + W_LBOX, lin_box_b,
                                                    obuf, 131072LL, NSEL, 32, 256, 0, 0, 0);
    gemm_kernel<<<dim3(7, 64, 2), 256, 0, stream>>>(query, 1048576LL, wbf + W_SOFF, samp_off_b,
                                                    dgrid, 1638400LL, NSEL, 400, 256, 0, 0, 0);
    boxattn_kernel<<<dim3(NSEL, 2), 256, 0, stream>>>(aw, obuf, dgrid, selref, vproj, kidx, boxout);
    gemm_kernel<<<dim3(4, 64, 2), 256, 0, stream>>>(boxout, 1048576LL, wbf + W_CAOUT, ca_out_b,
                                                    src2, 1048576LL, NSEL, 256, 256, 0, 0, 0);
    ln_kernel<<<dim3(NSEL, 2), 256, 0, stream>>>(selsrc, 1048576LL, src2, 1048576LL,
                                                 n1_g, n1_b, selsrc, 1048576LL);
    gemm_kernel<<<dim3(16, 64, 2), 256, 0, stream>>>(selsrc, 1048576LL, wbf + W_LIN1, lin1_b,
                                                     (float*)ffntb, 4194304LL, NSEL, DFF_, 256, 1, 1, 0);
    gemm_kernel<<<dim3(4, 64, 2), 256, 0, stream>>>(ffntb, 4194304LL, wbf + W_LIN2, lin2_b,
                                                    ff, 1048576LL, NSEL, 256, DFF_, 0, 0, 1);
    ln_kernel<<<dim3(NSEL, 2), 256, 0, stream>>>(selsrc, 1048576LL, ff, 1048576LL,
                                                 n2_g, n2_b, selsrc, 1048576LL);
    scatter_kernel<<<dim3(NSEL, 2), 256, 0, stream>>>(idxp, selsrc, out);
}